// Round 1
// baseline (1288.395 us; speedup 1.0000x reference)
//
#include <hip/hip_runtime.h>
#include <math.h>

#define B_ 4
#define S_ 1024
#define D_ 1024
#define H_ 16
#define HD_ 64
#define BSD_ (B_*S_*D_)

// ---------------- block reduce (256 threads = 4 waves) ----------------
__device__ __forceinline__ float block_reduce_sum_256(float v, float* sbuf) {
  #pragma unroll
  for (int off = 32; off > 0; off >>= 1) v += __shfl_xor(v, off, 64);
  int lane = threadIdx.x & 63, wid = threadIdx.x >> 6;
  __syncthreads();
  if (lane == 0) sbuf[wid] = v;
  __syncthreads();
  return sbuf[0] + sbuf[1] + sbuf[2] + sbuf[3];
}

// ---------------- LayerNorm: one block per (b,s) row, D=1024 ----------------
__global__ __launch_bounds__(256) void ln_kernel(const float* __restrict__ x,
                                                 const float* __restrict__ g,
                                                 const float* __restrict__ bta,
                                                 float* __restrict__ out) {
  __shared__ float sbuf[4];
  const int row = blockIdx.x;
  const float* xr = x + (size_t)row * D_;
  const int t = threadIdx.x;
  float v[4]; float s = 0.f;
  #pragma unroll
  for (int i = 0; i < 4; i++) { v[i] = xr[t + 256*i]; s += v[i]; }
  const float mean = block_reduce_sum_256(s, sbuf) * (1.0f/D_);
  float sq = 0.f;
  #pragma unroll
  for (int i = 0; i < 4; i++) { float d = v[i]-mean; sq += d*d; }
  const float var = block_reduce_sum_256(sq, sbuf) * (1.0f/D_);
  const float r = rsqrtf(var + 1e-5f);
  float* orow = out + (size_t)row * D_;
  #pragma unroll
  for (int i = 0; i < 4; i++) {
    int c = t + 256*i;
    orow[c] = (v[i]-mean)*r*g[c] + bta[c];
  }
}

// ---------------- fp32 GEMM: C[M,N] = A·B^T (+ optional A2·B2^T) + bias ------
// B is row-major [N,K] with row stride ldb (supports strided views of Wproj).
#define BM 64
#define BN 64
#define BK 16
#define LDP 68

__global__ __launch_bounds__(256) void gemm_kernel(
    const float* __restrict__ A, const float* __restrict__ Bw,
    const float* __restrict__ bias, float* __restrict__ C,
    int K, int lda, int ldb, int ldc,
    const float* __restrict__ A2, const float* __restrict__ B2,
    int lda2, int ldb2) {
  __shared__ __align__(16) float As[BK][LDP];
  __shared__ __align__(16) float Bs[BK][LDP];
  const int bm = blockIdx.y * BM, bn = blockIdx.x * BN;
  const int tid = threadIdx.x;
  const int tx = tid & 15, ty = tid >> 4;
  const int lrow = tid >> 2;          // 0..63
  const int lcol = (tid & 3) << 2;    // 0,4,8,12
  float acc[4][4] = {{0.f,0.f,0.f,0.f},{0.f,0.f,0.f,0.f},{0.f,0.f,0.f,0.f},{0.f,0.f,0.f,0.f}};
  const int npass = (A2 != nullptr) ? 2 : 1;
  for (int pass = 0; pass < npass; ++pass) {
    const float* Ap = pass ? A2 : A;
    const float* Bp = pass ? B2 : Bw;
    const int la = pass ? lda2 : lda;
    const int lb = pass ? ldb2 : ldb;
    const float* Arow = Ap + (size_t)(bm + lrow) * la + lcol;
    const float* Brow = Bp + (size_t)(bn + lrow) * lb + lcol;
    for (int k0 = 0; k0 < K; k0 += BK) {
      const float4 a4 = *(const float4*)(Arow + k0);
      const float4 b4 = *(const float4*)(Brow + k0);
      __syncthreads();
      As[lcol+0][lrow]=a4.x; As[lcol+1][lrow]=a4.y; As[lcol+2][lrow]=a4.z; As[lcol+3][lrow]=a4.w;
      Bs[lcol+0][lrow]=b4.x; Bs[lcol+1][lrow]=b4.y; Bs[lcol+2][lrow]=b4.z; Bs[lcol+3][lrow]=b4.w;
      __syncthreads();
      #pragma unroll
      for (int kk = 0; kk < BK; ++kk) {
        const float4 a = *(const float4*)&As[kk][ty*4];
        const float4 b = *(const float4*)&Bs[kk][tx*4];
        const float av[4] = {a.x,a.y,a.z,a.w};
        const float bv[4] = {b.x,b.y,b.z,b.w};
        #pragma unroll
        for (int i=0;i<4;i++)
          #pragma unroll
          for (int j=0;j<4;j++)
            acc[i][j] += av[i]*bv[j];
      }
    }
  }
  #pragma unroll
  for (int i = 0; i < 4; i++) {
    float* Crow = C + (size_t)(bm + ty*4 + i) * ldc + bn + tx*4;
    float4 o;
    o.x = acc[i][0]; o.y = acc[i][1]; o.z = acc[i][2]; o.w = acc[i][3];
    if (bias) {
      o.x += bias[bn+tx*4+0]; o.y += bias[bn+tx*4+1];
      o.z += bias[bn+tx*4+2]; o.w += bias[bn+tx*4+3];
    }
    *(float4*)Crow = o;
  }
}

// ---------------- global causal flash attention, fp32 ----------------
// block = (qt, b*H+h); 64-row Q tile; K/V tiles of 64; online softmax.
// KPs is shared between K (d-major [d][c]) and P ([key][r]) to fit 3 arrays < 64KB LDS.
__global__ __launch_bounds__(256) void gattn_kernel(
    const float* __restrict__ Q, const float* __restrict__ K,
    const float* __restrict__ V, float* __restrict__ O) {
  __shared__ __align__(16) float Qs[HD_][LDP];
  __shared__ __align__(16) float KPs[64][LDP];
  __shared__ __align__(16) float Vs[64][LDP];
  const int qt = blockIdx.x;
  const int bh = blockIdx.y;
  const int b = bh >> 4, h = bh & 15;
  const int tid = threadIdx.x;
  const int tx = tid & 15, ty = tid >> 4;
  const size_t base = ((size_t)b * S_) * D_ + (size_t)h * HD_;
  #pragma unroll
  for (int c = 0; c < 4; c++) {
    int f = tid + c*256;
    int r = f >> 4;
    int dc = (f & 15) << 2;
    const float4 q4 = *(const float4*)(Q + base + (size_t)(qt*64 + r) * D_ + dc);
    Qs[dc+0][r]=q4.x; Qs[dc+1][r]=q4.y; Qs[dc+2][r]=q4.z; Qs[dc+3][r]=q4.w;
  }
  float o[4][4] = {{0.f,0.f,0.f,0.f},{0.f,0.f,0.f,0.f},{0.f,0.f,0.f,0.f},{0.f,0.f,0.f,0.f}};
  float mrow[4], lrow[4];
  #pragma unroll
  for (int i=0;i<4;i++){ mrow[i] = -INFINITY; lrow[i] = 0.f; }
  for (int kt = 0; kt <= qt; ++kt) {
    __syncthreads();
    #pragma unroll
    for (int c = 0; c < 4; c++) {
      int f = tid + c*256;
      int r = f >> 4;
      int dc = (f & 15) << 2;
      const float4 k4 = *(const float4*)(K + base + (size_t)(kt*64 + r) * D_ + dc);
      KPs[dc+0][r]=k4.x; KPs[dc+1][r]=k4.y; KPs[dc+2][r]=k4.z; KPs[dc+3][r]=k4.w;
      const float4 v4 = *(const float4*)(V + base + (size_t)(kt*64 + r) * D_ + dc);
      *(float4*)&Vs[r][dc] = v4;
    }
    __syncthreads();
    float s[4][4] = {{0.f,0.f,0.f,0.f},{0.f,0.f,0.f,0.f},{0.f,0.f,0.f,0.f},{0.f,0.f,0.f,0.f}};
    #pragma unroll 8
    for (int d = 0; d < HD_; ++d) {
      const float4 a  = *(const float4*)&Qs[d][ty*4];
      const float4 bb = *(const float4*)&KPs[d][tx*4];
      const float av[4]={a.x,a.y,a.z,a.w};
      const float bv[4]={bb.x,bb.y,bb.z,bb.w};
      #pragma unroll
      for (int i=0;i<4;i++)
        #pragma unroll
        for (int j=0;j<4;j++)
          s[i][j] += av[i]*bv[j];
    }
    const bool diag = (kt == qt);
    #pragma unroll
    for (int i=0;i<4;i++) {
      #pragma unroll
      for (int j=0;j<4;j++) {
        float lg = s[i][j]*0.125f;           // 1/sqrt(HD)
        if (diag && (tx*4+j) > (ty*4+i)) lg = -INFINITY;
        s[i][j] = lg;
      }
    }
    #pragma unroll
    for (int i=0;i<4;i++) {
      float tm = fmaxf(fmaxf(s[i][0],s[i][1]), fmaxf(s[i][2],s[i][3]));
      #pragma unroll
      for (int off=1; off<16; off<<=1) tm = fmaxf(tm, __shfl_xor(tm, off, 64));
      const float nm = fmaxf(mrow[i], tm);
      const float alpha = __expf(mrow[i]-nm);
      float ps = 0.f;
      #pragma unroll
      for (int j=0;j<4;j++){ float p = __expf(s[i][j]-nm); s[i][j]=p; ps += p; }
      #pragma unroll
      for (int off=1; off<16; off<<=1) ps += __shfl_xor(ps, off, 64);
      lrow[i] = lrow[i]*alpha + ps;
      mrow[i] = nm;
      #pragma unroll
      for (int j=0;j<4;j++) o[i][j] *= alpha;
    }
    __syncthreads();   // KPs (K) reads done -> reuse as P
    #pragma unroll
    for (int i=0;i<4;i++)
      #pragma unroll
      for (int j=0;j<4;j++)
        KPs[tx*4+j][ty*4+i] = s[i][j];
    __syncthreads();
    #pragma unroll 8
    for (int kk = 0; kk < 64; ++kk) {
      const float4 a  = *(const float4*)&KPs[kk][ty*4];
      const float4 bb = *(const float4*)&Vs[kk][tx*4];
      const float av[4]={a.x,a.y,a.z,a.w};
      const float bv[4]={bb.x,bb.y,bb.z,bb.w};
      #pragma unroll
      for (int i=0;i<4;i++)
        #pragma unroll
        for (int j=0;j<4;j++)
          o[i][j] += av[i]*bv[j];
    }
  }
  #pragma unroll
  for (int i=0;i<4;i++){
    const float inv = 1.0f / lrow[i];
    float4 ov; ov.x=o[i][0]*inv; ov.y=o[i][1]*inv; ov.z=o[i][2]*inv; ov.w=o[i][3]*inv;
    *(float4*)(O + base + (size_t)(qt*64 + ty*4 + i) * D_ + tx*4) = ov;
  }
}

// ---------------- seq-mean over S: globe_out [B,S,D] -> mbd [B,D] ------------
__global__ __launch_bounds__(256) void seqmean_kernel(const float* __restrict__ g,
                                                      float* __restrict__ mbd) {
  const int b = blockIdx.y;
  const int d = blockIdx.x*256 + threadIdx.x;
  const float* p = g + (size_t)b*S_*D_ + d;
  float s0=0.f,s1=0.f,s2=0.f,s3=0.f;
  for (int s = 0; s < S_; s += 4) {
    s0 += p[(size_t)(s+0)*D_];
    s1 += p[(size_t)(s+1)*D_];
    s2 += p[(size_t)(s+2)*D_];
    s3 += p[(size_t)(s+3)*D_];
  }
  mbd[b*D_ + d] = (s0+s1+s2+s3)*(1.0f/S_);
}

// ---------------- predictor: sm, temp, win, span_len, local_max, n_win -------
__global__ __launch_bounds__(256) void predictor_kernel(
    const float* __restrict__ mbd, const float* __restrict__ Wp,
    const float* __restrict__ bp, float* __restrict__ fpar, int* __restrict__ ipar) {
  __shared__ float sbuf[4];
  __shared__ float sdots[4];
  const int tid = threadIdx.x;
  for (int b = 0; b < 4; b++) {
    float psum = 0.f;
    for (int d = tid; d < D_; d += 256) psum += mbd[b*D_ + d]*Wp[d];
    float tot = block_reduce_sum_256(psum, sbuf);
    if (tid == 0) sdots[b] = tot;
  }
  __syncthreads();
  if (tid == 0) {
    float smv = 0.f;
    for (int b = 0; b < 4; b++) {
      float z = sdots[b] + bp[0];
      float sig = 1.0f/(1.0f + expf(-z));   // sigmoid; clip(0,1) is a no-op
      smv += sig;
    }
    smv *= 0.25f;                            // mean over B
    int win = max(1, (int)(256.0f*smv));     // exact: 256*x has no rounding
    int span_len = max(1, (int)(512.0f*smv));
    int local_max = min(512, min(span_len, win));
    float temp = 1.0f + 0.01f*(1.0f - smv);
    int n_win = (S_ + win - 1)/win;
    fpar[0] = smv; fpar[1] = temp;
    ipar[0] = win; ipar[1] = span_len; ipar[2] = local_max; ipar[3] = n_win;
  }
}

// ---------------- dynamic sliding-window span attention, fp32 ----------------
// grid = (64 window-slots, B*H); each block loops windows w += gridDim.x.
__global__ __launch_bounds__(256) void lattn_kernel(
    const float* __restrict__ Lc, float* __restrict__ Out,
    const int* __restrict__ ip, const float* __restrict__ fpp) {
  __shared__ __align__(16) float Qs[HD_][LDP];
  __shared__ __align__(16) float KPs[64][LDP];
  __shared__ __align__(16) float Vs[64][LDP];
  const int n_win = ip[3];
  const int win = ip[0], span_len = ip[1], local_max = ip[2];
  const float sm = fpp[0], temp = fpp[1];
  const int bh = blockIdx.y;
  const int b = bh >> 4, h = bh & 15;
  const int tid = threadIdx.x;
  const int tx = tid & 15, ty = tid >> 4;
  const float sc = 0.35355339059327373f / temp;   // HD^-0.25 / temp
  for (int w = blockIdx.x; w < n_win; w += gridDim.x) {
    const int st = w * win;
    const int en = min(st + win, S_); const int wlen = en - st;
    const int ks = max(0, st - span_len + win);
    const int ke = min(st + span_len, S_); const int klen = ke - ks;
    int eff = (int)((double)wlen * (double)sm);    // matches python int(wlen*float(sm))
    eff = min(min(eff, wlen), min(klen, local_max));
    if (eff <= 0) continue;                        // rows stay zero (memset)
    const int nt = (eff + 63) >> 6;                // q-tiles == k-tiles
    for (int qt = 0; qt < nt; ++qt) {
      const int qn = min(64, eff - qt*64);
      __syncthreads();
      #pragma unroll
      for (int c = 0; c < 4; c++) {
        int f = tid + c*256;
        int r = f >> 4;
        int dc = (f & 15) << 2;
        float4 q4 = make_float4(0.f,0.f,0.f,0.f);
        if (r < qn) q4 = *(const float4*)(Lc + ((size_t)(b*S_ + st + qt*64 + r)) * D_ + h*HD_ + dc);
        Qs[dc+0][r]=q4.x; Qs[dc+1][r]=q4.y; Qs[dc+2][r]=q4.z; Qs[dc+3][r]=q4.w;
      }
      float o[4][4] = {{0.f,0.f,0.f,0.f},{0.f,0.f,0.f,0.f},{0.f,0.f,0.f,0.f},{0.f,0.f,0.f,0.f}};
      float mrow[4], lrow[4];
      #pragma unroll
      for (int i=0;i<4;i++){ mrow[i] = -INFINITY; lrow[i] = 0.f; }
      for (int kt = 0; kt < nt; ++kt) {
        const int kn = min(64, eff - kt*64);
        __syncthreads();
        #pragma unroll
        for (int c = 0; c < 4; c++) {
          int f = tid + c*256;
          int r = f >> 4;
          int dc = (f & 15) << 2;
          float4 k4 = make_float4(0.f,0.f,0.f,0.f);
          float4 v4 = make_float4(0.f,0.f,0.f,0.f);
          if (r < kn) {
            const size_t rowoff = ((size_t)(b*S_ + ks + kt*64 + r)) * D_ + h*HD_ + dc;
            k4 = *(const float4*)(Lc + rowoff);
            v4 = k4; // K and V are the same tensor slice in span_attn
          }
          KPs[dc+0][r]=k4.x; KPs[dc+1][r]=k4.y; KPs[dc+2][r]=k4.z; KPs[dc+3][r]=k4.w;
          *(float4*)&Vs[r][dc] = v4;
        }
        __syncthreads();
        float s[4][4] = {{0.f,0.f,0.f,0.f},{0.f,0.f,0.f,0.f},{0.f,0.f,0.f,0.f},{0.f,0.f,0.f,0.f}};
        #pragma unroll 8
        for (int d = 0; d < HD_; ++d) {
          const float4 a  = *(const float4*)&Qs[d][ty*4];
          const float4 bb = *(const float4*)&KPs[d][tx*4];
          const float av[4]={a.x,a.y,a.z,a.w};
          const float bv[4]={bb.x,bb.y,bb.z,bb.w};
          #pragma unroll
          for (int i=0;i<4;i++)
            #pragma unroll
            for (int j=0;j<4;j++)
              s[i][j] += av[i]*bv[j];
        }
        #pragma unroll
        for (int i=0;i<4;i++) {
          #pragma unroll
          for (int j=0;j<4;j++) {
            float lg = s[i][j]*sc;
            if (kt*64 + tx*4 + j >= eff) lg = -INFINITY;  // only eff keys exist
            s[i][j] = lg;
          }
        }
        #pragma unroll
        for (int i=0;i<4;i++) {
          float tm = fmaxf(fmaxf(s[i][0],s[i][1]), fmaxf(s[i][2],s[i][3]));
          #pragma unroll
          for (int off=1; off<16; off<<=1) tm = fmaxf(tm, __shfl_xor(tm, off, 64));
          const float nm = fmaxf(mrow[i], tm);
          const float alpha = __expf(mrow[i]-nm);
          float ps = 0.f;
          #pragma unroll
          for (int j=0;j<4;j++){ float p = __expf(s[i][j]-nm); s[i][j]=p; ps += p; }
          #pragma unroll
          for (int off=1; off<16; off<<=1) ps += __shfl_xor(ps, off, 64);
          lrow[i] = lrow[i]*alpha + ps;
          mrow[i] = nm;
          #pragma unroll
          for (int j=0;j<4;j++) o[i][j] *= alpha;
        }
        __syncthreads();
        #pragma unroll
        for (int i=0;i<4;i++)
          #pragma unroll
          for (int j=0;j<4;j++)
            KPs[tx*4+j][ty*4+i] = s[i][j];
        __syncthreads();
        #pragma unroll 8
        for (int kk = 0; kk < 64; ++kk) {
          const float4 a  = *(const float4*)&KPs[kk][ty*4];
          const float4 bb = *(const float4*)&Vs[kk][tx*4];
          const float av[4]={a.x,a.y,a.z,a.w};
          const float bv[4]={bb.x,bb.y,bb.z,bb.w};
          #pragma unroll
          for (int i=0;i<4;i++)
            #pragma unroll
            for (int j=0;j<4;j++)
              o[i][j] += av[i]*bv[j];
        }
      }
      #pragma unroll
      for (int i=0;i<4;i++){
        const int r = ty*4 + i;
        if (r < qn) {
          const float inv = 1.0f / lrow[i];
          float4 ov; ov.x=o[i][0]*inv; ov.y=o[i][1]*inv; ov.z=o[i][2]*inv; ov.w=o[i][3]*inv;
          *(float4*)(Out + ((size_t)(b*S_ + st + qt*64 + r)) * D_ + h*HD_ + tx*4) = ov;
        }
      }
    }
  }
}

// ---------------- launch ----------------
extern "C" void kernel_launch(void* const* d_in, const int* in_sizes, int n_in,
                              void* d_out, int out_size, void* d_ws, size_t ws_size,
                              hipStream_t stream) {
  const float* x      = (const float*)d_in[0];
  const float* ln_a_g = (const float*)d_in[1];
  const float* ln_a_b = (const float*)d_in[2];
  const float* ln_b_g = (const float*)d_in[3];
  const float* ln_b_b = (const float*)d_in[4];
  const float* Wq     = (const float*)d_in[5];
  const float* bq     = (const float*)d_in[6];
  const float* Wk     = (const float*)d_in[7];
  const float* Wv     = (const float*)d_in[8];
  const float* bv     = (const float*)d_in[9];
  const float* Wo     = (const float*)d_in[10];
  const float* bo     = (const float*)d_in[11];
  const float* Wp     = (const float*)d_in[12];
  const float* bp     = (const float*)d_in[13];
  const float* Wproj  = (const float*)d_in[14];
  const float* bproj  = (const float*)d_in[15];
  float* out = (float*)d_out;
  float* ws  = (float*)d_ws;

  // ws layout (fp32), 4 x 16MB big buffers + params; buffers aggressively reused:
  float* globe = ws;                    // LN_b(x); later: attention output (merged)
  float* Qb    = ws + (size_t)BSD_;     // Q; later: globe_out
  float* Kb    = ws + 2*(size_t)BSD_;   // K; later: local = LN_a(x)
  float* Vb    = ws + 3*(size_t)BSD_;   // V; later: local_out
  float* mbd   = ws + 4*(size_t)BSD_;   // [B,D] seq-means
  float* fpar  = mbd + B_*D_;           // sm, temp
  int*   ipar  = (int*)(fpar + 8);      // win, span_len, local_max, n_win

  const dim3 blk(256);
  const dim3 gg(D_/BN, (B_*S_)/BM);

  // 1) globe = LN_b(x)
  ln_kernel<<<dim3(B_*S_), blk, 0, stream>>>(x, ln_b_g, ln_b_b, globe);
  // 2) Q = globe Wq^T + bq ; K = globe Wk^T ; V = globe Wv^T + bv
  gemm_kernel<<<gg, blk, 0, stream>>>(globe, Wq, bq,      Qb, D_, D_, D_, D_, nullptr, nullptr, 0, 0);
  gemm_kernel<<<gg, blk, 0, stream>>>(globe, Wk, nullptr, Kb, D_, D_, D_, D_, nullptr, nullptr, 0, 0);
  gemm_kernel<<<gg, blk, 0, stream>>>(globe, Wv, bv,      Vb, D_, D_, D_, D_, nullptr, nullptr, 0, 0);
  // 3) causal attention -> reuse globe buffer
  gattn_kernel<<<dim3(S_/64, B_*H_), blk, 0, stream>>>(Qb, Kb, Vb, globe);
  // 4) globe_out = attn Wo^T + bo -> reuse Qb
  gemm_kernel<<<gg, blk, 0, stream>>>(globe, Wo, bo, Qb, D_, D_, D_, D_, nullptr, nullptr, 0, 0);
  // 5) span predictor (device-side; no host sync)
  seqmean_kernel<<<dim3(D_/256, B_), blk, 0, stream>>>(Qb, mbd);
  predictor_kernel<<<dim3(1), blk, 0, stream>>>(mbd, Wp, bp, fpar, ipar);
  // 6) local = LN_a(x) -> reuse Kb
  ln_kernel<<<dim3(B_*S_), blk, 0, stream>>>(x, ln_a_g, ln_a_b, Kb);
  // 7) local_out -> reuse Vb (zero first: un-attended rows are zero)
  hipMemsetAsync(Vb, 0, (size_t)BSD_*sizeof(float), stream);
  lattn_kernel<<<dim3(64, B_*H_), blk, 0, stream>>>(Kb, Vb, ipar, fpar);
  // 8) out = local_out W1^T + globe_out W2^T + bproj  (W1/W2 strided views of Wproj [D,2D])
  gemm_kernel<<<gg, blk, 0, stream>>>(Vb, Wproj, bproj, out, D_, D_, 2*D_, D_,
                                      Qb, Wproj + D_, D_, 2*D_);
}

// Round 2
// 711.440 us; speedup vs baseline: 1.8110x; 1.8110x over previous
//
#include <hip/hip_runtime.h>
#include <math.h>

#define B_ 4
#define S_ 1024
#define D_ 1024
#define H_ 16
#define HD_ 64
#define BSD_ (B_*S_*D_)

using short8 = __attribute__((ext_vector_type(8))) short;
using f32x4  = __attribute__((ext_vector_type(4))) float;

// ---------------- bf16 helpers (RNE) ----------------
__device__ __forceinline__ ushort f2bf(float f) {
  uint u = __float_as_uint(f);
  return (ushort)((u + 0x7fffu + ((u >> 16) & 1u)) >> 16);
}
__device__ __forceinline__ float bf2f(ushort h) {
  return __uint_as_float(((uint)h) << 16);
}

// ---------------- block reduce (256 threads = 4 waves) ----------------
__device__ __forceinline__ float block_reduce_sum_256(float v, float* sbuf) {
  #pragma unroll
  for (int off = 32; off > 0; off >>= 1) v += __shfl_xor(v, off, 64);
  int lane = threadIdx.x & 63, wid = threadIdx.x >> 6;
  __syncthreads();
  if (lane == 0) sbuf[wid] = v;
  __syncthreads();
  return sbuf[0] + sbuf[1] + sbuf[2] + sbuf[3];
}

// ---------------- LayerNorm ----------------
__global__ __launch_bounds__(256) void ln_kernel(const float* __restrict__ x,
                                                 const float* __restrict__ g,
                                                 const float* __restrict__ bta,
                                                 float* __restrict__ out) {
  __shared__ float sbuf[4];
  const int row = blockIdx.x;
  const float* xr = x + (size_t)row * D_;
  const int t = threadIdx.x;
  float v[4]; float s = 0.f;
  #pragma unroll
  for (int i = 0; i < 4; i++) { v[i] = xr[t + 256*i]; s += v[i]; }
  const float mean = block_reduce_sum_256(s, sbuf) * (1.0f/D_);
  float sq = 0.f;
  #pragma unroll
  for (int i = 0; i < 4; i++) { float d = v[i]-mean; sq += d*d; }
  const float var = block_reduce_sum_256(sq, sbuf) * (1.0f/D_);
  const float r = rsqrtf(var + 1e-5f);
  float* orow = out + (size_t)row * D_;
  #pragma unroll
  for (int i = 0; i < 4; i++) {
    int c = t + 256*i;
    orow[c] = (v[i]-mean)*r*g[c] + bta[c];
  }
}

// ---------------- split converts: fp32 -> bf16x3 concat along K ----------------
// A pattern: [hi | lo | hi]   (activations, K=1024 -> 3072)
__global__ __launch_bounds__(256) void split_act_kernel(const float* __restrict__ in,
                                                        ushort* __restrict__ out) {
  const int idx = blockIdx.x*256 + threadIdx.x;
  const int row = idx >> 8;            // 256 groups of 4 per 1024-col row
  const int col4 = (idx & 255) << 2;
  const float4 a = *(const float4*)(in + (size_t)row*1024 + col4);
  ushort4 hi, lo;
  hi.x = f2bf(a.x); hi.y = f2bf(a.y); hi.z = f2bf(a.z); hi.w = f2bf(a.w);
  lo.x = f2bf(a.x - bf2f(hi.x)); lo.y = f2bf(a.y - bf2f(hi.y));
  lo.z = f2bf(a.z - bf2f(hi.z)); lo.w = f2bf(a.w - bf2f(hi.w));
  ushort* orow = out + (size_t)row*3072;
  *(ushort4*)(orow + col4)        = hi;
  *(ushort4*)(orow + 1024 + col4) = lo;
  *(ushort4*)(orow + 2048 + col4) = hi;
}

// B pattern: [hi | hi | lo]  for Wq/Wk/Wv stacked rows (3072 rows)
__global__ __launch_bounds__(256) void split_w3_kernel(const float* __restrict__ Wq,
                                                       const float* __restrict__ Wk,
                                                       const float* __restrict__ Wv,
                                                       ushort* __restrict__ out) {
  const int idx = blockIdx.x*256 + threadIdx.x;
  const int n = idx >> 8;
  const int col4 = (idx & 255) << 2;
  const float* src = (n < 1024) ? (Wq + (size_t)n*1024)
                   : (n < 2048) ? (Wk + (size_t)(n-1024)*1024)
                                : (Wv + (size_t)(n-2048)*1024);
  const float4 a = *(const float4*)(src + col4);
  ushort4 hi, lo;
  hi.x = f2bf(a.x); hi.y = f2bf(a.y); hi.z = f2bf(a.z); hi.w = f2bf(a.w);
  lo.x = f2bf(a.x - bf2f(hi.x)); lo.y = f2bf(a.y - bf2f(hi.y));
  lo.z = f2bf(a.z - bf2f(hi.z)); lo.w = f2bf(a.w - bf2f(hi.w));
  ushort* orow = out + (size_t)n*3072;
  *(ushort4*)(orow + col4)        = hi;
  *(ushort4*)(orow + 1024 + col4) = hi;
  *(ushort4*)(orow + 2048 + col4) = lo;
}

// B pattern for a single 1024-row weight (Wo)
__global__ __launch_bounds__(256) void split_w1_kernel(const float* __restrict__ W,
                                                       ushort* __restrict__ out) {
  const int idx = blockIdx.x*256 + threadIdx.x;
  const int n = idx >> 8;
  const int col4 = (idx & 255) << 2;
  const float4 a = *(const float4*)(W + (size_t)n*1024 + col4);
  ushort4 hi, lo;
  hi.x = f2bf(a.x); hi.y = f2bf(a.y); hi.z = f2bf(a.z); hi.w = f2bf(a.w);
  lo.x = f2bf(a.x - bf2f(hi.x)); lo.y = f2bf(a.y - bf2f(hi.y));
  lo.z = f2bf(a.z - bf2f(hi.z)); lo.w = f2bf(a.w - bf2f(hi.w));
  ushort* orow = out + (size_t)n*3072;
  *(ushort4*)(orow + col4)        = hi;
  *(ushort4*)(orow + 1024 + col4) = hi;
  *(ushort4*)(orow + 2048 + col4) = lo;
}

// plain fp32 -> bf16 convert, writes rows of `ncols` at out[row*ostride + ooff + col]
__global__ __launch_bounds__(256) void cvt_bf16_kernel(const float* __restrict__ in,
                                                       ushort* __restrict__ out,
                                                       int gprshift, int ostride, int ooff) {
  const int idx = blockIdx.x*256 + threadIdx.x;
  const int row = idx >> gprshift;
  const int col4 = (idx & ((1 << gprshift) - 1)) << 2;
  const int ncols = 4 << gprshift;
  const float4 a = *(const float4*)(in + (size_t)row*ncols + col4);
  ushort4 hi;
  hi.x = f2bf(a.x); hi.y = f2bf(a.y); hi.z = f2bf(a.z); hi.w = f2bf(a.w);
  *(ushort4*)(out + (size_t)row*ostride + ooff + col4) = hi;
}

__global__ __launch_bounds__(256) void bias_cat_kernel(const float* __restrict__ bq,
                                                       const float* __restrict__ bv,
                                                       float* __restrict__ out) {
  const int n = blockIdx.x*256 + threadIdx.x;
  out[n] = (n < 1024) ? bq[n] : (n < 2048) ? 0.f : bv[n-2048];
}

// ---------------- bf16 MFMA GEMM: C[M,N] = A[M,K] · Bw[N,K]^T + bias ----------------
// 128x128 tile, BK=32, 4 waves each computing 64x64 via 4x4 grid of 16x16x32 MFMAs.
// LDS padded to stride 40 (bf16) to break bank conflicts.
__global__ __launch_bounds__(256) void mfma_gemm(
    const ushort* __restrict__ A, const ushort* __restrict__ Bw,
    const float* __restrict__ bias, float* __restrict__ C,
    int K, int ldc) {
  __shared__ __align__(16) ushort As[128*40];
  __shared__ __align__(16) ushort Bs[128*40];
  const int tid = threadIdx.x;
  const int bm = blockIdx.y * 128, bn = blockIdx.x * 128;
  const int wave = tid >> 6, lane = tid & 63;
  const int wm = wave >> 1, wn = wave & 1;
  const int lm = lane & 15, q = lane >> 4;
  const int srow = tid >> 2;           // 0..63
  const int schunk = (tid & 3) << 3;   // 0,8,16,24 (ushort offset)

  f32x4 acc[4][4];
  #pragma unroll
  for (int i = 0; i < 4; i++)
    #pragma unroll
    for (int j = 0; j < 4; j++)
      acc[i][j] = (f32x4){0.f,0.f,0.f,0.f};

  const ushort* Ag = A + (size_t)(bm + srow)*K + schunk;
  const ushort* Bg = Bw + (size_t)(bn + srow)*K + schunk;
  const int aoff0 = (wm*64 + lm)*40 + q*8;
  const int boff0 = (wn*64 + lm)*40 + q*8;

  for (int k0 = 0; k0 < K; k0 += 32) {
    const float4 a0 = *(const float4*)(Ag + k0);
    const float4 a1 = *(const float4*)(Ag + (size_t)64*K + k0);
    const float4 b0 = *(const float4*)(Bg + k0);
    const float4 b1 = *(const float4*)(Bg + (size_t)64*K + k0);
    __syncthreads();
    *(float4*)&As[srow*40 + schunk]      = a0;
    *(float4*)&As[(srow+64)*40 + schunk] = a1;
    *(float4*)&Bs[srow*40 + schunk]      = b0;
    *(float4*)&Bs[(srow+64)*40 + schunk] = b1;
    __syncthreads();
    short8 af[4], bf[4];
    #pragma unroll
    for (int mt = 0; mt < 4; mt++) af[mt] = *(const short8*)&As[aoff0 + mt*640];
    #pragma unroll
    for (int nt = 0; nt < 4; nt++) bf[nt] = *(const short8*)&Bs[boff0 + nt*640];
    #pragma unroll
    for (int mt = 0; mt < 4; mt++)
      #pragma unroll
      for (int nt = 0; nt < 4; nt++)
        acc[mt][nt] = __builtin_amdgcn_mfma_f32_16x16x32_bf16(af[mt], bf[nt], acc[mt][nt], 0, 0, 0);
  }

  #pragma unroll
  for (int mt = 0; mt < 4; mt++) {
    #pragma unroll
    for (int nt = 0; nt < 4; nt++) {
      const int n = bn + wn*64 + nt*16 + lm;
      const float bb = bias ? bias[n] : 0.f;
      #pragma unroll
      for (int reg = 0; reg < 4; reg++) {
        const int m = bm + wm*64 + mt*16 + q*4 + reg;
        C[(size_t)m*ldc + n] = acc[mt][nt][reg] + bb;
      }
    }
  }
}

// ---------------- global causal flash attention, fp32, load-balanced ----------------
// grid = (8 pairs, B*H); block handles q-tiles {15-p, p}: 17 kt-units each, all resident.
#define LDP 68
__global__ __launch_bounds__(256) void gattn_kernel(
    const float* __restrict__ QKV, float* __restrict__ O) {
  __shared__ __align__(16) float Qs[HD_][LDP];
  __shared__ __align__(16) float KPs[64][LDP];
  __shared__ __align__(16) float Vs[64][LDP];
  const int bh = blockIdx.y;
  const int b = bh >> 4, h = bh & 15;
  const int tid = threadIdx.x;
  const int tx = tid & 15, ty = tid >> 4;
  const size_t qkvbase = (size_t)b * S_ * 3072 + (size_t)h * HD_;
  const size_t obase   = (size_t)b * S_ * D_   + (size_t)h * HD_;
  for (int half = 0; half < 2; ++half) {
    const int qt = half ? blockIdx.x : 15 - blockIdx.x;
    __syncthreads();
    #pragma unroll
    for (int c = 0; c < 4; c++) {
      int f = tid + c*256;
      int r = f >> 4;
      int dc = (f & 15) << 2;
      const float4 q4 = *(const float4*)(QKV + qkvbase + (size_t)(qt*64 + r) * 3072 + dc);
      Qs[dc+0][r]=q4.x; Qs[dc+1][r]=q4.y; Qs[dc+2][r]=q4.z; Qs[dc+3][r]=q4.w;
    }
    float o[4][4] = {{0.f,0.f,0.f,0.f},{0.f,0.f,0.f,0.f},{0.f,0.f,0.f,0.f},{0.f,0.f,0.f,0.f}};
    float mrow[4], lrow[4];
    #pragma unroll
    for (int i=0;i<4;i++){ mrow[i] = -INFINITY; lrow[i] = 0.f; }
    for (int kt = 0; kt <= qt; ++kt) {
      __syncthreads();
      #pragma unroll
      for (int c = 0; c < 4; c++) {
        int f = tid + c*256;
        int r = f >> 4;
        int dc = (f & 15) << 2;
        const size_t rowoff = qkvbase + (size_t)(kt*64 + r) * 3072 + dc;
        const float4 k4 = *(const float4*)(QKV + rowoff + 1024);
        KPs[dc+0][r]=k4.x; KPs[dc+1][r]=k4.y; KPs[dc+2][r]=k4.z; KPs[dc+3][r]=k4.w;
        const float4 v4 = *(const float4*)(QKV + rowoff + 2048);
        *(float4*)&Vs[r][dc] = v4;
      }
      __syncthreads();
      float s[4][4] = {{0.f,0.f,0.f,0.f},{0.f,0.f,0.f,0.f},{0.f,0.f,0.f,0.f},{0.f,0.f,0.f,0.f}};
      #pragma unroll 8
      for (int d = 0; d < HD_; ++d) {
        const float4 a  = *(const float4*)&Qs[d][ty*4];
        const float4 bb = *(const float4*)&KPs[d][tx*4];
        const float av[4]={a.x,a.y,a.z,a.w};
        const float bv[4]={bb.x,bb.y,bb.z,bb.w};
        #pragma unroll
        for (int i=0;i<4;i++)
          #pragma unroll
          for (int j=0;j<4;j++)
            s[i][j] += av[i]*bv[j];
      }
      const bool diag = (kt == qt);
      #pragma unroll
      for (int i=0;i<4;i++) {
        #pragma unroll
        for (int j=0;j<4;j++) {
          float lg = s[i][j]*0.125f;
          if (diag && (tx*4+j) > (ty*4+i)) lg = -INFINITY;
          s[i][j] = lg;
        }
      }
      #pragma unroll
      for (int i=0;i<4;i++) {
        float tm = fmaxf(fmaxf(s[i][0],s[i][1]), fmaxf(s[i][2],s[i][3]));
        #pragma unroll
        for (int off=1; off<16; off<<=1) tm = fmaxf(tm, __shfl_xor(tm, off, 64));
        const float nm = fmaxf(mrow[i], tm);
        const float alpha = __expf(mrow[i]-nm);
        float ps = 0.f;
        #pragma unroll
        for (int j=0;j<4;j++){ float p = __expf(s[i][j]-nm); s[i][j]=p; ps += p; }
        #pragma unroll
        for (int off=1; off<16; off<<=1) ps += __shfl_xor(ps, off, 64);
        lrow[i] = lrow[i]*alpha + ps;
        mrow[i] = nm;
        #pragma unroll
        for (int j=0;j<4;j++) o[i][j] *= alpha;
      }
      __syncthreads();
      #pragma unroll
      for (int i=0;i<4;i++)
        #pragma unroll
        for (int j=0;j<4;j++)
          KPs[tx*4+j][ty*4+i] = s[i][j];
      __syncthreads();
      #pragma unroll 8
      for (int kk = 0; kk < 64; ++kk) {
        const float4 a  = *(const float4*)&KPs[kk][ty*4];
        const float4 bb = *(const float4*)&Vs[kk][tx*4];
        const float av[4]={a.x,a.y,a.z,a.w};
        const float bv[4]={bb.x,bb.y,bb.z,bb.w};
        #pragma unroll
        for (int i=0;i<4;i++)
          #pragma unroll
          for (int j=0;j<4;j++)
            o[i][j] += av[i]*bv[j];
      }
    }
    #pragma unroll
    for (int i=0;i<4;i++){
      const float inv = 1.0f / lrow[i];
      float4 ov; ov.x=o[i][0]*inv; ov.y=o[i][1]*inv; ov.z=o[i][2]*inv; ov.w=o[i][3]*inv;
      *(float4*)(O + obase + (size_t)(qt*64 + ty*4 + i) * D_ + tx*4) = ov;
    }
  }
}

// ---------------- seq-mean over S ----------------
__global__ __launch_bounds__(256) void seqmean_kernel(const float* __restrict__ g,
                                                      float* __restrict__ mbd) {
  const int b = blockIdx.y;
  const int d = blockIdx.x*256 + threadIdx.x;
  const float* p = g + (size_t)b*S_*D_ + d;
  float s0=0.f,s1=0.f,s2=0.f,s3=0.f;
  for (int s = 0; s < S_; s += 4) {
    s0 += p[(size_t)(s+0)*D_];
    s1 += p[(size_t)(s+1)*D_];
    s2 += p[(size_t)(s+2)*D_];
    s3 += p[(size_t)(s+3)*D_];
  }
  mbd[b*D_ + d] = (s0+s1+s2+s3)*(1.0f/S_);
}

// ---------------- predictor ----------------
__global__ __launch_bounds__(256) void predictor_kernel(
    const float* __restrict__ mbd, const float* __restrict__ Wp,
    const float* __restrict__ bp, float* __restrict__ fpar, int* __restrict__ ipar) {
  __shared__ float sbuf[4];
  __shared__ float sdots[4];
  const int tid = threadIdx.x;
  for (int b = 0; b < 4; b++) {
    float psum = 0.f;
    for (int d = tid; d < D_; d += 256) psum += mbd[b*D_ + d]*Wp[d];
    float tot = block_reduce_sum_256(psum, sbuf);
    if (tid == 0) sdots[b] = tot;
  }
  __syncthreads();
  if (tid == 0) {
    float smv = 0.f;
    for (int b = 0; b < 4; b++) {
      float z = sdots[b] + bp[0];
      smv += 1.0f/(1.0f + expf(-z));
    }
    smv *= 0.25f;
    int win = max(1, (int)(256.0f*smv));
    int span_len = max(1, (int)(512.0f*smv));
    int local_max = min(512, min(span_len, win));
    float temp = 1.0f + 0.01f*(1.0f - smv);
    int n_win = (S_ + win - 1)/win;
    fpar[0] = smv; fpar[1] = temp;
    ipar[0] = win; ipar[1] = span_len; ipar[2] = local_max; ipar[3] = n_win;
  }
}

// ---------------- dynamic sliding-window span attention, fp32 -> bf16 out --------
// writes bf16 into A3[:, 0:1024] (row stride 2048)
__global__ __launch_bounds__(256) void lattn_kernel(
    const float* __restrict__ Lc, ushort* __restrict__ Out,
    const int* __restrict__ ip, const float* __restrict__ fpp) {
  __shared__ __align__(16) float Qs[HD_][LDP];
  __shared__ __align__(16) float KPs[64][LDP];
  __shared__ __align__(16) float Vs[64][LDP];
  const int n_win = ip[3];
  const int win = ip[0], span_len = ip[1], local_max = ip[2];
  const float sm = fpp[0], temp = fpp[1];
  const int bh = blockIdx.y;
  const int b = bh >> 4, h = bh & 15;
  const int tid = threadIdx.x;
  const int tx = tid & 15, ty = tid >> 4;
  const float sc = 0.35355339059327373f / temp;
  for (int w = blockIdx.x; w < n_win; w += gridDim.x) {
    const int st = w * win;
    const int en = min(st + win, S_); const int wlen = en - st;
    const int ks = max(0, st - span_len + win);
    const int ke = min(st + span_len, S_); const int klen = ke - ks;
    int eff = (int)((double)wlen * (double)sm);
    eff = min(min(eff, wlen), min(klen, local_max));
    if (eff <= 0) continue;
    const int nt = (eff + 63) >> 6;
    for (int qt = 0; qt < nt; ++qt) {
      const int qn = min(64, eff - qt*64);
      __syncthreads();
      #pragma unroll
      for (int c = 0; c < 4; c++) {
        int f = tid + c*256;
        int r = f >> 4;
        int dc = (f & 15) << 2;
        float4 q4 = make_float4(0.f,0.f,0.f,0.f);
        if (r < qn) q4 = *(const float4*)(Lc + ((size_t)(b*S_ + st + qt*64 + r)) * D_ + h*HD_ + dc);
        Qs[dc+0][r]=q4.x; Qs[dc+1][r]=q4.y; Qs[dc+2][r]=q4.z; Qs[dc+3][r]=q4.w;
      }
      float o[4][4] = {{0.f,0.f,0.f,0.f},{0.f,0.f,0.f,0.f},{0.f,0.f,0.f,0.f},{0.f,0.f,0.f,0.f}};
      float mrow[4], lrow[4];
      #pragma unroll
      for (int i=0;i<4;i++){ mrow[i] = -INFINITY; lrow[i] = 0.f; }
      for (int kt = 0; kt < nt; ++kt) {
        const int kn = min(64, eff - kt*64);
        __syncthreads();
        #pragma unroll
        for (int c = 0; c < 4; c++) {
          int f = tid + c*256;
          int r = f >> 4;
          int dc = (f & 15) << 2;
          float4 k4 = make_float4(0.f,0.f,0.f,0.f);
          if (r < kn) k4 = *(const float4*)(Lc + ((size_t)(b*S_ + ks + kt*64 + r)) * D_ + h*HD_ + dc);
          KPs[dc+0][r]=k4.x; KPs[dc+1][r]=k4.y; KPs[dc+2][r]=k4.z; KPs[dc+3][r]=k4.w;
          *(float4*)&Vs[r][dc] = k4;
        }
        __syncthreads();
        float s[4][4] = {{0.f,0.f,0.f,0.f},{0.f,0.f,0.f,0.f},{0.f,0.f,0.f,0.f},{0.f,0.f,0.f,0.f}};
        #pragma unroll 8
        for (int d = 0; d < HD_; ++d) {
          const float4 a  = *(const float4*)&Qs[d][ty*4];
          const float4 bb = *(const float4*)&KPs[d][tx*4];
          const float av[4]={a.x,a.y,a.z,a.w};
          const float bv[4]={bb.x,bb.y,bb.z,bb.w};
          #pragma unroll
          for (int i=0;i<4;i++)
            #pragma unroll
            for (int j=0;j<4;j++)
              s[i][j] += av[i]*bv[j];
        }
        #pragma unroll
        for (int i=0;i<4;i++) {
          #pragma unroll
          for (int j=0;j<4;j++) {
            float lg = s[i][j]*sc;
            if (kt*64 + tx*4 + j >= eff) lg = -INFINITY;
            s[i][j] = lg;
          }
        }
        #pragma unroll
        for (int i=0;i<4;i++) {
          float tm = fmaxf(fmaxf(s[i][0],s[i][1]), fmaxf(s[i][2],s[i][3]));
          #pragma unroll
          for (int off=1; off<16; off<<=1) tm = fmaxf(tm, __shfl_xor(tm, off, 64));
          const float nm = fmaxf(mrow[i], tm);
          const float alpha = __expf(mrow[i]-nm);
          float ps = 0.f;
          #pragma unroll
          for (int j=0;j<4;j++){ float p = __expf(s[i][j]-nm); s[i][j]=p; ps += p; }
          #pragma unroll
          for (int off=1; off<16; off<<=1) ps += __shfl_xor(ps, off, 64);
          lrow[i] = lrow[i]*alpha + ps;
          mrow[i] = nm;
          #pragma unroll
          for (int j=0;j<4;j++) o[i][j] *= alpha;
        }
        __syncthreads();
        #pragma unroll
        for (int i=0;i<4;i++)
          #pragma unroll
          for (int j=0;j<4;j++)
            KPs[tx*4+j][ty*4+i] = s[i][j];
        __syncthreads();
        #pragma unroll 8
        for (int kk = 0; kk < 64; ++kk) {
          const float4 a  = *(const float4*)&KPs[kk][ty*4];
          const float4 bb = *(const float4*)&Vs[kk][tx*4];
          const float av[4]={a.x,a.y,a.z,a.w};
          const float bv[4]={bb.x,bb.y,bb.z,bb.w};
          #pragma unroll
          for (int i=0;i<4;i++)
            #pragma unroll
            for (int j=0;j<4;j++)
              o[i][j] += av[i]*bv[j];
        }
      }
      #pragma unroll
      for (int i=0;i<4;i++){
        const int r = ty*4 + i;
        if (r < qn) {
          const float inv = 1.0f / lrow[i];
          ushort4 ov;
          ov.x = f2bf(o[i][0]*inv); ov.y = f2bf(o[i][1]*inv);
          ov.z = f2bf(o[i][2]*inv); ov.w = f2bf(o[i][3]*inv);
          *(ushort4*)(Out + ((size_t)(b*S_ + st + qt*64 + r)) * 2048 + h*HD_ + tx*4) = ov;
        }
      }
    }
  }
}

// ---------------- launch ----------------
extern "C" void kernel_launch(void* const* d_in, const int* in_sizes, int n_in,
                              void* d_out, int out_size, void* d_ws, size_t ws_size,
                              hipStream_t stream) {
  const float* x      = (const float*)d_in[0];
  const float* ln_a_g = (const float*)d_in[1];
  const float* ln_a_b = (const float*)d_in[2];
  const float* ln_b_g = (const float*)d_in[3];
  const float* ln_b_b = (const float*)d_in[4];
  const float* Wq     = (const float*)d_in[5];
  const float* bq     = (const float*)d_in[6];
  const float* Wk     = (const float*)d_in[7];
  const float* Wv     = (const float*)d_in[8];
  const float* bv     = (const float*)d_in[9];
  const float* Wo     = (const float*)d_in[10];
  const float* bo     = (const float*)d_in[11];
  const float* Wp     = (const float*)d_in[12];
  const float* bp     = (const float*)d_in[13];
  const float* Wproj  = (const float*)d_in[14];
  const float* bproj  = (const float*)d_in[15];
  float* out = (float*)d_out;
  float* ws  = (float*)d_ws;

  // fp32 region (float offsets)
  float* QKVf = ws;                          // [4096,3072] fp32 (48MB); later overlaid by A3/B3 bf16
  float* buf0 = ws + 12582912;               // [4096,1024] LNb out -> attn_out
  float* glo  = ws + 16777216;               // [4096,1024] globe_out
  float* loc  = ws + 20971520;               // [4096,1024] LN_a out
  float* biascat = ws + 25165824;            // [3072]
  float* mbd  = biascat + 4096;              // [B,D]
  float* fpar = mbd + 4096;                  // sm, temp
  int*   ipar = (int*)(fpar + 8);
  // bf16 region
  ushort* Acat  = (ushort*)(ws + 25182208);  // [4096,3072] bf16 (25.2MB), reused for both splits
  ushort* Bqkv  = Acat + 12582912;           // [3072,3072] bf16 (18.9MB)
  ushort* Bo    = Bqkv + 9437184;            // [1024,3072] bf16 (6.3MB)
  // overlay (QKV fp32 dead after gattn):
  ushort* A3    = (ushort*)ws;               // [4096,2048] bf16 (16.8MB)
  ushort* B3    = A3 + 8388608;              // [1024,2048] bf16 (4.2MB)

  const dim3 blk(256);

  // 1) globe = LN_b(x)
  ln_kernel<<<dim3(B_*S_), blk, 0, stream>>>(x, ln_b_g, ln_b_b, buf0);
  // 2) bf16x3 split of activations and QKV weights; bias concat
  split_act_kernel<<<dim3(4096), blk, 0, stream>>>(buf0, Acat);
  split_w3_kernel<<<dim3(3072), blk, 0, stream>>>(Wq, Wk, Wv, Bqkv);
  bias_cat_kernel<<<dim3(12), blk, 0, stream>>>(bq, bv, biascat);
  // 3) QKV = Acat · Bqkv^T + biascat   [4096,3072] fp32
  mfma_gemm<<<dim3(24, 32), blk, 0, stream>>>(Acat, Bqkv, biascat, QKVf, 3072, 3072);
  // 4) causal attention -> buf0
  gattn_kernel<<<dim3(8, B_*H_), blk, 0, stream>>>(QKVf, buf0);
  // 5) globe_out = attn · Wo^T + bo  (bf16x3)
  split_act_kernel<<<dim3(4096), blk, 0, stream>>>(buf0, Acat);
  split_w1_kernel<<<dim3(1024), blk, 0, stream>>>(Wo, Bo);
  mfma_gemm<<<dim3(8, 32), blk, 0, stream>>>(Acat, Bo, bo, glo, 3072, 1024);
  // 6) predictor (device-side)
  seqmean_kernel<<<dim3(4, B_), blk, 0, stream>>>(glo, mbd);
  predictor_kernel<<<dim3(1), blk, 0, stream>>>(mbd, Wp, bp, fpar, ipar);
  // 7) local = LN_a(x)
  ln_kernel<<<dim3(B_*S_), blk, 0, stream>>>(x, ln_a_g, ln_a_b, loc);
  // 8) local attention -> A3[:, 0:1024] bf16 (zero first; QKVf is dead now)
  hipMemsetAsync(A3, 0, (size_t)4096*2048*2, stream);
  lattn_kernel<<<dim3(64, B_*H_), blk, 0, stream>>>(loc, A3, ipar, fpar);
  // 9) A3[:, 1024:2048] = bf16(globe_out); B3 = bf16(Wproj)
  cvt_bf16_kernel<<<dim3(4096), blk, 0, stream>>>(glo, A3, 8, 2048, 1024);
  cvt_bf16_kernel<<<dim3(2048), blk, 0, stream>>>(Wproj, B3, 9, 2048, 0);
  // 10) out = A3 · B3^T + bproj   [4096,1024] fp32
  mfma_gemm<<<dim3(8, 32), blk, 0, stream>>>(A3, B3, bproj, out, 2048, 1024);
}

// Round 4
// 630.630 us; speedup vs baseline: 2.0430x; 1.1281x over previous
//
#include <hip/hip_runtime.h>
#include <math.h>

#define B_ 4
#define S_ 1024
#define D_ 1024
#define H_ 16
#define HD_ 64
#define BSD_ (B_*S_*D_)

using short8 = __attribute__((ext_vector_type(8))) short;
using f32x4  = __attribute__((ext_vector_type(4))) float;

#define MFMA16(a,b,c) __builtin_amdgcn_mfma_f32_16x16x32_bf16((a),(b),(c),0,0,0)

// ---------------- bf16 helpers (RNE) ----------------
__device__ __forceinline__ ushort f2bf(float f) {
  uint u = __float_as_uint(f);
  return (ushort)((u + 0x7fffu + ((u >> 16) & 1u)) >> 16);
}
__device__ __forceinline__ float bf2f(ushort h) {
  return __uint_as_float(((uint)h) << 16);
}
__device__ __forceinline__ void split8(const float* p, short8* hi, short8* lo) {
  #pragma unroll
  for (int j = 0; j < 8; j++) {
    ushort h = f2bf(p[j]);
    (*hi)[j] = (short)h;
    (*lo)[j] = (short)f2bf(p[j] - bf2f(h));
  }
}

// ---------------- block reduce (256 threads = 4 waves) ----------------
__device__ __forceinline__ float block_reduce_sum_256(float v, float* sbuf) {
  #pragma unroll
  for (int off = 32; off > 0; off >>= 1) v += __shfl_xor(v, off, 64);
  int lane = threadIdx.x & 63, wid = threadIdx.x >> 6;
  __syncthreads();
  if (lane == 0) sbuf[wid] = v;
  __syncthreads();
  return sbuf[0] + sbuf[1] + sbuf[2] + sbuf[3];
}

// ---------------- LayerNorm (fp32 out) ----------------
__global__ __launch_bounds__(256) void ln_kernel(const float* __restrict__ x,
                                                 const float* __restrict__ g,
                                                 const float* __restrict__ bta,
                                                 float* __restrict__ out) {
  __shared__ float sbuf[4];
  const int row = blockIdx.x;
  const float* xr = x + (size_t)row * D_;
  const int t = threadIdx.x;
  float v[4]; float s = 0.f;
  #pragma unroll
  for (int i = 0; i < 4; i++) { v[i] = xr[t + 256*i]; s += v[i]; }
  const float mean = block_reduce_sum_256(s, sbuf) * (1.0f/D_);
  float sq = 0.f;
  #pragma unroll
  for (int i = 0; i < 4; i++) { float d = v[i]-mean; sq += d*d; }
  const float var = block_reduce_sum_256(sq, sbuf) * (1.0f/D_);
  const float r = rsqrtf(var + 1e-5f);
  float* orow = out + (size_t)row * D_;
  #pragma unroll
  for (int i = 0; i < 4; i++) {
    int c = t + 256*i;
    orow[c] = (v[i]-mean)*r*g[c] + bta[c];
  }
}

// ---------------- fused LayerNorm + bf16x3 act-split ([hi|lo|hi]) ----------------
__global__ __launch_bounds__(256) void ln_split_kernel(const float* __restrict__ x,
                                                       const float* __restrict__ g,
                                                       const float* __restrict__ bta,
                                                       ushort* __restrict__ out) {
  __shared__ float sbuf[4];
  const int row = blockIdx.x;
  const int t = threadIdx.x;
  const int c = t*4;
  const float* xr = x + (size_t)row * D_;
  float4 v = *(const float4*)(xr + c);
  float s = v.x + v.y + v.z + v.w;
  const float mean = block_reduce_sum_256(s, sbuf) * (1.0f/D_);
  float4 dv = make_float4(v.x-mean, v.y-mean, v.z-mean, v.w-mean);
  float sq = dv.x*dv.x + dv.y*dv.y + dv.z*dv.z + dv.w*dv.w;
  const float var = block_reduce_sum_256(sq, sbuf) * (1.0f/D_);
  const float r = rsqrtf(var + 1e-5f);
  float4 gg = *(const float4*)(g + c);
  float4 bb = *(const float4*)(bta + c);
  float n[4];
  n[0] = dv.x*r*gg.x + bb.x; n[1] = dv.y*r*gg.y + bb.y;
  n[2] = dv.z*r*gg.z + bb.z; n[3] = dv.w*r*gg.w + bb.w;
  ushort4 hi, lo;
  hi.x = f2bf(n[0]); hi.y = f2bf(n[1]); hi.z = f2bf(n[2]); hi.w = f2bf(n[3]);
  lo.x = f2bf(n[0]-bf2f(hi.x)); lo.y = f2bf(n[1]-bf2f(hi.y));
  lo.z = f2bf(n[2]-bf2f(hi.z)); lo.w = f2bf(n[3]-bf2f(hi.w));
  ushort* orow = out + (size_t)row*3072;
  *(ushort4*)(orow + c)        = hi;
  *(ushort4*)(orow + 1024 + c) = lo;
  *(ushort4*)(orow + 2048 + c) = hi;
}

// ---------------- act split [hi|lo|hi] from fp32 ----------------
__global__ __launch_bounds__(256) void split_act_kernel(const float* __restrict__ in,
                                                        ushort* __restrict__ out) {
  const int idx = blockIdx.x*256 + threadIdx.x;
  const int row = idx >> 8;
  const int col4 = (idx & 255) << 2;
  const float4 a = *(const float4*)(in + (size_t)row*1024 + col4);
  ushort4 hi, lo;
  hi.x = f2bf(a.x); hi.y = f2bf(a.y); hi.z = f2bf(a.z); hi.w = f2bf(a.w);
  lo.x = f2bf(a.x - bf2f(hi.x)); lo.y = f2bf(a.y - bf2f(hi.y));
  lo.z = f2bf(a.z - bf2f(hi.z)); lo.w = f2bf(a.w - bf2f(hi.w));
  ushort* orow = out + (size_t)row*3072;
  *(ushort4*)(orow + col4)        = hi;
  *(ushort4*)(orow + 1024 + col4) = lo;
  *(ushort4*)(orow + 2048 + col4) = hi;
}

// ---------------- weight split [hi|hi|lo] for Wq/Wk/Wv stacked (3072 rows) -------
__global__ __launch_bounds__(256) void split_w3_kernel(const float* __restrict__ Wq,
                                                       const float* __restrict__ Wk,
                                                       const float* __restrict__ Wv,
                                                       ushort* __restrict__ out) {
  const int idx = blockIdx.x*256 + threadIdx.x;
  const int n = idx >> 8;
  const int col4 = (idx & 255) << 2;
  const float* src = (n < 1024) ? (Wq + (size_t)n*1024)
                   : (n < 2048) ? (Wk + (size_t)(n-1024)*1024)
                                : (Wv + (size_t)(n-2048)*1024);
  const float4 a = *(const float4*)(src + col4);
  ushort4 hi, lo;
  hi.x = f2bf(a.x); hi.y = f2bf(a.y); hi.z = f2bf(a.z); hi.w = f2bf(a.w);
  lo.x = f2bf(a.x - bf2f(hi.x)); lo.y = f2bf(a.y - bf2f(hi.y));
  lo.z = f2bf(a.z - bf2f(hi.z)); lo.w = f2bf(a.w - bf2f(hi.w));
  ushort* orow = out + (size_t)n*3072;
  *(ushort4*)(orow + col4)        = hi;
  *(ushort4*)(orow + 1024 + col4) = hi;
  *(ushort4*)(orow + 2048 + col4) = lo;
}

// ---------------- weight split [hi|hi|lo] single 1024-row weight (Wo) ------------
__global__ __launch_bounds__(256) void split_w1_kernel(const float* __restrict__ W,
                                                       ushort* __restrict__ out) {
  const int idx = blockIdx.x*256 + threadIdx.x;
  const int n = idx >> 8;
  const int col4 = (idx & 255) << 2;
  const float4 a = *(const float4*)(W + (size_t)n*1024 + col4);
  ushort4 hi, lo;
  hi.x = f2bf(a.x); hi.y = f2bf(a.y); hi.z = f2bf(a.z); hi.w = f2bf(a.w);
  lo.x = f2bf(a.x - bf2f(hi.x)); lo.y = f2bf(a.y - bf2f(hi.y));
  lo.z = f2bf(a.z - bf2f(hi.z)); lo.w = f2bf(a.w - bf2f(hi.w));
  ushort* orow = out + (size_t)n*3072;
  *(ushort4*)(orow + col4)        = hi;
  *(ushort4*)(orow + 1024 + col4) = hi;
  *(ushort4*)(orow + 2048 + col4) = lo;
}

// ---------------- plain fp32 -> bf16 convert ----------------
__global__ __launch_bounds__(256) void cvt_bf16_kernel(const float* __restrict__ in,
                                                       ushort* __restrict__ out,
                                                       int gprshift, int ostride, int ooff) {
  const int idx = blockIdx.x*256 + threadIdx.x;
  const int row = idx >> gprshift;
  const int col4 = (idx & ((1 << gprshift) - 1)) << 2;
  const int ncols = 4 << gprshift;
  const float4 a = *(const float4*)(in + (size_t)row*ncols + col4);
  ushort4 hi;
  hi.x = f2bf(a.x); hi.y = f2bf(a.y); hi.z = f2bf(a.z); hi.w = f2bf(a.w);
  *(ushort4*)(out + (size_t)row*ostride + ooff + col4) = hi;
}

__global__ __launch_bounds__(256) void bias_cat_kernel(const float* __restrict__ bq,
                                                       const float* __restrict__ bv,
                                                       float* __restrict__ out) {
  const int n = blockIdx.x*256 + threadIdx.x;
  out[n] = (n < 1024) ? bq[n] : (n < 2048) ? 0.f : bv[n-2048];
}

// ---------------- bf16 MFMA GEMM (proven round-2 version) ----------------
__global__ __launch_bounds__(256) void mfma_gemm(
    const ushort* __restrict__ A, const ushort* __restrict__ Bw,
    const float* __restrict__ bias, float* __restrict__ C,
    int K, int ldc) {
  __shared__ __align__(16) ushort As[128*40];
  __shared__ __align__(16) ushort Bs[128*40];
  const int tid = threadIdx.x;
  const int bm = blockIdx.y * 128, bn = blockIdx.x * 128;
  const int wave = tid >> 6, lane = tid & 63;
  const int wm = wave >> 1, wn = wave & 1;
  const int lm = lane & 15, q = lane >> 4;
  const int srow = tid >> 2;
  const int schunk = (tid & 3) << 3;

  f32x4 acc[4][4];
  #pragma unroll
  for (int i = 0; i < 4; i++)
    #pragma unroll
    for (int j = 0; j < 4; j++)
      acc[i][j] = (f32x4){0.f,0.f,0.f,0.f};

  const ushort* Ag = A + (size_t)(bm + srow)*K + schunk;
  const ushort* Bg = Bw + (size_t)(bn + srow)*K + schunk;
  const int aoff0 = (wm*64 + lm)*40 + q*8;
  const int boff0 = (wn*64 + lm)*40 + q*8;

  for (int k0 = 0; k0 < K; k0 += 32) {
    const float4 a0 = *(const float4*)(Ag + k0);
    const float4 a1 = *(const float4*)(Ag + (size_t)64*K + k0);
    const float4 b0 = *(const float4*)(Bg + k0);
    const float4 b1 = *(const float4*)(Bg + (size_t)64*K + k0);
    __syncthreads();
    *(float4*)&As[srow*40 + schunk]      = a0;
    *(float4*)&As[(srow+64)*40 + schunk] = a1;
    *(float4*)&Bs[srow*40 + schunk]      = b0;
    *(float4*)&Bs[(srow+64)*40 + schunk] = b1;
    __syncthreads();
    short8 af[4], bf[4];
    #pragma unroll
    for (int mt = 0; mt < 4; mt++) af[mt] = *(const short8*)&As[aoff0 + mt*640];
    #pragma unroll
    for (int nt = 0; nt < 4; nt++) bf[nt] = *(const short8*)&Bs[boff0 + nt*640];
    #pragma unroll
    for (int mt = 0; mt < 4; mt++)
      #pragma unroll
      for (int nt = 0; nt < 4; nt++)
        acc[mt][nt] = MFMA16(af[mt], bf[nt], acc[mt][nt]);
  }

  #pragma unroll
  for (int mt = 0; mt < 4; mt++) {
    #pragma unroll
    for (int nt = 0; nt < 4; nt++) {
      const int n = bn + wn*64 + nt*16 + lm;
      const float bb = bias ? bias[n] : 0.f;
      #pragma unroll
      for (int reg = 0; reg < 4; reg++) {
        const int m = bm + wm*64 + mt*16 + q*4 + reg;
        C[(size_t)m*ldc + n] = acc[mt][nt][reg] + bb;
      }
    }
  }
}

// ---------------- Q/K pre-split into [hi|lo] rows (128 cols) ----------------
__global__ __launch_bounds__(256) void qk_split_kernel(const float* __restrict__ QKV,
                                                       ushort* __restrict__ Qsp,
                                                       ushort* __restrict__ Ksp) {
  const int row = blockIdx.x;            // b*1024 + s
  const int b = row >> 10, s = row & 1023;
  const int t = threadIdx.x;
  const int h = t >> 4, c4 = (t & 15) * 4;
  const float* src = QKV + (size_t)row*3072 + h*64 + c4;
  const float4 qv = *(const float4*)src;
  const float4 kv = *(const float4*)(src + 1024);
  ushort4 qh, ql, kh, kl;
  qh.x=f2bf(qv.x); qh.y=f2bf(qv.y); qh.z=f2bf(qv.z); qh.w=f2bf(qv.w);
  ql.x=f2bf(qv.x-bf2f(qh.x)); ql.y=f2bf(qv.y-bf2f(qh.y));
  ql.z=f2bf(qv.z-bf2f(qh.z)); ql.w=f2bf(qv.w-bf2f(qh.w));
  kh.x=f2bf(kv.x); kh.y=f2bf(kv.y); kh.z=f2bf(kv.z); kh.w=f2bf(kv.w);
  kl.x=f2bf(kv.x-bf2f(kh.x)); kl.y=f2bf(kv.y-bf2f(kh.y));
  kl.z=f2bf(kv.z-bf2f(kh.z)); kl.w=f2bf(kv.w-bf2f(kh.w));
  ushort* qd = Qsp + ((size_t)(b*16 + h)*1024 + s)*128;
  ushort* kd = Ksp + ((size_t)(b*16 + h)*1024 + s)*128;
  *(ushort4*)(qd + c4)      = qh;
  *(ushort4*)(qd + 64 + c4) = ql;
  *(ushort4*)(kd + c4)      = kh;
  *(ushort4*)(kd + 64 + c4) = kl;
}

// ---------------- V transpose + split: Vth/Vtl[(bh)*64+d][s] ----------------
__global__ __launch_bounds__(256) void vt_split_kernel(const float* __restrict__ QKV,
                                                       ushort* __restrict__ Vth,
                                                       ushort* __restrict__ Vtl) {
  __shared__ float T[64][65];
  const int sc = blockIdx.x;             // 0..15 (s-chunk of 64)
  const int bh = blockIdx.y;             // 0..63
  const int b = bh >> 4, h = bh & 15;
  const int t = threadIdx.x;
  {
    const int r = t >> 2, c16 = (t & 3) * 16;
    const float* src = QKV + ((size_t)(b*1024 + sc*64 + r))*3072 + 2048 + h*64 + c16;
    #pragma unroll
    for (int j = 0; j < 4; j++)
      *(float4*)&T[r][c16 + j*4] = *(const float4*)(src + j*4);
  }
  __syncthreads();
  const int d = t >> 2, s16 = (t & 3) * 16;
  short8 h0, h1, l0, l1;
  #pragma unroll
  for (int j = 0; j < 8; j++) {
    float v = T[s16 + j][d];
    ushort hh = f2bf(v);
    h0[j] = (short)hh; l0[j] = (short)f2bf(v - bf2f(hh));
  }
  #pragma unroll
  for (int j = 0; j < 8; j++) {
    float v = T[s16 + 8 + j][d];
    ushort hh = f2bf(v);
    h1[j] = (short)hh; l1[j] = (short)f2bf(v - bf2f(hh));
  }
  const size_t off = ((size_t)bh*64 + d)*1024 + sc*64 + s16;
  *(short8*)(Vth + off)     = h0;
  *(short8*)(Vth + off + 8) = h1;
  *(short8*)(Vtl + off)     = l0;
  *(short8*)(Vtl + off + 8) = l1;
}

// ---------------- MFMA causal flash attention ----------------
// grid (8, 64): block pair handles q-tiles {15-bx, bx} of 64 rows (17 kt-units).
// Wave w owns 16 q-rows. Scores = QhKh+QlKh+QhKl; PV = PhVh+PlVh+PhVl.
// LDS: Kc (64x136 ushort) unioned with Pf (64x66 float); Vc separate. 34.8 KB.
__global__ __launch_bounds__(256) void gattn_mfma(
    const ushort* __restrict__ Qsp, const ushort* __restrict__ Ksp,
    const ushort* __restrict__ Vth, const ushort* __restrict__ Vtl,
    float* __restrict__ O) {
  __shared__ __align__(16) char su[64*136*2];   // max(Kc 17408 B, Pf 16896 B)
  __shared__ __align__(16) ushort Vc[64*136];
  ushort* Kc = (ushort*)su;
  float*  Pf = (float*)su;
  const int bh = blockIdx.y;
  const int b = bh >> 4, h = bh & 15;
  const int tid = threadIdx.x;
  const int w = tid >> 6, lane = tid & 63;
  const int lm = lane & 15, q = lane >> 4;
  const ushort* Qb_ = Qsp + (size_t)bh * (1024*128);
  const ushort* Kb_ = Ksp + (size_t)bh * (1024*128);
  const ushort* Vhb = Vth + (size_t)bh * (64*1024);
  const ushort* Vlb = Vtl + (size_t)bh * (64*1024);

  for (int half = 0; half < 2; ++half) {
    const int qt = half ? blockIdx.x : 15 - blockIdx.x;
    short8 qh[2], ql[2];
    {
      const ushort* qr = Qb_ + (size_t)(qt*64 + w*16 + lm)*128 + q*8;
      qh[0] = *(const short8*)(qr);
      qh[1] = *(const short8*)(qr + 32);
      ql[0] = *(const short8*)(qr + 64);
      ql[1] = *(const short8*)(qr + 96);
    }
    f32x4 of[4];
    float mst[4], lst[4];
    #pragma unroll
    for (int nt = 0; nt < 4; nt++) of[nt] = (f32x4){0.f,0.f,0.f,0.f};
    #pragma unroll
    for (int rm = 0; rm < 4; rm++) { mst[rm] = -INFINITY; lst[rm] = 0.f; }
    const int nkt = qt + 1;
    for (int kt = 0; kt < nkt; ++kt) {
      __syncthreads();                 // (A) prior iter's Pf/Vc reads done
      #pragma unroll
      for (int i = 0; i < 4; i++) {
        const int slot = i*256 + tid;  // 0..1023: 64 rows x 16 chunks of 8
        const int row = slot >> 4, c8 = slot & 15;
        *(float4*)&Kc[row*136 + c8*8] =
            *(const float4*)(Kb_ + (size_t)(kt*64 + row)*128 + c8*8);
        const ushort* vsrc = ((c8 < 8) ? Vhb : Vlb) + (size_t)row*1024 + kt*64 + (c8&7)*8;
        *(float4*)&Vc[row*136 + c8*8] = *(const float4*)vsrc;
      }
      __syncthreads();                 // (B) staging visible
      // ---- scores ----
      f32x4 sS[4];
      #pragma unroll
      for (int nt = 0; nt < 4; nt++) {
        const ushort* kr = &Kc[(nt*16 + lm)*136 + q*8];
        const short8 kh0 = *(const short8*)(kr);
        const short8 kh1 = *(const short8*)(kr + 32);
        const short8 kl0 = *(const short8*)(kr + 64);
        const short8 kl1 = *(const short8*)(kr + 96);
        f32x4 a = (f32x4){0.f,0.f,0.f,0.f};
        a = MFMA16(qh[0], kh0, a);
        a = MFMA16(ql[0], kh0, a);
        a = MFMA16(qh[0], kl0, a);
        a = MFMA16(qh[1], kh1, a);
        a = MFMA16(ql[1], kh1, a);
        a = MFMA16(qh[1], kl1, a);
        sS[nt] = a;
      }
      // ---- scale + causal mask + online softmax (fp32, C-layout) ----
      const int ktbase = kt*64;
      const int qrow0 = qt*64 + w*16 + q*4;
      #pragma unroll
      for (int rm = 0; rm < 4; rm++) {
        const int qrow = qrow0 + rm;
        float v[4];
        #pragma unroll
        for (int nt = 0; nt < 4; nt++) {
          const int kcol = ktbase + nt*16 + lm;
          const float x = sS[nt][rm]*0.125f;
          v[nt] = (kcol <= qrow) ? x : -INFINITY;
        }
        float tm = fmaxf(fmaxf(v[0],v[1]), fmaxf(v[2],v[3]));
        #pragma unroll
        for (int off = 1; off < 16; off <<= 1) tm = fmaxf(tm, __shfl_xor(tm, off, 64));
        const float nm = fmaxf(mst[rm], tm);
        const float alpha = __expf(mst[rm] - nm);
        float ps = 0.f;
        #pragma unroll
        for (int nt = 0; nt < 4; nt++) {
          float p = __expf(v[nt] - nm);
          sS[nt][rm] = p;
          ps += p;
        }
        #pragma unroll
        for (int off = 1; off < 16; off <<= 1) ps += __shfl_xor(ps, off, 64);
        lst[rm] = lst[rm]*alpha + ps;
        mst[rm] = nm;
        #pragma unroll
        for (int nt = 0; nt < 4; nt++) of[nt][rm] *= alpha;
      }
      __syncthreads();                 // (C) all Kc reads done; Pf may overwrite
      #pragma unroll
      for (int rm = 0; rm < 4; rm++)
        #pragma unroll
        for (int nt = 0; nt < 4; nt++)
          Pf[(w*16 + q*4 + rm)*66 + nt*16 + lm] = sS[nt][rm];
      __syncthreads();                 // (D) Pf visible
      // ---- reload P as A-frags, bf16 split ----
      short8 ph[2], pl[2];
      {
        const float* prow = &Pf[(w*16 + lm)*66];
        float pv[16];
        *(float4*)&pv[0]  = *(const float4*)(prow + q*8);
        *(float4*)&pv[4]  = *(const float4*)(prow + q*8 + 4);
        *(float4*)&pv[8]  = *(const float4*)(prow + 32 + q*8);
        *(float4*)&pv[12] = *(const float4*)(prow + 32 + q*8 + 4);
        split8(&pv[0], &ph[0], &pl[0]);
        split8(&pv[8], &ph[1], &pl[1]);
      }
      // ---- O += P V ----
      #pragma unroll
      for (int nt = 0; nt < 4; nt++) {
        const ushort* vr = &Vc[(nt*16 + lm)*136 + q*8];
        const short8 vh0 = *(const short8*)(vr);
        const short8 vh1 = *(const short8*)(vr + 32);
        const short8 vl0 = *(const short8*)(vr + 64);
        const short8 vl1 = *(const short8*)(vr + 96);
        f32x4 a = of[nt];
        a = MFMA16(ph[0], vh0, a);
        a = MFMA16(pl[0], vh0, a);
        a = MFMA16(ph[0], vl0, a);
        a = MFMA16(ph[1], vh1, a);
        a = MFMA16(pl[1], vh1, a);
        a = MFMA16(ph[1], vl1, a);
        of[nt] = a;
      }
    }
    // ---- epilogue ----
    #pragma unroll
    for (int rm = 0; rm < 4; rm++) {
      const float inv = 1.0f / lst[rm];
      const int s = qt*64 + w*16 + q*4 + rm;
      float* orow = O + ((size_t)(b*1024 + s))*1024 + h*64;
      #pragma unroll
      for (int nt = 0; nt < 4; nt++)
        orow[nt*16 + lm] = of[nt][rm] * inv;
    }
  }
}

// ---------------- seq-mean over S ----------------
__global__ __launch_bounds__(256) void seqmean_kernel(const float* __restrict__ g,
                                                      float* __restrict__ mbd) {
  const int b = blockIdx.y;
  const int d = blockIdx.x*256 + threadIdx.x;
  const float* p = g + (size_t)b*S_*D_ + d;
  float s0=0.f,s1=0.f,s2=0.f,s3=0.f;
  for (int s = 0; s < S_; s += 4) {
    s0 += p[(size_t)(s+0)*D_];
    s1 += p[(size_t)(s+1)*D_];
    s2 += p[(size_t)(s+2)*D_];
    s3 += p[(size_t)(s+3)*D_];
  }
  mbd[b*D_ + d] = (s0+s1+s2+s3)*(1.0f/S_);
}

// ---------------- predictor ----------------
__global__ __launch_bounds__(256) void predictor_kernel(
    const float* __restrict__ mbd, const float* __restrict__ Wp,
    const float* __restrict__ bp, float* __restrict__ fpar, int* __restrict__ ipar) {
  __shared__ float sbuf[4];
  __shared__ float sdots[4];
  const int tid = threadIdx.x;
  for (int b = 0; b < 4; b++) {
    float psum = 0.f;
    for (int d = tid; d < D_; d += 256) psum += mbd[b*D_ + d]*Wp[d];
    float tot = block_reduce_sum_256(psum, sbuf);
    if (tid == 0) sdots[b] = tot;
  }
  __syncthreads();
  if (tid == 0) {
    float smv = 0.f;
    for (int b = 0; b < 4; b++) {
      float z = sdots[b] + bp[0];
      smv += 1.0f/(1.0f + expf(-z));
    }
    smv *= 0.25f;
    int win = max(1, (int)(256.0f*smv));
    int span_len = max(1, (int)(512.0f*smv));
    int local_max = min(512, min(span_len, win));
    float temp = 1.0f + 0.01f*(1.0f - smv);
    int n_win = (S_ + win - 1)/win;
    fpar[0] = smv; fpar[1] = temp;
    ipar[0] = win; ipar[1] = span_len; ipar[2] = local_max; ipar[3] = n_win;
  }
}

// ---------------- dynamic sliding-window span attention (fp32 -> bf16 out) -------
#define LDP 68
__global__ __launch_bounds__(256) void lattn_kernel(
    const float* __restrict__ Lc, ushort* __restrict__ Out,
    const int* __restrict__ ip, const float* __restrict__ fpp) {
  __shared__ __align__(16) float Qs[HD_][LDP];
  __shared__ __align__(16) float KPs[64][LDP];
  __shared__ __align__(16) float Vs[64][LDP];
  const int n_win = ip[3];
  const int win = ip[0], span_len = ip[1], local_max = ip[2];
  const float sm = fpp[0], temp = fpp[1];
  const int bh = blockIdx.y;
  const int b = bh >> 4, h = bh & 15;
  const int tid = threadIdx.x;
  const int tx = tid & 15, ty = tid >> 4;
  const float sc = 0.35355339059327373f / temp;
  for (int w = blockIdx.x; w < n_win; w += gridDim.x) {
    const int st = w * win;
    const int en = min(st + win, S_); const int wlen = en - st;
    const int ks = max(0, st - span_len + win);
    const int ke = min(st + span_len, S_); const int klen = ke - ks;
    int eff = (int)((double)wlen * (double)sm);
    eff = min(min(eff, wlen), min(klen, local_max));
    if (eff <= 0) continue;
    const int nt = (eff + 63) >> 6;
    for (int qt = 0; qt < nt; ++qt) {
      const int qn = min(64, eff - qt*64);
      __syncthreads();
      #pragma unroll
      for (int c = 0; c < 4; c++) {
        int f = tid + c*256;
        int r = f >> 4;
        int dc = (f & 15) << 2;
        float4 q4 = make_float4(0.f,0.f,0.f,0.f);
        if (r < qn) q4 = *(const float4*)(Lc + ((size_t)(b*S_ + st + qt*64 + r)) * D_ + h*HD_ + dc);
        Qs[dc+0][r]=q4.x; Qs[dc+1][r]=q4.y; Qs[dc+2][r]=q4.z; Qs[dc+3][r]=q4.w;
      }
      float o[4][4] = {{0.f,0.f,0.f,0.f},{0.f,0.f,0.f,0.f},{0.f,0.f,0.f,0.f},{0.f,0.f,0.f,0.f}};
      float mrow[4], lrow[4];
      #pragma unroll
      for (int i=0;i<4;i++){ mrow[i] = -INFINITY; lrow[i] = 0.f; }
      for (int kt = 0; kt < nt; ++kt) {
        const int kn = min(64, eff - kt*64);
        __syncthreads();
        #pragma unroll
        for (int c = 0; c < 4; c++) {
          int f = tid + c*256;
          int r = f >> 4;
          int dc = (f & 15) << 2;
          float4 k4 = make_float4(0.f,0.f,0.f,0.f);
          if (r < kn) k4 = *(const float4*)(Lc + ((size_t)(b*S_ + ks + kt*64 + r)) * D_ + h*HD_ + dc);
          KPs[dc+0][r]=k4.x; KPs[dc+1][r]=k4.y; KPs[dc+2][r]=k4.z; KPs[dc+3][r]=k4.w;
          *(float4*)&Vs[r][dc] = k4;
        }
        __syncthreads();
        float s[4][4] = {{0.f,0.f,0.f,0.f},{0.f,0.f,0.f,0.f},{0.f,0.f,0.f,0.f},{0.f,0.f,0.f,0.f}};
        #pragma unroll 8
        for (int d = 0; d < HD_; ++d) {
          const float4 a  = *(const float4*)&Qs[d][ty*4];
          const float4 bb = *(const float4*)&KPs[d][tx*4];
          const float av[4]={a.x,a.y,a.z,a.w};
          const float bv[4]={bb.x,bb.y,bb.z,bb.w};
          #pragma unroll
          for (int i=0;i<4;i++)
            #pragma unroll
            for (int j=0;j<4;j++)
              s[i][j] += av[i]*bv[j];
        }
        #pragma unroll
        for (int i=0;i<4;i++) {
          #pragma unroll
          for (int j=0;j<4;j++) {
            float lg = s[i][j]*sc;
            if (kt*64 + tx*4 + j >= eff) lg = -INFINITY;
            s[i][j] = lg;
          }
        }
        #pragma unroll
        for (int i=0;i<4;i++) {
          float tm = fmaxf(fmaxf(s[i][0],s[i][1]), fmaxf(s[i][2],s[i][3]));
          #pragma unroll
          for (int off=1; off<16; off<<=1) tm = fmaxf(tm, __shfl_xor(tm, off, 64));
          const float nm = fmaxf(mrow[i], tm);
          const float alpha = __expf(mrow[i]-nm);
          float ps = 0.f;
          #pragma unroll
          for (int j=0;j<4;j++){ float p = __expf(s[i][j]-nm); s[i][j]=p; ps += p; }
          #pragma unroll
          for (int off=1; off<16; off<<=1) ps += __shfl_xor(ps, off, 64);
          lrow[i] = lrow[i]*alpha + ps;
          mrow[i] = nm;
          #pragma unroll
          for (int j=0;j<4;j++) o[i][j] *= alpha;
        }
        __syncthreads();
        #pragma unroll
        for (int i=0;i<4;i++)
          #pragma unroll
          for (int j=0;j<4;j++)
            KPs[tx*4+j][ty*4+i] = s[i][j];
        __syncthreads();
        #pragma unroll 8
        for (int kk = 0; kk < 64; ++kk) {
          const float4 a  = *(const float4*)&KPs[kk][ty*4];
          const float4 bb = *(const float4*)&Vs[kk][tx*4];
          const float av[4]={a.x,a.y,a.z,a.w};
          const float bv[4]={bb.x,bb.y,bb.z,bb.w};
          #pragma unroll
          for (int i=0;i<4;i++)
            #pragma unroll
            for (int j=0;j<4;j++)
              o[i][j] += av[i]*bv[j];
        }
      }
      #pragma unroll
      for (int i=0;i<4;i++){
        const int r = ty*4 + i;
        if (r < qn) {
          const float inv = 1.0f / lrow[i];
          ushort4 ov;
          ov.x = f2bf(o[i][0]*inv); ov.y = f2bf(o[i][1]*inv);
          ov.z = f2bf(o[i][2]*inv); ov.w = f2bf(o[i][3]*inv);
          *(ushort4*)(Out + ((size_t)(b*S_ + st + qt*64 + r)) * 2048 + h*HD_ + tx*4) = ov;
        }
      }
    }
  }
}

// ---------------- launch ----------------
extern "C" void kernel_launch(void* const* d_in, const int* in_sizes, int n_in,
                              void* d_out, int out_size, void* d_ws, size_t ws_size,
                              hipStream_t stream) {
  const float* x      = (const float*)d_in[0];
  const float* ln_a_g = (const float*)d_in[1];
  const float* ln_a_b = (const float*)d_in[2];
  const float* ln_b_g = (const float*)d_in[3];
  const float* ln_b_b = (const float*)d_in[4];
  const float* Wq     = (const float*)d_in[5];
  const float* bq     = (const float*)d_in[6];
  const float* Wk     = (const float*)d_in[7];
  const float* Wv     = (const float*)d_in[8];
  const float* bv     = (const float*)d_in[9];
  const float* Wo     = (const float*)d_in[10];
  const float* bo     = (const float*)d_in[11];
  const float* Wp     = (const float*)d_in[12];
  const float* bp     = (const float*)d_in[13];
  const float* Wproj  = (const float*)d_in[14];
  const float* bproj  = (const float*)d_in[15];
  float* out = (float*)d_out;
  float* ws  = (float*)d_ws;

  // float-offset layout (~151 MB):
  float* QKVf = ws;                          // [4096,3072] fp32; later A3/B3 bf16 overlay
  float* buf0 = ws + 12582912;               // [4096,1024] attn out
  float* glo  = ws + 16777216;               // [4096,1024] globe_out
  float* loc  = ws + 20971520;               // [4096,1024] LN_a out; earlier Vth/Vtl overlay
  float* biascat = ws + 25165824;            // [3072]
  float* mbd  = biascat + 4096;
  float* fpar = mbd + 4096;
  int*   ipar = (int*)(fpar + 8);
  ushort* Acat  = (ushort*)(ws + 25182208);  // [4096,3072] bf16; later Qsp overlay
  ushort* Bqkv  = Acat + 12582912;           // [3072,3072] bf16; later Ksp overlay
  ushort* Bo    = Bqkv + 9437184;            // [1024,3072] bf16
  // overlays:
  ushort* Qsp = Acat;                        // [64*1024,128] bf16 (16.8 MB < Acat)
  ushort* Ksp = Bqkv;                        // [64*1024,128] bf16 (16.8 MB ... fits Bqkv+partial? no: 8.4M ushorts < 9.4M Bqkv) 
  ushort* Vth = (ushort*)loc;                // [64*64,1024] bf16 (8 MB)
  ushort* Vtl = Vth + 4194304;               // [64*64,1024] bf16 (8 MB)
  ushort* A3  = (ushort*)ws;                 // [4096,2048] bf16
  ushort* B3  = A3 + 8388608;                // [1024,2048] bf16

  const dim3 blk(256);

  // 1) LN_b(x) fused with bf16x3 split -> Acat
  ln_split_kernel<<<dim3(B_*S_), blk, 0, stream>>>(x, ln_b_g, ln_b_b, Acat);
  // 2) weight split + bias concat
  split_w3_kernel<<<dim3(3072), blk, 0, stream>>>(Wq, Wk, Wv, Bqkv);
  bias_cat_kernel<<<dim3(12), blk, 0, stream>>>(bq, bv, biascat);
  // 3) QKV = Acat · Bqkv^T + biascat
  mfma_gemm<<<dim3(24, 32), blk, 0, stream>>>(Acat, Bqkv, biascat, QKVf, 3072, 3072);
  // 4) attention pre-splits (QKVf -> Qsp/Ksp/Vth/Vtl; overlay dead Acat/Bqkv/loc)
  qk_split_kernel<<<dim3(4096), blk, 0, stream>>>(QKVf, Qsp, Ksp);
  vt_split_kernel<<<dim3(16, 64), blk, 0, stream>>>(QKVf, Vth, Vtl);
  // 5) MFMA causal attention -> buf0
  gattn_mfma<<<dim3(8, 64), blk, 0, stream>>>(Qsp, Ksp, Vth, Vtl, buf0);
  // 6) globe_out = attn · Wo^T + bo (bf16x3)
  split_act_kernel<<<dim3(4096), blk, 0, stream>>>(buf0, Acat);
  split_w1_kernel<<<dim3(1024), blk, 0, stream>>>(Wo, Bo);
  mfma_gemm<<<dim3(8, 32), blk, 0, stream>>>(Acat, Bo, bo, glo, 3072, 1024);
  // 7) predictor (device-side)
  seqmean_kernel<<<dim3(4, B_), blk, 0, stream>>>(glo, mbd);
  predictor_kernel<<<dim3(1), blk, 0, stream>>>(mbd, Wp, bp, fpar, ipar);
  // 8) local = LN_a(x) -> loc (Vth/Vtl dead now)
  ln_kernel<<<dim3(B_*S_), blk, 0, stream>>>(x, ln_a_g, ln_a_b, loc);
  // 9) local attention -> A3[:, 0:1024] bf16 (QKVf dead)
  hipMemsetAsync(A3, 0, (size_t)4096*2048*2, stream);
  lattn_kernel<<<dim3(64, B_*H_), blk, 0, stream>>>(loc, A3, ipar, fpar);
  // 10) A3[:, 1024:2048] = bf16(globe_out); B3 = bf16(Wproj)
  cvt_bf16_kernel<<<dim3(4096), blk, 0, stream>>>(glo, A3, 8, 2048, 1024);
  cvt_bf16_kernel<<<dim3(2048), blk, 0, stream>>>(Wproj, B3, 9, 2048, 0);
  // 11) out = A3 · B3^T + bproj
  mfma_gemm<<<dim3(8, 32), blk, 0, stream>>>(A3, B3, bproj, out, 2048, 1024);
}

// Round 5
// 514.461 us; speedup vs baseline: 2.5044x; 1.2258x over previous
//
#include <hip/hip_runtime.h>
#include <math.h>

#define B_ 4
#define S_ 1024
#define D_ 1024
#define H_ 16
#define HD_ 64
#define BSD_ (B_*S_*D_)

using short8 = __attribute__((ext_vector_type(8))) short;
using f32x4  = __attribute__((ext_vector_type(4))) float;

#define MFMA16(a,b,c) __builtin_amdgcn_mfma_f32_16x16x32_bf16((a),(b),(c),0,0,0)

// ---------------- bf16 helpers (RNE) ----------------
__device__ __forceinline__ ushort f2bf(float f) {
  uint u = __float_as_uint(f);
  return (ushort)((u + 0x7fffu + ((u >> 16) & 1u)) >> 16);
}
__device__ __forceinline__ float bf2f(ushort h) {
  return __uint_as_float(((uint)h) << 16);
}
__device__ __forceinline__ void split8(const float* p, short8* hi, short8* lo) {
  #pragma unroll
  for (int j = 0; j < 8; j++) {
    ushort h = f2bf(p[j]);
    (*hi)[j] = (short)h;
    (*lo)[j] = (short)f2bf(p[j] - bf2f(h));
  }
}
// async global->LDS, 16B per lane; LDS dest = wave-uniform base + lane*16
__device__ __forceinline__ void async_load16(const ushort* g, ushort* l) {
  __builtin_amdgcn_global_load_lds(
      (const __attribute__((address_space(1))) unsigned int*)g,
      (__attribute__((address_space(3))) unsigned int*)l, 16, 0, 0);
}

// ---------------- block reduce (256 threads = 4 waves) ----------------
__device__ __forceinline__ float block_reduce_sum_256(float v, float* sbuf) {
  #pragma unroll
  for (int off = 32; off > 0; off >>= 1) v += __shfl_xor(v, off, 64);
  int lane = threadIdx.x & 63, wid = threadIdx.x >> 6;
  __syncthreads();
  if (lane == 0) sbuf[wid] = v;
  __syncthreads();
  return sbuf[0] + sbuf[1] + sbuf[2] + sbuf[3];
}

// ---------------- LayerNorm (fp32 out) ----------------
__global__ __launch_bounds__(256) void ln_kernel(const float* __restrict__ x,
                                                 const float* __restrict__ g,
                                                 const float* __restrict__ bta,
                                                 float* __restrict__ out) {
  __shared__ float sbuf[4];
  const int row = blockIdx.x;
  const float* xr = x + (size_t)row * D_;
  const int t = threadIdx.x;
  float v[4]; float s = 0.f;
  #pragma unroll
  for (int i = 0; i < 4; i++) { v[i] = xr[t + 256*i]; s += v[i]; }
  const float mean = block_reduce_sum_256(s, sbuf) * (1.0f/D_);
  float sq = 0.f;
  #pragma unroll
  for (int i = 0; i < 4; i++) { float d = v[i]-mean; sq += d*d; }
  const float var = block_reduce_sum_256(sq, sbuf) * (1.0f/D_);
  const float r = rsqrtf(var + 1e-5f);
  float* orow = out + (size_t)row * D_;
  #pragma unroll
  for (int i = 0; i < 4; i++) {
    int c = t + 256*i;
    orow[c] = (v[i]-mean)*r*g[c] + bta[c];
  }
}

// ---------------- fused LayerNorm + bf16x3 act-split ([hi|lo|hi]) ----------------
__global__ __launch_bounds__(256) void ln_split_kernel(const float* __restrict__ x,
                                                       const float* __restrict__ g,
                                                       const float* __restrict__ bta,
                                                       ushort* __restrict__ out) {
  __shared__ float sbuf[4];
  const int row = blockIdx.x;
  const int t = threadIdx.x;
  const int c = t*4;
  const float* xr = x + (size_t)row * D_;
  float4 v = *(const float4*)(xr + c);
  float s = v.x + v.y + v.z + v.w;
  const float mean = block_reduce_sum_256(s, sbuf) * (1.0f/D_);
  float4 dv = make_float4(v.x-mean, v.y-mean, v.z-mean, v.w-mean);
  float sq = dv.x*dv.x + dv.y*dv.y + dv.z*dv.z + dv.w*dv.w;
  const float var = block_reduce_sum_256(sq, sbuf) * (1.0f/D_);
  const float r = rsqrtf(var + 1e-5f);
  float4 gg = *(const float4*)(g + c);
  float4 bb = *(const float4*)(bta + c);
  float n[4];
  n[0] = dv.x*r*gg.x + bb.x; n[1] = dv.y*r*gg.y + bb.y;
  n[2] = dv.z*r*gg.z + bb.z; n[3] = dv.w*r*gg.w + bb.w;
  ushort4 hi, lo;
  hi.x = f2bf(n[0]); hi.y = f2bf(n[1]); hi.z = f2bf(n[2]); hi.w = f2bf(n[3]);
  lo.x = f2bf(n[0]-bf2f(hi.x)); lo.y = f2bf(n[1]-bf2f(hi.y));
  lo.z = f2bf(n[2]-bf2f(hi.z)); lo.w = f2bf(n[3]-bf2f(hi.w));
  ushort* orow = out + (size_t)row*3072;
  *(ushort4*)(orow + c)        = hi;
  *(ushort4*)(orow + 1024 + c) = lo;
  *(ushort4*)(orow + 2048 + c) = hi;
}

// ---------------- act split [hi|lo|hi] from fp32 ----------------
__global__ __launch_bounds__(256) void split_act_kernel(const float* __restrict__ in,
                                                        ushort* __restrict__ out) {
  const int idx = blockIdx.x*256 + threadIdx.x;
  const int row = idx >> 8;
  const int col4 = (idx & 255) << 2;
  const float4 a = *(const float4*)(in + (size_t)row*1024 + col4);
  ushort4 hi, lo;
  hi.x = f2bf(a.x); hi.y = f2bf(a.y); hi.z = f2bf(a.z); hi.w = f2bf(a.w);
  lo.x = f2bf(a.x - bf2f(hi.x)); lo.y = f2bf(a.y - bf2f(hi.y));
  lo.z = f2bf(a.z - bf2f(hi.z)); lo.w = f2bf(a.w - bf2f(hi.w));
  ushort* orow = out + (size_t)row*3072;
  *(ushort4*)(orow + col4)        = hi;
  *(ushort4*)(orow + 1024 + col4) = lo;
  *(ushort4*)(orow + 2048 + col4) = hi;
}

// ---------------- weight split [hi|hi|lo] for Wq/Wk/Wv stacked (3072 rows) -------
__global__ __launch_bounds__(256) void split_w3_kernel(const float* __restrict__ Wq,
                                                       const float* __restrict__ Wk,
                                                       const float* __restrict__ Wv,
                                                       ushort* __restrict__ out) {
  const int idx = blockIdx.x*256 + threadIdx.x;
  const int n = idx >> 8;
  const int col4 = (idx & 255) << 2;
  const float* src = (n < 1024) ? (Wq + (size_t)n*1024)
                   : (n < 2048) ? (Wk + (size_t)(n-1024)*1024)
                                : (Wv + (size_t)(n-2048)*1024);
  const float4 a = *(const float4*)(src + col4);
  ushort4 hi, lo;
  hi.x = f2bf(a.x); hi.y = f2bf(a.y); hi.z = f2bf(a.z); hi.w = f2bf(a.w);
  lo.x = f2bf(a.x - bf2f(hi.x)); lo.y = f2bf(a.y - bf2f(hi.y));
  lo.z = f2bf(a.z - bf2f(hi.z)); lo.w = f2bf(a.w - bf2f(hi.w));
  ushort* orow = out + (size_t)n*3072;
  *(ushort4*)(orow + col4)        = hi;
  *(ushort4*)(orow + 1024 + col4) = hi;
  *(ushort4*)(orow + 2048 + col4) = lo;
}

// ---------------- weight split [hi|hi|lo] single 1024-row weight (Wo) ------------
__global__ __launch_bounds__(256) void split_w1_kernel(const float* __restrict__ W,
                                                       ushort* __restrict__ out) {
  const int idx = blockIdx.x*256 + threadIdx.x;
  const int n = idx >> 8;
  const int col4 = (idx & 255) << 2;
  const float4 a = *(const float4*)(W + (size_t)n*1024 + col4);
  ushort4 hi, lo;
  hi.x = f2bf(a.x); hi.y = f2bf(a.y); hi.z = f2bf(a.z); hi.w = f2bf(a.w);
  lo.x = f2bf(a.x - bf2f(hi.x)); lo.y = f2bf(a.y - bf2f(hi.y));
  lo.z = f2bf(a.z - bf2f(hi.z)); lo.w = f2bf(a.w - bf2f(hi.w));
  ushort* orow = out + (size_t)n*3072;
  *(ushort4*)(orow + col4)        = hi;
  *(ushort4*)(orow + 1024 + col4) = hi;
  *(ushort4*)(orow + 2048 + col4) = lo;
}

// ---------------- plain fp32 -> bf16 convert ----------------
__global__ __launch_bounds__(256) void cvt_bf16_kernel(const float* __restrict__ in,
                                                       ushort* __restrict__ out,
                                                       int gprshift, int ostride, int ooff) {
  const int idx = blockIdx.x*256 + threadIdx.x;
  const int row = idx >> gprshift;
  const int col4 = (idx & ((1 << gprshift) - 1)) << 2;
  const int ncols = 4 << gprshift;
  const float4 a = *(const float4*)(in + (size_t)row*ncols + col4);
  ushort4 hi;
  hi.x = f2bf(a.x); hi.y = f2bf(a.y); hi.z = f2bf(a.z); hi.w = f2bf(a.w);
  *(ushort4*)(out + (size_t)row*ostride + ooff + col4) = hi;
}

__global__ __launch_bounds__(256) void bias_cat_kernel(const float* __restrict__ bq,
                                                       const float* __restrict__ bv,
                                                       float* __restrict__ out) {
  const int n = blockIdx.x*256 + threadIdx.x;
  out[n] = (n < 1024) ? bq[n] : (n < 2048) ? 0.f : bv[n-2048];
}

// ---------------- bf16 MFMA GEMM, m97-style async staging ----------------
// 128x128 tile, BK=32. Unpadded LDS rows (64 B); global_load_lds width=16:
// lane i -> LDS base + i*16 B == row (i>>2), chunk (i&3) — exactly our layout.
__global__ __launch_bounds__(256) void mfma_gemm(
    const ushort* __restrict__ A, const ushort* __restrict__ Bw,
    const float* __restrict__ bias, float* __restrict__ C,
    int K, int ldc) {
  __shared__ __align__(16) ushort As[128*32];
  __shared__ __align__(16) ushort Bs[128*32];
  const int tid = threadIdx.x;
  const int bm = blockIdx.y * 128, bn = blockIdx.x * 128;
  const int wave = tid >> 6, lane = tid & 63;
  const int wm = wave >> 1, wn = wave & 1;
  const int lm = lane & 15, q = lane >> 4;
  const int lrow = lane >> 2;          // 0..15
  const int lch  = (lane & 3) << 3;    // ushort offset 0,8,16,24

  f32x4 acc[4][4];
  #pragma unroll
  for (int i = 0; i < 4; i++)
    #pragma unroll
    for (int j = 0; j < 4; j++)
      acc[i][j] = (f32x4){0.f,0.f,0.f,0.f};

  const ushort* Ar0 = A  + (size_t)(bm + wave*32 + lrow)*K + lch;
  const ushort* Ar1 = A  + (size_t)(bm + wave*32 + 16 + lrow)*K + lch;
  const ushort* Br0 = Bw + (size_t)(bn + wave*32 + lrow)*K + lch;
  const ushort* Br1 = Bw + (size_t)(bn + wave*32 + 16 + lrow)*K + lch;
  ushort* AsD0 = &As[(wave*32)*32];
  ushort* AsD1 = &As[(wave*32 + 16)*32];
  ushort* BsD0 = &Bs[(wave*32)*32];
  ushort* BsD1 = &Bs[(wave*32 + 16)*32];
  const int aoff0 = (wm*64 + lm)*32 + q*8;
  const int boff0 = (wn*64 + lm)*32 + q*8;

  for (int k0 = 0; k0 < K; k0 += 32) {
    __syncthreads();                    // prior tile's frag reads done
    async_load16(Ar0 + k0, AsD0);
    async_load16(Ar1 + k0, AsD1);
    async_load16(Br0 + k0, BsD0);
    async_load16(Br1 + k0, BsD1);
    __syncthreads();                    // vmcnt drained; staging visible
    short8 af[4], bf[4];
    #pragma unroll
    for (int mt = 0; mt < 4; mt++) af[mt] = *(const short8*)&As[aoff0 + mt*512];
    #pragma unroll
    for (int nt = 0; nt < 4; nt++) bf[nt] = *(const short8*)&Bs[boff0 + nt*512];
    #pragma unroll
    for (int mt = 0; mt < 4; mt++)
      #pragma unroll
      for (int nt = 0; nt < 4; nt++)
        acc[mt][nt] = MFMA16(af[mt], bf[nt], acc[mt][nt]);
  }

  #pragma unroll
  for (int mt = 0; mt < 4; mt++) {
    #pragma unroll
    for (int nt = 0; nt < 4; nt++) {
      const int n = bn + wn*64 + nt*16 + lm;
      const float bb = bias ? bias[n] : 0.f;
      #pragma unroll
      for (int reg = 0; reg < 4; reg++) {
        const int m = bm + wm*64 + mt*16 + q*4 + reg;
        C[(size_t)m*ldc + n] = acc[mt][nt][reg] + bb;
      }
    }
  }
}

// ---------------- Q/K pre-split into [hi|lo] rows (128 cols) ----------------
__global__ __launch_bounds__(256) void qk_split_kernel(const float* __restrict__ QKV,
                                                       ushort* __restrict__ Qsp,
                                                       ushort* __restrict__ Ksp) {
  const int row = blockIdx.x;            // b*1024 + s
  const int b = row >> 10, s = row & 1023;
  const int t = threadIdx.x;
  const int h = t >> 4, c4 = (t & 15) * 4;
  const float* src = QKV + (size_t)row*3072 + h*64 + c4;
  const float4 qv = *(const float4*)src;
  const float4 kv = *(const float4*)(src + 1024);
  ushort4 qh, ql, kh, kl;
  qh.x=f2bf(qv.x); qh.y=f2bf(qv.y); qh.z=f2bf(qv.z); qh.w=f2bf(qv.w);
  ql.x=f2bf(qv.x-bf2f(qh.x)); ql.y=f2bf(qv.y-bf2f(qh.y));
  ql.z=f2bf(qv.z-bf2f(qh.z)); ql.w=f2bf(qv.w-bf2f(qh.w));
  kh.x=f2bf(kv.x); kh.y=f2bf(kv.y); kh.z=f2bf(kv.z); kh.w=f2bf(kv.w);
  kl.x=f2bf(kv.x-bf2f(kh.x)); kl.y=f2bf(kv.y-bf2f(kh.y));
  kl.z=f2bf(kv.z-bf2f(kh.z)); kl.w=f2bf(kv.w-bf2f(kh.w));
  ushort* qd = Qsp + ((size_t)(b*16 + h)*1024 + s)*128;
  ushort* kd = Ksp + ((size_t)(b*16 + h)*1024 + s)*128;
  *(ushort4*)(qd + c4)      = qh;
  *(ushort4*)(qd + 64 + c4) = ql;
  *(ushort4*)(kd + c4)      = kh;
  *(ushort4*)(kd + 64 + c4) = kl;
}

// ---------------- V transpose + split: Vth/Vtl[(bh)*64+d][s] ----------------
__global__ __launch_bounds__(256) void vt_split_kernel(const float* __restrict__ QKV,
                                                       ushort* __restrict__ Vth,
                                                       ushort* __restrict__ Vtl) {
  __shared__ float T[64][65];
  const int sc = blockIdx.x;             // 0..15 (s-chunk of 64)
  const int bh = blockIdx.y;             // 0..63
  const int b = bh >> 4, h = bh & 15;
  const int t = threadIdx.x;
  {
    const int r = t >> 2, c16 = (t & 3) * 16;
    const float* src = QKV + ((size_t)(b*1024 + sc*64 + r))*3072 + 2048 + h*64 + c16;
    #pragma unroll
    for (int j = 0; j < 4; j++)
      *(float4*)&T[r][c16 + j*4] = *(const float4*)(src + j*4);
  }
  __syncthreads();
  const int d = t >> 2, s16 = (t & 3) * 16;
  short8 h0, h1, l0, l1;
  #pragma unroll
  for (int j = 0; j < 8; j++) {
    float v = T[s16 + j][d];
    ushort hh = f2bf(v);
    h0[j] = (short)hh; l0[j] = (short)f2bf(v - bf2f(hh));
  }
  #pragma unroll
  for (int j = 0; j < 8; j++) {
    float v = T[s16 + 8 + j][d];
    ushort hh = f2bf(v);
    h1[j] = (short)hh; l1[j] = (short)f2bf(v - bf2f(hh));
  }
  const size_t off = ((size_t)bh*64 + d)*1024 + sc*64 + s16;
  *(short8*)(Vth + off)     = h0;
  *(short8*)(Vth + off + 8) = h1;
  *(short8*)(Vtl + off)     = l0;
  *(short8*)(Vtl + off + 8) = l1;
}

// ---------------- MFMA causal flash attention (proven round-4 version) -----------
__global__ __launch_bounds__(256) void gattn_mfma(
    const ushort* __restrict__ Qsp, const ushort* __restrict__ Ksp,
    const ushort* __restrict__ Vth, const ushort* __restrict__ Vtl,
    float* __restrict__ O) {
  __shared__ __align__(16) char su[64*136*2];   // max(Kc 17408 B, Pf 16896 B)
  __shared__ __align__(16) ushort Vc[64*136];
  ushort* Kc = (ushort*)su;
  float*  Pf = (float*)su;
  const int bh = blockIdx.y;
  const int b = bh >> 4, h = bh & 15;
  const int tid = threadIdx.x;
  const int w = tid >> 6, lane = tid & 63;
  const int lm = lane & 15, q = lane >> 4;
  const ushort* Qb_ = Qsp + (size_t)bh * (1024*128);
  const ushort* Kb_ = Ksp + (size_t)bh * (1024*128);
  const ushort* Vhb = Vth + (size_t)bh * (64*1024);
  const ushort* Vlb = Vtl + (size_t)bh * (64*1024);

  for (int half = 0; half < 2; ++half) {
    const int qt = half ? blockIdx.x : 15 - blockIdx.x;
    short8 qh[2], ql[2];
    {
      const ushort* qr = Qb_ + (size_t)(qt*64 + w*16 + lm)*128 + q*8;
      qh[0] = *(const short8*)(qr);
      qh[1] = *(const short8*)(qr + 32);
      ql[0] = *(const short8*)(qr + 64);
      ql[1] = *(const short8*)(qr + 96);
    }
    f32x4 of[4];
    float mst[4], lst[4];
    #pragma unroll
    for (int nt = 0; nt < 4; nt++) of[nt] = (f32x4){0.f,0.f,0.f,0.f};
    #pragma unroll
    for (int rm = 0; rm < 4; rm++) { mst[rm] = -INFINITY; lst[rm] = 0.f; }
    const int nkt = qt + 1;
    for (int kt = 0; kt < nkt; ++kt) {
      __syncthreads();                 // (A) prior iter's Pf/Vc reads done
      #pragma unroll
      for (int i = 0; i < 4; i++) {
        const int slot = i*256 + tid;  // 0..1023: 64 rows x 16 chunks of 8
        const int row = slot >> 4, c8 = slot & 15;
        *(float4*)&Kc[row*136 + c8*8] =
            *(const float4*)(Kb_ + (size_t)(kt*64 + row)*128 + c8*8);
        const ushort* vsrc = ((c8 < 8) ? Vhb : Vlb) + (size_t)row*1024 + kt*64 + (c8&7)*8;
        *(float4*)&Vc[row*136 + c8*8] = *(const float4*)vsrc;
      }
      __syncthreads();                 // (B) staging visible
      f32x4 sS[4];
      #pragma unroll
      for (int nt = 0; nt < 4; nt++) {
        const ushort* kr = &Kc[(nt*16 + lm)*136 + q*8];
        const short8 kh0 = *(const short8*)(kr);
        const short8 kh1 = *(const short8*)(kr + 32);
        const short8 kl0 = *(const short8*)(kr + 64);
        const short8 kl1 = *(const short8*)(kr + 96);
        f32x4 a = (f32x4){0.f,0.f,0.f,0.f};
        a = MFMA16(qh[0], kh0, a);
        a = MFMA16(ql[0], kh0, a);
        a = MFMA16(qh[0], kl0, a);
        a = MFMA16(qh[1], kh1, a);
        a = MFMA16(ql[1], kh1, a);
        a = MFMA16(qh[1], kl1, a);
        sS[nt] = a;
      }
      const int ktbase = kt*64;
      const int qrow0 = qt*64 + w*16 + q*4;
      #pragma unroll
      for (int rm = 0; rm < 4; rm++) {
        const int qrow = qrow0 + rm;
        float v[4];
        #pragma unroll
        for (int nt = 0; nt < 4; nt++) {
          const int kcol = ktbase + nt*16 + lm;
          const float x = sS[nt][rm]*0.125f;
          v[nt] = (kcol <= qrow) ? x : -INFINITY;
        }
        float tm = fmaxf(fmaxf(v[0],v[1]), fmaxf(v[2],v[3]));
        #pragma unroll
        for (int off = 1; off < 16; off <<= 1) tm = fmaxf(tm, __shfl_xor(tm, off, 64));
        const float nm = fmaxf(mst[rm], tm);
        const float alpha = __expf(mst[rm] - nm);
        float ps = 0.f;
        #pragma unroll
        for (int nt = 0; nt < 4; nt++) {
          float p = __expf(v[nt] - nm);
          sS[nt][rm] = p;
          ps += p;
        }
        #pragma unroll
        for (int off = 1; off < 16; off <<= 1) ps += __shfl_xor(ps, off, 64);
        lst[rm] = lst[rm]*alpha + ps;
        mst[rm] = nm;
        #pragma unroll
        for (int nt = 0; nt < 4; nt++) of[nt][rm] *= alpha;
      }
      __syncthreads();                 // (C) all Kc reads done; Pf may overwrite
      #pragma unroll
      for (int rm = 0; rm < 4; rm++)
        #pragma unroll
        for (int nt = 0; nt < 4; nt++)
          Pf[(w*16 + q*4 + rm)*66 + nt*16 + lm] = sS[nt][rm];
      __syncthreads();                 // (D) Pf visible
      short8 ph[2], pl[2];
      {
        const float* prow = &Pf[(w*16 + lm)*66];
        float pv[16];
        *(float4*)&pv[0]  = *(const float4*)(prow + q*8);
        *(float4*)&pv[4]  = *(const float4*)(prow + q*8 + 4);
        *(float4*)&pv[8]  = *(const float4*)(prow + 32 + q*8);
        *(float4*)&pv[12] = *(const float4*)(prow + 32 + q*8 + 4);
        split8(&pv[0], &ph[0], &pl[0]);
        split8(&pv[8], &ph[1], &pl[1]);
      }
      #pragma unroll
      for (int nt = 0; nt < 4; nt++) {
        const ushort* vr = &Vc[(nt*16 + lm)*136 + q*8];
        const short8 vh0 = *(const short8*)(vr);
        const short8 vh1 = *(const short8*)(vr + 32);
        const short8 vl0 = *(const short8*)(vr + 64);
        const short8 vl1 = *(const short8*)(vr + 96);
        f32x4 a = of[nt];
        a = MFMA16(ph[0], vh0, a);
        a = MFMA16(pl[0], vh0, a);
        a = MFMA16(ph[0], vl0, a);
        a = MFMA16(ph[1], vh1, a);
        a = MFMA16(pl[1], vh1, a);
        a = MFMA16(ph[1], vl1, a);
        of[nt] = a;
      }
    }
    #pragma unroll
    for (int rm = 0; rm < 4; rm++) {
      const float inv = 1.0f / lst[rm];
      const int s = qt*64 + w*16 + q*4 + rm;
      float* orow = O + ((size_t)(b*1024 + s))*1024 + h*64;
      #pragma unroll
      for (int nt = 0; nt < 4; nt++)
        orow[nt*16 + lm] = of[nt][rm] * inv;
    }
  }
}

// ---------------- seq-mean, 2-stage deterministic ----------------
// stage 1: grid (4, 8, B): block sums 128 rows of 256 cols -> part[b][sc][d]
__global__ __launch_bounds__(256) void seqmean1_kernel(const float* __restrict__ g,
                                                       float* __restrict__ part) {
  const int d = blockIdx.x*256 + threadIdx.x;
  const int sc = blockIdx.y;
  const int b = blockIdx.z;
  const float* p = g + ((size_t)b*S_ + sc*128)*D_ + d;
  float s = 0.f;
  #pragma unroll 4
  for (int i = 0; i < 128; i++) s += p[(size_t)i*D_];
  part[((size_t)(b*8 + sc))*D_ + d] = s;
}
// stage 2: grid (4, B): fixed-order sum of 8 partials
__global__ __launch_bounds__(256) void seqmean2_kernel(const float* __restrict__ part,
                                                       float* __restrict__ mbd) {
  const int d = blockIdx.x*256 + threadIdx.x;
  const int b = blockIdx.y;
  float s = 0.f;
  #pragma unroll
  for (int i = 0; i < 8; i++) s += part[((size_t)(b*8 + i))*D_ + d];
  mbd[b*D_ + d] = s * (1.0f/S_);
}

// ---------------- predictor ----------------
__global__ __launch_bounds__(256) void predictor_kernel(
    const float* __restrict__ mbd, const float* __restrict__ Wp,
    const float* __restrict__ bp, float* __restrict__ fpar, int* __restrict__ ipar) {
  __shared__ float sbuf[4];
  __shared__ float sdots[4];
  const int tid = threadIdx.x;
  for (int b = 0; b < 4; b++) {
    float psum = 0.f;
    for (int d = tid; d < D_; d += 256) psum += mbd[b*D_ + d]*Wp[d];
    float tot = block_reduce_sum_256(psum, sbuf);
    if (tid == 0) sdots[b] = tot;
  }
  __syncthreads();
  if (tid == 0) {
    float smv = 0.f;
    for (int b = 0; b < 4; b++) {
      float z = sdots[b] + bp[0];
      smv += 1.0f/(1.0f + expf(-z));
    }
    smv *= 0.25f;
    int win = max(1, (int)(256.0f*smv));
    int span_len = max(1, (int)(512.0f*smv));
    int local_max = min(512, min(span_len, win));
    float temp = 1.0f + 0.01f*(1.0f - smv);
    int n_win = (S_ + win - 1)/win;
    fpar[0] = smv; fpar[1] = temp;
    ipar[0] = win; ipar[1] = span_len; ipar[2] = local_max; ipar[3] = n_win;
  }
}

// ---------------- dynamic sliding-window span attention (fp32 -> bf16 out) -------
#define LDP 68
__global__ __launch_bounds__(256) void lattn_kernel(
    const float* __restrict__ Lc, ushort* __restrict__ Out,
    const int* __restrict__ ip, const float* __restrict__ fpp) {
  __shared__ __align__(16) float Qs[HD_][LDP];
  __shared__ __align__(16) float KPs[64][LDP];
  __shared__ __align__(16) float Vs[64][LDP];
  const int n_win = ip[3];
  const int win = ip[0], span_len = ip[1], local_max = ip[2];
  const float sm = fpp[0], temp = fpp[1];
  const int bh = blockIdx.y;
  const int b = bh >> 4, h = bh & 15;
  const int tid = threadIdx.x;
  const int tx = tid & 15, ty = tid >> 4;
  const float sc = 0.35355339059327373f / temp;
  for (int w = blockIdx.x; w < n_win; w += gridDim.x) {
    const int st = w * win;
    const int en = min(st + win, S_); const int wlen = en - st;
    const int ks = max(0, st - span_len + win);
    const int ke = min(st + span_len, S_); const int klen = ke - ks;
    int eff = (int)((double)wlen * (double)sm);
    eff = min(min(eff, wlen), min(klen, local_max));
    if (eff <= 0) continue;
    const int nt = (eff + 63) >> 6;
    for (int qt = 0; qt < nt; ++qt) {
      const int qn = min(64, eff - qt*64);
      __syncthreads();
      #pragma unroll
      for (int c = 0; c < 4; c++) {
        int f = tid + c*256;
        int r = f >> 4;
        int dc = (f & 15) << 2;
        float4 q4 = make_float4(0.f,0.f,0.f,0.f);
        if (r < qn) q4 = *(const float4*)(Lc + ((size_t)(b*S_ + st + qt*64 + r)) * D_ + h*HD_ + dc);
        Qs[dc+0][r]=q4.x; Qs[dc+1][r]=q4.y; Qs[dc+2][r]=q4.z; Qs[dc+3][r]=q4.w;
      }
      float o[4][4] = {{0.f,0.f,0.f,0.f},{0.f,0.f,0.f,0.f},{0.f,0.f,0.f,0.f},{0.f,0.f,0.f,0.f}};
      float mrow[4], lrow[4];
      #pragma unroll
      for (int i=0;i<4;i++){ mrow[i] = -INFINITY; lrow[i] = 0.f; }
      for (int kt = 0; kt < nt; ++kt) {
        const int kn = min(64, eff - kt*64);
        __syncthreads();
        #pragma unroll
        for (int c = 0; c < 4; c++) {
          int f = tid + c*256;
          int r = f >> 4;
          int dc = (f & 15) << 2;
          float4 k4 = make_float4(0.f,0.f,0.f,0.f);
          if (r < kn) k4 = *(const float4*)(Lc + ((size_t)(b*S_ + ks + kt*64 + r)) * D_ + h*HD_ + dc);
          KPs[dc+0][r]=k4.x; KPs[dc+1][r]=k4.y; KPs[dc+2][r]=k4.z; KPs[dc+3][r]=k4.w;
          *(float4*)&Vs[r][dc] = k4;
        }
        __syncthreads();
        float s[4][4] = {{0.f,0.f,0.f,0.f},{0.f,0.f,0.f,0.f},{0.f,0.f,0.f,0.f},{0.f,0.f,0.f,0.f}};
        #pragma unroll 8
        for (int d = 0; d < HD_; ++d) {
          const float4 a  = *(const float4*)&Qs[d][ty*4];
          const float4 bb = *(const float4*)&KPs[d][tx*4];
          const float av[4]={a.x,a.y,a.z,a.w};
          const float bv[4]={bb.x,bb.y,bb.z,bb.w};
          #pragma unroll
          for (int i=0;i<4;i++)
            #pragma unroll
            for (int j=0;j<4;j++)
              s[i][j] += av[i]*bv[j];
        }
        #pragma unroll
        for (int i=0;i<4;i++) {
          #pragma unroll
          for (int j=0;j<4;j++) {
            float lg = s[i][j]*sc;
            if (kt*64 + tx*4 + j >= eff) lg = -INFINITY;
            s[i][j] = lg;
          }
        }
        #pragma unroll
        for (int i=0;i<4;i++) {
          float tm = fmaxf(fmaxf(s[i][0],s[i][1]), fmaxf(s[i][2],s[i][3]));
          #pragma unroll
          for (int off=1; off<16; off<<=1) tm = fmaxf(tm, __shfl_xor(tm, off, 64));
          const float nm = fmaxf(mrow[i], tm);
          const float alpha = __expf(mrow[i]-nm);
          float ps = 0.f;
          #pragma unroll
          for (int j=0;j<4;j++){ float p = __expf(s[i][j]-nm); s[i][j]=p; ps += p; }
          #pragma unroll
          for (int off=1; off<16; off<<=1) ps += __shfl_xor(ps, off, 64);
          lrow[i] = lrow[i]*alpha + ps;
          mrow[i] = nm;
          #pragma unroll
          for (int j=0;j<4;j++) o[i][j] *= alpha;
        }
        __syncthreads();
        #pragma unroll
        for (int i=0;i<4;i++)
          #pragma unroll
          for (int j=0;j<4;j++)
            KPs[tx*4+j][ty*4+i] = s[i][j];
        __syncthreads();
        #pragma unroll 8
        for (int kk = 0; kk < 64; ++kk) {
          const float4 a  = *(const float4*)&KPs[kk][ty*4];
          const float4 bb = *(const float4*)&Vs[kk][tx*4];
          const float av[4]={a.x,a.y,a.z,a.w};
          const float bv[4]={bb.x,bb.y,bb.z,bb.w};
          #pragma unroll
          for (int i=0;i<4;i++)
            #pragma unroll
            for (int j=0;j<4;j++)
              o[i][j] += av[i]*bv[j];
        }
      }
      #pragma unroll
      for (int i=0;i<4;i++){
        const int r = ty*4 + i;
        if (r < qn) {
          const float inv = 1.0f / lrow[i];
          ushort4 ov;
          ov.x = f2bf(o[i][0]*inv); ov.y = f2bf(o[i][1]*inv);
          ov.z = f2bf(o[i][2]*inv); ov.w = f2bf(o[i][3]*inv);
          *(ushort4*)(Out + ((size_t)(b*S_ + st + qt*64 + r)) * 2048 + h*HD_ + tx*4) = ov;
        }
      }
    }
  }
}

// ---------------- launch ----------------
extern "C" void kernel_launch(void* const* d_in, const int* in_sizes, int n_in,
                              void* d_out, int out_size, void* d_ws, size_t ws_size,
                              hipStream_t stream) {
  const float* x      = (const float*)d_in[0];
  const float* ln_a_g = (const float*)d_in[1];
  const float* ln_a_b = (const float*)d_in[2];
  const float* ln_b_g = (const float*)d_in[3];
  const float* ln_b_b = (const float*)d_in[4];
  const float* Wq     = (const float*)d_in[5];
  const float* bq     = (const float*)d_in[6];
  const float* Wk     = (const float*)d_in[7];
  const float* Wv     = (const float*)d_in[8];
  const float* bv     = (const float*)d_in[9];
  const float* Wo     = (const float*)d_in[10];
  const float* bo     = (const float*)d_in[11];
  const float* Wp     = (const float*)d_in[12];
  const float* bp     = (const float*)d_in[13];
  const float* Wproj  = (const float*)d_in[14];
  const float* bproj  = (const float*)d_in[15];
  float* out = (float*)d_out;
  float* ws  = (float*)d_ws;

  // float-offset layout (~151 MB):
  float* QKVf = ws;                          // [4096,3072] fp32; later A3/B3 bf16 overlay
  float* buf0 = ws + 12582912;               // [4096,1024] attn out
  float* glo  = ws + 16777216;               // [4096,1024] globe_out
  float* loc  = ws + 20971520;               // [4096,1024] LN_a out; earlier Vth/Vtl overlay
  float* biascat = ws + 25165824;            // [3072]
  float* mbd  = biascat + 4096;
  float* fpar = mbd + 4096;
  int*   ipar = (int*)(fpar + 8);
  ushort* Acat  = (ushort*)(ws + 25182208);  // [4096,3072] bf16; later Qsp / part overlay
  ushort* Bqkv  = Acat + 12582912;           // [3072,3072] bf16; later Ksp overlay
  ushort* Bo    = Bqkv + 9437184;            // [1024,3072] bf16
  // overlays:
  ushort* Qsp = Acat;                        // [64*1024,128] bf16
  ushort* Ksp = Bqkv;                        // [64*1024,128] bf16
  ushort* Vth = (ushort*)loc;                // [64*64,1024] bf16 (8 MB)
  ushort* Vtl = Vth + 4194304;               // [64*64,1024] bf16 (8 MB)
  float*  part = (float*)Acat;               // [B*8,1024] fp32 (dead Acat region)
  ushort* A3  = (ushort*)ws;                 // [4096,2048] bf16
  ushort* B3  = A3 + 8388608;                // [1024,2048] bf16

  const dim3 blk(256);

  // 1) LN_b(x) fused with bf16x3 split -> Acat
  ln_split_kernel<<<dim3(B_*S_), blk, 0, stream>>>(x, ln_b_g, ln_b_b, Acat);
  // 2) weight split + bias concat
  split_w3_kernel<<<dim3(3072), blk, 0, stream>>>(Wq, Wk, Wv, Bqkv);
  bias_cat_kernel<<<dim3(12), blk, 0, stream>>>(bq, bv, biascat);
  // 3) QKV = Acat · Bqkv^T + biascat
  mfma_gemm<<<dim3(24, 32), blk, 0, stream>>>(Acat, Bqkv, biascat, QKVf, 3072, 3072);
  // 4) attention pre-splits
  qk_split_kernel<<<dim3(4096), blk, 0, stream>>>(QKVf, Qsp, Ksp);
  vt_split_kernel<<<dim3(16, 64), blk, 0, stream>>>(QKVf, Vth, Vtl);
  // 5) MFMA causal attention -> buf0
  gattn_mfma<<<dim3(8, 64), blk, 0, stream>>>(Qsp, Ksp, Vth, Vtl, buf0);
  // 6) globe_out = attn · Wo^T + bo (bf16x3)
  split_act_kernel<<<dim3(4096), blk, 0, stream>>>(buf0, Acat);
  split_w1_kernel<<<dim3(1024), blk, 0, stream>>>(Wo, Bo);
  mfma_gemm<<<dim3(8, 32), blk, 0, stream>>>(Acat, Bo, bo, glo, 3072, 1024);
  // 7) predictor (device-side); part overlays dead Acat
  seqmean1_kernel<<<dim3(4, 8, B_), blk, 0, stream>>>(glo, part);
  seqmean2_kernel<<<dim3(4, B_), blk, 0, stream>>>(part, mbd);
  predictor_kernel<<<dim3(1), blk, 0, stream>>>(mbd, Wp, bp, fpar, ipar);
  // 8) local = LN_a(x) -> loc (Vth/Vtl dead now)
  ln_kernel<<<dim3(B_*S_), blk, 0, stream>>>(x, ln_a_g, ln_a_b, loc);
  // 9) local attention -> A3[:, 0:1024] bf16 (QKVf dead)
  hipMemsetAsync(A3, 0, (size_t)4096*2048*2, stream);
  lattn_kernel<<<dim3(64, B_*H_), blk, 0, stream>>>(loc, A3, ipar, fpar);
  // 10) A3[:, 1024:2048] = bf16(globe_out); B3 = bf16(Wproj)
  cvt_bf16_kernel<<<dim3(4096), blk, 0, stream>>>(glo, A3, 8, 2048, 1024);
  cvt_bf16_kernel<<<dim3(2048), blk, 0, stream>>>(Wproj, B3, 9, 2048, 0);
  // 11) out = A3 · B3^T + bproj
  mfma_gemm<<<dim3(8, 32), blk, 0, stream>>>(A3, B3, bproj, out, 2048, 1024);
}

// Round 6
// 489.537 us; speedup vs baseline: 2.6319x; 1.0509x over previous
//
#include <hip/hip_runtime.h>
#include <math.h>

#define B_ 4
#define S_ 1024
#define D_ 1024
#define H_ 16
#define HD_ 64
#define BSD_ (B_*S_*D_)

using short8 = __attribute__((ext_vector_type(8))) short;
using f32x4  = __attribute__((ext_vector_type(4))) float;

#define MFMA16(a,b,c) __builtin_amdgcn_mfma_f32_16x16x32_bf16((a),(b),(c),0,0,0)

// ---------------- bf16 helpers (RNE) ----------------
__device__ __forceinline__ ushort f2bf(float f) {
  uint u = __float_as_uint(f);
  return (ushort)((u + 0x7fffu + ((u >> 16) & 1u)) >> 16);
}
__device__ __forceinline__ float bf2f(ushort h) {
  return __uint_as_float(((uint)h) << 16);
}
__device__ __forceinline__ void split8(const float* p, short8* hi, short8* lo) {
  #pragma unroll
  for (int j = 0; j < 8; j++) {
    ushort h = f2bf(p[j]);
    (*hi)[j] = (short)h;
    (*lo)[j] = (short)f2bf(p[j] - bf2f(h));
  }
}
// async global->LDS, 16B per lane; LDS dest = wave-uniform base + lane*16
__device__ __forceinline__ void async_load16(const ushort* g, ushort* l) {
  __builtin_amdgcn_global_load_lds(
      (const __attribute__((address_space(1))) unsigned int*)g,
      (__attribute__((address_space(3))) unsigned int*)l, 16, 0, 0);
}

// ---------------- block reduce (256 threads = 4 waves) ----------------
__device__ __forceinline__ float block_reduce_sum_256(float v, float* sbuf) {
  #pragma unroll
  for (int off = 32; off > 0; off >>= 1) v += __shfl_xor(v, off, 64);
  int lane = threadIdx.x & 63, wid = threadIdx.x >> 6;
  __syncthreads();
  if (lane == 0) sbuf[wid] = v;
  __syncthreads();
  return sbuf[0] + sbuf[1] + sbuf[2] + sbuf[3];
}

// ---------------- LayerNorm (fp32 out) ----------------
__global__ __launch_bounds__(256) void ln_kernel(const float* __restrict__ x,
                                                 const float* __restrict__ g,
                                                 const float* __restrict__ bta,
                                                 float* __restrict__ out) {
  __shared__ float sbuf[4];
  const int row = blockIdx.x;
  const float* xr = x + (size_t)row * D_;
  const int t = threadIdx.x;
  float v[4]; float s = 0.f;
  #pragma unroll
  for (int i = 0; i < 4; i++) { v[i] = xr[t + 256*i]; s += v[i]; }
  const float mean = block_reduce_sum_256(s, sbuf) * (1.0f/D_);
  float sq = 0.f;
  #pragma unroll
  for (int i = 0; i < 4; i++) { float d = v[i]-mean; sq += d*d; }
  const float var = block_reduce_sum_256(sq, sbuf) * (1.0f/D_);
  const float r = rsqrtf(var + 1e-5f);
  float* orow = out + (size_t)row * D_;
  #pragma unroll
  for (int i = 0; i < 4; i++) {
    int c = t + 256*i;
    orow[c] = (v[i]-mean)*r*g[c] + bta[c];
  }
}

// ---------------- fused LayerNorm + [hi|lo] split (stride 2048) ----------------
__global__ __launch_bounds__(256) void ln_split_kernel(const float* __restrict__ x,
                                                       const float* __restrict__ g,
                                                       const float* __restrict__ bta,
                                                       ushort* __restrict__ out) {
  __shared__ float sbuf[4];
  const int row = blockIdx.x;
  const int t = threadIdx.x;
  const int c = t*4;
  const float* xr = x + (size_t)row * D_;
  float4 v = *(const float4*)(xr + c);
  float s = v.x + v.y + v.z + v.w;
  const float mean = block_reduce_sum_256(s, sbuf) * (1.0f/D_);
  float4 dv = make_float4(v.x-mean, v.y-mean, v.z-mean, v.w-mean);
  float sq = dv.x*dv.x + dv.y*dv.y + dv.z*dv.z + dv.w*dv.w;
  const float var = block_reduce_sum_256(sq, sbuf) * (1.0f/D_);
  const float r = rsqrtf(var + 1e-5f);
  float4 gg = *(const float4*)(g + c);
  float4 bb = *(const float4*)(bta + c);
  float n[4];
  n[0] = dv.x*r*gg.x + bb.x; n[1] = dv.y*r*gg.y + bb.y;
  n[2] = dv.z*r*gg.z + bb.z; n[3] = dv.w*r*gg.w + bb.w;
  ushort4 hi, lo;
  hi.x = f2bf(n[0]); hi.y = f2bf(n[1]); hi.z = f2bf(n[2]); hi.w = f2bf(n[3]);
  lo.x = f2bf(n[0]-bf2f(hi.x)); lo.y = f2bf(n[1]-bf2f(hi.y));
  lo.z = f2bf(n[2]-bf2f(hi.z)); lo.w = f2bf(n[3]-bf2f(hi.w));
  ushort* orow = out + (size_t)row*2048;
  *(ushort4*)(orow + c)        = hi;
  *(ushort4*)(orow + 1024 + c) = lo;
}

// ---------------- act split [hi|lo] from fp32 (stride 2048) ----------------
__global__ __launch_bounds__(256) void split_act_kernel(const float* __restrict__ in,
                                                        ushort* __restrict__ out) {
  const int idx = blockIdx.x*256 + threadIdx.x;
  const int row = idx >> 8;
  const int col4 = (idx & 255) << 2;
  const float4 a = *(const float4*)(in + (size_t)row*1024 + col4);
  ushort4 hi, lo;
  hi.x = f2bf(a.x); hi.y = f2bf(a.y); hi.z = f2bf(a.z); hi.w = f2bf(a.w);
  lo.x = f2bf(a.x - bf2f(hi.x)); lo.y = f2bf(a.y - bf2f(hi.y));
  lo.z = f2bf(a.z - bf2f(hi.z)); lo.w = f2bf(a.w - bf2f(hi.w));
  ushort* orow = out + (size_t)row*2048;
  *(ushort4*)(orow + col4)        = hi;
  *(ushort4*)(orow + 1024 + col4) = lo;
}

// ---------------- weight split [hi|lo] for Wq/Wk/Wv stacked (3072 rows) ----------
__global__ __launch_bounds__(256) void split_w3_kernel(const float* __restrict__ Wq,
                                                       const float* __restrict__ Wk,
                                                       const float* __restrict__ Wv,
                                                       ushort* __restrict__ out) {
  const int idx = blockIdx.x*256 + threadIdx.x;
  const int n = idx >> 8;
  const int col4 = (idx & 255) << 2;
  const float* src = (n < 1024) ? (Wq + (size_t)n*1024)
                   : (n < 2048) ? (Wk + (size_t)(n-1024)*1024)
                                : (Wv + (size_t)(n-2048)*1024);
  const float4 a = *(const float4*)(src + col4);
  ushort4 hi, lo;
  hi.x = f2bf(a.x); hi.y = f2bf(a.y); hi.z = f2bf(a.z); hi.w = f2bf(a.w);
  lo.x = f2bf(a.x - bf2f(hi.x)); lo.y = f2bf(a.y - bf2f(hi.y));
  lo.z = f2bf(a.z - bf2f(hi.z)); lo.w = f2bf(a.w - bf2f(hi.w));
  ushort* orow = out + (size_t)n*2048;
  *(ushort4*)(orow + col4)        = hi;
  *(ushort4*)(orow + 1024 + col4) = lo;
}

// ---------------- weight split [hi|lo] single 1024-row weight (Wo) ---------------
__global__ __launch_bounds__(256) void split_w1_kernel(const float* __restrict__ W,
                                                       ushort* __restrict__ out) {
  const int idx = blockIdx.x*256 + threadIdx.x;
  const int n = idx >> 8;
  const int col4 = (idx & 255) << 2;
  const float4 a = *(const float4*)(W + (size_t)n*1024 + col4);
  ushort4 hi, lo;
  hi.x = f2bf(a.x); hi.y = f2bf(a.y); hi.z = f2bf(a.z); hi.w = f2bf(a.w);
  lo.x = f2bf(a.x - bf2f(hi.x)); lo.y = f2bf(a.y - bf2f(hi.y));
  lo.z = f2bf(a.z - bf2f(hi.z)); lo.w = f2bf(a.w - bf2f(hi.w));
  ushort* orow = out + (size_t)n*2048;
  *(ushort4*)(orow + col4)        = hi;
  *(ushort4*)(orow + 1024 + col4) = lo;
}

// ---------------- plain fp32 -> bf16 convert ----------------
__global__ __launch_bounds__(256) void cvt_bf16_kernel(const float* __restrict__ in,
                                                       ushort* __restrict__ out,
                                                       int gprshift, int ostride, int ooff) {
  const int idx = blockIdx.x*256 + threadIdx.x;
  const int row = idx >> gprshift;
  const int col4 = (idx & ((1 << gprshift) - 1)) << 2;
  const int ncols = 4 << gprshift;
  const float4 a = *(const float4*)(in + (size_t)row*ncols + col4);
  ushort4 hi;
  hi.x = f2bf(a.x); hi.y = f2bf(a.y); hi.z = f2bf(a.z); hi.w = f2bf(a.w);
  *(ushort4*)(out + (size_t)row*ostride + ooff + col4) = hi;
}

__global__ __launch_bounds__(256) void bias_cat_kernel(const float* __restrict__ bq,
                                                       const float* __restrict__ bv,
                                                       float* __restrict__ out) {
  const int n = blockIdx.x*256 + threadIdx.x;
  out[n] = (n < 1024) ? bq[n] : (n < 2048) ? 0.f : bv[n-2048];
}

// ---------------- dual-panel bf16x3 MFMA GEMM ----------------
// A=[M,2*Kh]=[Ah|Al], B=[N,2*Kh]=[Bh|Bl]. C = (Ah+Al)(Bh+Bl) - AlBl
// = AhBh + AlBh + AhBl, 3 MFMAs per tile per 32-k chunk. 32 K-iters at Kh=1024.
// LDS chunk XOR-swizzled with row&3 to cut read bank conflicts.
__global__ __launch_bounds__(256) void mfma_gemm2(
    const ushort* __restrict__ A, const ushort* __restrict__ Bw,
    const float* __restrict__ bias, float* __restrict__ C,
    int Kh, int ldc) {
  __shared__ __align__(16) ushort Ash[128*32];
  __shared__ __align__(16) ushort Asl[128*32];
  __shared__ __align__(16) ushort Bsh[128*32];
  __shared__ __align__(16) ushort Bsl[128*32];
  const int lda = 2*Kh;
  const int tid = threadIdx.x;
  const int bm = blockIdx.y * 128, bn = blockIdx.x * 128;
  const int wave = tid >> 6, lane = tid & 63;
  const int wm = wave >> 1, wn = wave & 1;
  const int lm = lane & 15, q = lane >> 4;
  const int lrow = lane >> 2;                        // 0..15
  const int sw = (((lane & 3) ^ (lrow & 3)) << 3);   // swizzled global k-chunk (ushorts)

  f32x4 acc[4][4];
  #pragma unroll
  for (int i = 0; i < 4; i++)
    #pragma unroll
    for (int j = 0; j < 4; j++)
      acc[i][j] = (f32x4){0.f,0.f,0.f,0.f};

  const ushort* Agh = A  + (size_t)(bm + wave*32 + lrow)*lda + sw;
  const ushort* Agl = Agh + Kh;
  const ushort* Bgh = Bw + (size_t)(bn + wave*32 + lrow)*lda + sw;
  const ushort* Bgl = Bgh + Kh;
  const size_t r16a = (size_t)16*lda;
  ushort* AhD0 = &Ash[(wave*32)*32];      ushort* AhD1 = &Ash[(wave*32+16)*32];
  ushort* AlD0 = &Asl[(wave*32)*32];      ushort* AlD1 = &Asl[(wave*32+16)*32];
  ushort* BhD0 = &Bsh[(wave*32)*32];      ushort* BhD1 = &Bsh[(wave*32+16)*32];
  ushort* BlD0 = &Bsl[(wave*32)*32];      ushort* BlD1 = &Bsl[(wave*32+16)*32];
  const int rsw  = ((q ^ (lm & 3)) << 3);
  const int aoff = (wm*64 + lm)*32 + rsw;
  const int boff = (wn*64 + lm)*32 + rsw;

  for (int k0 = 0; k0 < Kh; k0 += 32) {
    __syncthreads();                    // prior tile's frag reads done
    async_load16(Agh + k0, AhD0);
    async_load16(Agh + r16a + k0, AhD1);
    async_load16(Agl + k0, AlD0);
    async_load16(Agl + r16a + k0, AlD1);
    async_load16(Bgh + k0, BhD0);
    async_load16(Bgh + r16a + k0, BhD1);
    async_load16(Bgl + k0, BlD0);
    async_load16(Bgl + r16a + k0, BlD1);
    __syncthreads();                    // vmcnt drained; staging visible
    short8 ah[4], al[4], bh[4], bl[4];
    #pragma unroll
    for (int mt = 0; mt < 4; mt++) {
      ah[mt] = *(const short8*)&Ash[aoff + mt*512];
      al[mt] = *(const short8*)&Asl[aoff + mt*512];
    }
    #pragma unroll
    for (int nt = 0; nt < 4; nt++) {
      bh[nt] = *(const short8*)&Bsh[boff + nt*512];
      bl[nt] = *(const short8*)&Bsl[boff + nt*512];
    }
    #pragma unroll
    for (int mt = 0; mt < 4; mt++)
      #pragma unroll
      for (int nt = 0; nt < 4; nt++) {
        f32x4 a = acc[mt][nt];
        a = MFMA16(ah[mt], bh[nt], a);
        a = MFMA16(al[mt], bh[nt], a);
        a = MFMA16(ah[mt], bl[nt], a);
        acc[mt][nt] = a;
      }
  }

  #pragma unroll
  for (int mt = 0; mt < 4; mt++) {
    #pragma unroll
    for (int nt = 0; nt < 4; nt++) {
      const int n = bn + wn*64 + nt*16 + lm;
      const float bb = bias ? bias[n] : 0.f;
      #pragma unroll
      for (int reg = 0; reg < 4; reg++) {
        const int m = bm + wm*64 + mt*16 + q*4 + reg;
        C[(size_t)m*ldc + n] = acc[mt][nt][reg] + bb;
      }
    }
  }
}

// ---------------- plain bf16 MFMA GEMM (final projection), swizzled ----------------
__global__ __launch_bounds__(256) void mfma_gemm(
    const ushort* __restrict__ A, const ushort* __restrict__ Bw,
    const float* __restrict__ bias, float* __restrict__ C,
    int K, int ldc) {
  __shared__ __align__(16) ushort As[128*32];
  __shared__ __align__(16) ushort Bs[128*32];
  const int tid = threadIdx.x;
  const int bm = blockIdx.y * 128, bn = blockIdx.x * 128;
  const int wave = tid >> 6, lane = tid & 63;
  const int wm = wave >> 1, wn = wave & 1;
  const int lm = lane & 15, q = lane >> 4;
  const int lrow = lane >> 2;
  const int sw = (((lane & 3) ^ (lrow & 3)) << 3);

  f32x4 acc[4][4];
  #pragma unroll
  for (int i = 0; i < 4; i++)
    #pragma unroll
    for (int j = 0; j < 4; j++)
      acc[i][j] = (f32x4){0.f,0.f,0.f,0.f};

  const ushort* Ar0 = A  + (size_t)(bm + wave*32 + lrow)*K + sw;
  const ushort* Br0 = Bw + (size_t)(bn + wave*32 + lrow)*K + sw;
  const size_t r16 = (size_t)16*K;
  ushort* AsD0 = &As[(wave*32)*32];
  ushort* AsD1 = &As[(wave*32 + 16)*32];
  ushort* BsD0 = &Bs[(wave*32)*32];
  ushort* BsD1 = &Bs[(wave*32 + 16)*32];
  const int rsw  = ((q ^ (lm & 3)) << 3);
  const int aoff0 = (wm*64 + lm)*32 + rsw;
  const int boff0 = (wn*64 + lm)*32 + rsw;

  for (int k0 = 0; k0 < K; k0 += 32) {
    __syncthreads();
    async_load16(Ar0 + k0, AsD0);
    async_load16(Ar0 + r16 + k0, AsD1);
    async_load16(Br0 + k0, BsD0);
    async_load16(Br0 + r16 + k0, BsD1);
    __syncthreads();
    short8 af[4], bf[4];
    #pragma unroll
    for (int mt = 0; mt < 4; mt++) af[mt] = *(const short8*)&As[aoff0 + mt*512];
    #pragma unroll
    for (int nt = 0; nt < 4; nt++) bf[nt] = *(const short8*)&Bs[boff0 + nt*512];
    #pragma unroll
    for (int mt = 0; mt < 4; mt++)
      #pragma unroll
      for (int nt = 0; nt < 4; nt++)
        acc[mt][nt] = MFMA16(af[mt], bf[nt], acc[mt][nt]);
  }

  #pragma unroll
  for (int mt = 0; mt < 4; mt++) {
    #pragma unroll
    for (int nt = 0; nt < 4; nt++) {
      const int n = bn + wn*64 + nt*16 + lm;
      const float bb = bias ? bias[n] : 0.f;
      #pragma unroll
      for (int reg = 0; reg < 4; reg++) {
        const int m = bm + wm*64 + mt*16 + q*4 + reg;
        C[(size_t)m*ldc + n] = acc[mt][nt][reg] + bb;
      }
    }
  }
}

// ---------------- Q/K pre-split into [hi|lo] rows (128 cols) ----------------
__global__ __launch_bounds__(256) void qk_split_kernel(const float* __restrict__ QKV,
                                                       ushort* __restrict__ Qsp,
                                                       ushort* __restrict__ Ksp) {
  const int row = blockIdx.x;            // b*1024 + s
  const int b = row >> 10, s = row & 1023;
  const int t = threadIdx.x;
  const int h = t >> 4, c4 = (t & 15) * 4;
  const float* src = QKV + (size_t)row*3072 + h*64 + c4;
  const float4 qv = *(const float4*)src;
  const float4 kv = *(const float4*)(src + 1024);
  ushort4 qh, ql, kh, kl;
  qh.x=f2bf(qv.x); qh.y=f2bf(qv.y); qh.z=f2bf(qv.z); qh.w=f2bf(qv.w);
  ql.x=f2bf(qv.x-bf2f(qh.x)); ql.y=f2bf(qv.y-bf2f(qh.y));
  ql.z=f2bf(qv.z-bf2f(qh.z)); ql.w=f2bf(qv.w-bf2f(qh.w));
  kh.x=f2bf(kv.x); kh.y=f2bf(kv.y); kh.z=f2bf(kv.z); kh.w=f2bf(kv.w);
  kl.x=f2bf(kv.x-bf2f(kh.x)); kl.y=f2bf(kv.y-bf2f(kh.y));
  kl.z=f2bf(kv.z-bf2f(kh.z)); kl.w=f2bf(kv.w-bf2f(kh.w));
  ushort* qd = Qsp + ((size_t)(b*16 + h)*1024 + s)*128;
  ushort* kd = Ksp + ((size_t)(b*16 + h)*1024 + s)*128;
  *(ushort4*)(qd + c4)      = qh;
  *(ushort4*)(qd + 64 + c4) = ql;
  *(ushort4*)(kd + c4)      = kh;
  *(ushort4*)(kd + 64 + c4) = kl;
}

// ---------------- V transpose + split: Vth/Vtl[(bh)*64+d][s] ----------------
__global__ __launch_bounds__(256) void vt_split_kernel(const float* __restrict__ QKV,
                                                       ushort* __restrict__ Vth,
                                                       ushort* __restrict__ Vtl) {
  __shared__ float T[64][65];
  const int sc = blockIdx.x;             // 0..15 (s-chunk of 64)
  const int bh = blockIdx.y;             // 0..63
  const int b = bh >> 4, h = bh & 15;
  const int t = threadIdx.x;
  {
    const int r = t >> 2, c16 = (t & 3) * 16;
    const float* src = QKV + ((size_t)(b*1024 + sc*64 + r))*3072 + 2048 + h*64 + c16;
    #pragma unroll
    for (int j = 0; j < 4; j++)
      *(float4*)&T[r][c16 + j*4] = *(const float4*)(src + j*4);
  }
  __syncthreads();
  const int d = t >> 2, s16 = (t & 3) * 16;
  short8 h0, h1, l0, l1;
  #pragma unroll
  for (int j = 0; j < 8; j++) {
    float v = T[s16 + j][d];
    ushort hh = f2bf(v);
    h0[j] = (short)hh; l0[j] = (short)f2bf(v - bf2f(hh));
  }
  #pragma unroll
  for (int j = 0; j < 8; j++) {
    float v = T[s16 + 8 + j][d];
    ushort hh = f2bf(v);
    h1[j] = (short)hh; l1[j] = (short)f2bf(v - bf2f(hh));
  }
  const size_t off = ((size_t)bh*64 + d)*1024 + sc*64 + s16;
  *(short8*)(Vth + off)     = h0;
  *(short8*)(Vth + off + 8) = h1;
  *(short8*)(Vtl + off)     = l0;
  *(short8*)(Vtl + off + 8) = l1;
}

// ---------------- MFMA causal flash attention (proven round-4/5 version) ---------
__global__ __launch_bounds__(256) void gattn_mfma(
    const ushort* __restrict__ Qsp, const ushort* __restrict__ Ksp,
    const ushort* __restrict__ Vth, const ushort* __restrict__ Vtl,
    float* __restrict__ O) {
  __shared__ __align__(16) char su[64*136*2];   // max(Kc 17408 B, Pf 16896 B)
  __shared__ __align__(16) ushort Vc[64*136];
  ushort* Kc = (ushort*)su;
  float*  Pf = (float*)su;
  const int bh = blockIdx.y;
  const int b = bh >> 4, h = bh & 15;
  const int tid = threadIdx.x;
  const int w = tid >> 6, lane = tid & 63;
  const int lm = lane & 15, q = lane >> 4;
  const ushort* Qb_ = Qsp + (size_t)bh * (1024*128);
  const ushort* Kb_ = Ksp + (size_t)bh * (1024*128);
  const ushort* Vhb = Vth + (size_t)bh * (64*1024);
  const ushort* Vlb = Vtl + (size_t)bh * (64*1024);

  for (int half = 0; half < 2; ++half) {
    const int qt = half ? blockIdx.x : 15 - blockIdx.x;
    short8 qh[2], ql[2];
    {
      const ushort* qr = Qb_ + (size_t)(qt*64 + w*16 + lm)*128 + q*8;
      qh[0] = *(const short8*)(qr);
      qh[1] = *(const short8*)(qr + 32);
      ql[0] = *(const short8*)(qr + 64);
      ql[1] = *(const short8*)(qr + 96);
    }
    f32x4 of[4];
    float mst[4], lst[4];
    #pragma unroll
    for (int nt = 0; nt < 4; nt++) of[nt] = (f32x4){0.f,0.f,0.f,0.f};
    #pragma unroll
    for (int rm = 0; rm < 4; rm++) { mst[rm] = -INFINITY; lst[rm] = 0.f; }
    const int nkt = qt + 1;
    for (int kt = 0; kt < nkt; ++kt) {
      __syncthreads();                 // (A) prior iter's Pf/Vc reads done
      #pragma unroll
      for (int i = 0; i < 4; i++) {
        const int slot = i*256 + tid;  // 0..1023: 64 rows x 16 chunks of 8
        const int row = slot >> 4, c8 = slot & 15;
        *(float4*)&Kc[row*136 + c8*8] =
            *(const float4*)(Kb_ + (size_t)(kt*64 + row)*128 + c8*8);
        const ushort* vsrc = ((c8 < 8) ? Vhb : Vlb) + (size_t)row*1024 + kt*64 + (c8&7)*8;
        *(float4*)&Vc[row*136 + c8*8] = *(const float4*)vsrc;
      }
      __syncthreads();                 // (B) staging visible
      f32x4 sS[4];
      #pragma unroll
      for (int nt = 0; nt < 4; nt++) {
        const ushort* kr = &Kc[(nt*16 + lm)*136 + q*8];
        const short8 kh0 = *(const short8*)(kr);
        const short8 kh1 = *(const short8*)(kr + 32);
        const short8 kl0 = *(const short8*)(kr + 64);
        const short8 kl1 = *(const short8*)(kr + 96);
        f32x4 a = (f32x4){0.f,0.f,0.f,0.f};
        a = MFMA16(qh[0], kh0, a);
        a = MFMA16(ql[0], kh0, a);
        a = MFMA16(qh[0], kl0, a);
        a = MFMA16(qh[1], kh1, a);
        a = MFMA16(ql[1], kh1, a);
        a = MFMA16(qh[1], kl1, a);
        sS[nt] = a;
      }
      const int ktbase = kt*64;
      const int qrow0 = qt*64 + w*16 + q*4;
      #pragma unroll
      for (int rm = 0; rm < 4; rm++) {
        const int qrow = qrow0 + rm;
        float v[4];
        #pragma unroll
        for (int nt = 0; nt < 4; nt++) {
          const int kcol = ktbase + nt*16 + lm;
          const float x = sS[nt][rm]*0.125f;
          v[nt] = (kcol <= qrow) ? x : -INFINITY;
        }
        float tm = fmaxf(fmaxf(v[0],v[1]), fmaxf(v[2],v[3]));
        #pragma unroll
        for (int off = 1; off < 16; off <<= 1) tm = fmaxf(tm, __shfl_xor(tm, off, 64));
        const float nm = fmaxf(mst[rm], tm);
        const float alpha = __expf(mst[rm] - nm);
        float ps = 0.f;
        #pragma unroll
        for (int nt = 0; nt < 4; nt++) {
          float p = __expf(v[nt] - nm);
          sS[nt][rm] = p;
          ps += p;
        }
        #pragma unroll
        for (int off = 1; off < 16; off <<= 1) ps += __shfl_xor(ps, off, 64);
        lst[rm] = lst[rm]*alpha + ps;
        mst[rm] = nm;
        #pragma unroll
        for (int nt = 0; nt < 4; nt++) of[nt][rm] *= alpha;
      }
      __syncthreads();                 // (C) all Kc reads done; Pf may overwrite
      #pragma unroll
      for (int rm = 0; rm < 4; rm++)
        #pragma unroll
        for (int nt = 0; nt < 4; nt++)
          Pf[(w*16 + q*4 + rm)*66 + nt*16 + lm] = sS[nt][rm];
      __syncthreads();                 // (D) Pf visible
      short8 ph[2], pl[2];
      {
        const float* prow = &Pf[(w*16 + lm)*66];
        float pv[16];
        *(float4*)&pv[0]  = *(const float4*)(prow + q*8);
        *(float4*)&pv[4]  = *(const float4*)(prow + q*8 + 4);
        *(float4*)&pv[8]  = *(const float4*)(prow + 32 + q*8);
        *(float4*)&pv[12] = *(const float4*)(prow + 32 + q*8 + 4);
        split8(&pv[0], &ph[0], &pl[0]);
        split8(&pv[8], &ph[1], &pl[1]);
      }
      #pragma unroll
      for (int nt = 0; nt < 4; nt++) {
        const ushort* vr = &Vc[(nt*16 + lm)*136 + q*8];
        const short8 vh0 = *(const short8*)(vr);
        const short8 vh1 = *(const short8*)(vr + 32);
        const short8 vl0 = *(const short8*)(vr + 64);
        const short8 vl1 = *(const short8*)(vr + 96);
        f32x4 a = of[nt];
        a = MFMA16(ph[0], vh0, a);
        a = MFMA16(pl[0], vh0, a);
        a = MFMA16(ph[0], vl0, a);
        a = MFMA16(ph[1], vh1, a);
        a = MFMA16(pl[1], vh1, a);
        a = MFMA16(ph[1], vl1, a);
        of[nt] = a;
      }
    }
    #pragma unroll
    for (int rm = 0; rm < 4; rm++) {
      const float inv = 1.0f / lst[rm];
      const int s = qt*64 + w*16 + q*4 + rm;
      float* orow = O + ((size_t)(b*1024 + s))*1024 + h*64;
      #pragma unroll
      for (int nt = 0; nt < 4; nt++)
        orow[nt*16 + lm] = of[nt][rm] * inv;
    }
  }
}

// ---------------- seq-mean, 2-stage deterministic ----------------
__global__ __launch_bounds__(256) void seqmean1_kernel(const float* __restrict__ g,
                                                       float* __restrict__ part) {
  const int d = blockIdx.x*256 + threadIdx.x;
  const int sc = blockIdx.y;
  const int b = blockIdx.z;
  const float* p = g + ((size_t)b*S_ + sc*128)*D_ + d;
  float s = 0.f;
  #pragma unroll 4
  for (int i = 0; i < 128; i++) s += p[(size_t)i*D_];
  part[((size_t)(b*8 + sc))*D_ + d] = s;
}
__global__ __launch_bounds__(256) void seqmean2_kernel(const float* __restrict__ part,
                                                       float* __restrict__ mbd) {
  const int d = blockIdx.x*256 + threadIdx.x;
  const int b = blockIdx.y;
  float s = 0.f;
  #pragma unroll
  for (int i = 0; i < 8; i++) s += part[((size_t)(b*8 + i))*D_ + d];
  mbd[b*D_ + d] = s * (1.0f/S_);
}

// ---------------- predictor ----------------
__global__ __launch_bounds__(256) void predictor_kernel(
    const float* __restrict__ mbd, const float* __restrict__ Wp,
    const float* __restrict__ bp, float* __restrict__ fpar, int* __restrict__ ipar) {
  __shared__ float sbuf[4];
  __shared__ float sdots[4];
  const int tid = threadIdx.x;
  for (int b = 0; b < 4; b++) {
    float psum = 0.f;
    for (int d = tid; d < D_; d += 256) psum += mbd[b*D_ + d]*Wp[d];
    float tot = block_reduce_sum_256(psum, sbuf);
    if (tid == 0) sdots[b] = tot;
  }
  __syncthreads();
  if (tid == 0) {
    float smv = 0.f;
    for (int b = 0; b < 4; b++) {
      float z = sdots[b] + bp[0];
      smv += 1.0f/(1.0f + expf(-z));
    }
    smv *= 0.25f;
    int win = max(1, (int)(256.0f*smv));
    int span_len = max(1, (int)(512.0f*smv));
    int local_max = min(512, min(span_len, win));
    float temp = 1.0f + 0.01f*(1.0f - smv);
    int n_win = (S_ + win - 1)/win;
    fpar[0] = smv; fpar[1] = temp;
    ipar[0] = win; ipar[1] = span_len; ipar[2] = local_max; ipar[3] = n_win;
  }
}

// ---------------- dynamic sliding-window span attention (fp32 -> bf16 out) -------
#define LDP 68
__global__ __launch_bounds__(256) void lattn_kernel(
    const float* __restrict__ Lc, ushort* __restrict__ Out,
    const int* __restrict__ ip, const float* __restrict__ fpp) {
  __shared__ __align__(16) float Qs[HD_][LDP];
  __shared__ __align__(16) float KPs[64][LDP];
  __shared__ __align__(16) float Vs[64][LDP];
  const int n_win = ip[3];
  const int win = ip[0], span_len = ip[1], local_max = ip[2];
  const float sm = fpp[0], temp = fpp[1];
  const int bh = blockIdx.y;
  const int b = bh >> 4, h = bh & 15;
  const int tid = threadIdx.x;
  const int tx = tid & 15, ty = tid >> 4;
  const float sc = 0.35355339059327373f / temp;
  for (int w = blockIdx.x; w < n_win; w += gridDim.x) {
    const int st = w * win;
    const int en = min(st + win, S_); const int wlen = en - st;
    const int ks = max(0, st - span_len + win);
    const int ke = min(st + span_len, S_); const int klen = ke - ks;
    int eff = (int)((double)wlen * (double)sm);
    eff = min(min(eff, wlen), min(klen, local_max));
    if (eff <= 0) continue;
    const int nt = (eff + 63) >> 6;
    for (int qt = 0; qt < nt; ++qt) {
      const int qn = min(64, eff - qt*64);
      __syncthreads();
      #pragma unroll
      for (int c = 0; c < 4; c++) {
        int f = tid + c*256;
        int r = f >> 4;
        int dc = (f & 15) << 2;
        float4 q4 = make_float4(0.f,0.f,0.f,0.f);
        if (r < qn) q4 = *(const float4*)(Lc + ((size_t)(b*S_ + st + qt*64 + r)) * D_ + h*HD_ + dc);
        Qs[dc+0][r]=q4.x; Qs[dc+1][r]=q4.y; Qs[dc+2][r]=q4.z; Qs[dc+3][r]=q4.w;
      }
      float o[4][4] = {{0.f,0.f,0.f,0.f},{0.f,0.f,0.f,0.f},{0.f,0.f,0.f,0.f},{0.f,0.f,0.f,0.f}};
      float mrow[4], lrow[4];
      #pragma unroll
      for (int i=0;i<4;i++){ mrow[i] = -INFINITY; lrow[i] = 0.f; }
      for (int kt = 0; kt < nt; ++kt) {
        const int kn = min(64, eff - kt*64);
        __syncthreads();
        #pragma unroll
        for (int c = 0; c < 4; c++) {
          int f = tid + c*256;
          int r = f >> 4;
          int dc = (f & 15) << 2;
          float4 k4 = make_float4(0.f,0.f,0.f,0.f);
          if (r < kn) k4 = *(const float4*)(Lc + ((size_t)(b*S_ + ks + kt*64 + r)) * D_ + h*HD_ + dc);
          KPs[dc+0][r]=k4.x; KPs[dc+1][r]=k4.y; KPs[dc+2][r]=k4.z; KPs[dc+3][r]=k4.w;
          *(float4*)&Vs[r][dc] = k4;
        }
        __syncthreads();
        float s[4][4] = {{0.f,0.f,0.f,0.f},{0.f,0.f,0.f,0.f},{0.f,0.f,0.f,0.f},{0.f,0.f,0.f,0.f}};
        #pragma unroll 8
        for (int d = 0; d < HD_; ++d) {
          const float4 a  = *(const float4*)&Qs[d][ty*4];
          const float4 bb = *(const float4*)&KPs[d][tx*4];
          const float av[4]={a.x,a.y,a.z,a.w};
          const float bv[4]={bb.x,bb.y,bb.z,bb.w};
          #pragma unroll
          for (int i=0;i<4;i++)
            #pragma unroll
            for (int j=0;j<4;j++)
              s[i][j] += av[i]*bv[j];
        }
        #pragma unroll
        for (int i=0;i<4;i++) {
          #pragma unroll
          for (int j=0;j<4;j++) {
            float lg = s[i][j]*sc;
            if (kt*64 + tx*4 + j >= eff) lg = -INFINITY;
            s[i][j] = lg;
          }
        }
        #pragma unroll
        for (int i=0;i<4;i++) {
          float tm = fmaxf(fmaxf(s[i][0],s[i][1]), fmaxf(s[i][2],s[i][3]));
          #pragma unroll
          for (int off=1; off<16; off<<=1) tm = fmaxf(tm, __shfl_xor(tm, off, 64));
          const float nm = fmaxf(mrow[i], tm);
          const float alpha = __expf(mrow[i]-nm);
          float ps = 0.f;
          #pragma unroll
          for (int j=0;j<4;j++){ float p = __expf(s[i][j]-nm); s[i][j]=p; ps += p; }
          #pragma unroll
          for (int off=1; off<16; off<<=1) ps += __shfl_xor(ps, off, 64);
          lrow[i] = lrow[i]*alpha + ps;
          mrow[i] = nm;
          #pragma unroll
          for (int j=0;j<4;j++) o[i][j] *= alpha;
        }
        __syncthreads();
        #pragma unroll
        for (int i=0;i<4;i++)
          #pragma unroll
          for (int j=0;j<4;j++)
            KPs[tx*4+j][ty*4+i] = s[i][j];
        __syncthreads();
        #pragma unroll 8
        for (int kk = 0; kk < 64; ++kk) {
          const float4 a  = *(const float4*)&KPs[kk][ty*4];
          const float4 bb = *(const float4*)&Vs[kk][tx*4];
          const float av[4]={a.x,a.y,a.z,a.w};
          const float bv[4]={bb.x,bb.y,bb.z,bb.w};
          #pragma unroll
          for (int i=0;i<4;i++)
            #pragma unroll
            for (int j=0;j<4;j++)
              o[i][j] += av[i]*bv[j];
        }
      }
      #pragma unroll
      for (int i=0;i<4;i++){
        const int r = ty*4 + i;
        if (r < qn) {
          const float inv = 1.0f / lrow[i];
          ushort4 ov;
          ov.x = f2bf(o[i][0]*inv); ov.y = f2bf(o[i][1]*inv);
          ov.z = f2bf(o[i][2]*inv); ov.w = f2bf(o[i][3]*inv);
          *(ushort4*)(Out + ((size_t)(b*S_ + st + qt*64 + r)) * 2048 + h*HD_ + tx*4) = ov;
        }
      }
    }
  }
}

// ---------------- launch ----------------
extern "C" void kernel_launch(void* const* d_in, const int* in_sizes, int n_in,
                              void* d_out, int out_size, void* d_ws, size_t ws_size,
                              hipStream_t stream) {
  const float* x      = (const float*)d_in[0];
  const float* ln_a_g = (const float*)d_in[1];
  const float* ln_a_b = (const float*)d_in[2];
  const float* ln_b_g = (const float*)d_in[3];
  const float* ln_b_b = (const float*)d_in[4];
  const float* Wq     = (const float*)d_in[5];
  const float* bq     = (const float*)d_in[6];
  const float* Wk     = (const float*)d_in[7];
  const float* Wv     = (const float*)d_in[8];
  const float* bv     = (const float*)d_in[9];
  const float* Wo     = (const float*)d_in[10];
  const float* bo     = (const float*)d_in[11];
  const float* Wp     = (const float*)d_in[12];
  const float* bp     = (const float*)d_in[13];
  const float* Wproj  = (const float*)d_in[14];
  const float* bproj  = (const float*)d_in[15];
  float* out = (float*)d_out;
  float* ws  = (float*)d_ws;

  // float-offset layout (~151 MB):
  float* QKVf = ws;                          // [4096,3072] fp32; later A3/B3 bf16 overlay
  float* buf0 = ws + 12582912;               // [4096,1024] attn out
  float* glo  = ws + 16777216;               // [4096,1024] globe_out
  float* loc  = ws + 20971520;               // [4096,1024] LN_a out; earlier Vth/Vtl overlay
  float* biascat = ws + 25165824;            // [3072]
  float* mbd  = biascat + 4096;
  float* fpar = mbd + 4096;
  int*   ipar = (int*)(fpar + 8);
  ushort* Acat  = (ushort*)(ws + 25182208);  // [4096,2048] bf16; later Qsp / part overlay
  ushort* Bqkv  = Acat + 12582912;           // [3072,2048] bf16; later Ksp overlay
  ushort* Bo    = Bqkv + 9437184;            // [1024,2048] bf16
  // overlays:
  ushort* Qsp = Acat;                        // [64*1024,128] bf16
  ushort* Ksp = Bqkv;                        // [64*1024,128] bf16
  ushort* Vth = (ushort*)loc;                // [64*64,1024] bf16 (8 MB)
  ushort* Vtl = Vth + 4194304;               // [64*64,1024] bf16 (8 MB)
  float*  part = (float*)Acat;               // [B*8,1024] fp32 (dead Acat region)
  ushort* A3  = (ushort*)ws;                 // [4096,2048] bf16
  ushort* B3  = A3 + 8388608;                // [1024,2048] bf16

  const dim3 blk(256);

  // 1) LN_b(x) fused with [hi|lo] split -> Acat [4096,2048]
  ln_split_kernel<<<dim3(B_*S_), blk, 0, stream>>>(x, ln_b_g, ln_b_b, Acat);
  // 2) weight split [hi|lo] + bias concat
  split_w3_kernel<<<dim3(3072), blk, 0, stream>>>(Wq, Wk, Wv, Bqkv);
  bias_cat_kernel<<<dim3(12), blk, 0, stream>>>(bq, bv, biascat);
  // 3) QKV = (Ah+Al)(Bh+Bl)-AlBl via dual-panel bf16x3, Kh=1024
  mfma_gemm2<<<dim3(24, 32), blk, 0, stream>>>(Acat, Bqkv, biascat, QKVf, 1024, 3072);
  // 4) attention pre-splits
  qk_split_kernel<<<dim3(4096), blk, 0, stream>>>(QKVf, Qsp, Ksp);
  vt_split_kernel<<<dim3(16, 64), blk, 0, stream>>>(QKVf, Vth, Vtl);
  // 5) MFMA causal attention -> buf0
  gattn_mfma<<<dim3(8, 64), blk, 0, stream>>>(Qsp, Ksp, Vth, Vtl, buf0);
  // 6) globe_out = attn · Wo^T + bo (dual-panel bf16x3)
  split_act_kernel<<<dim3(4096), blk, 0, stream>>>(buf0, Acat);
  split_w1_kernel<<<dim3(1024), blk, 0, stream>>>(Wo, Bo);
  mfma_gemm2<<<dim3(8, 32), blk, 0, stream>>>(Acat, Bo, bo, glo, 1024, 1024);
  // 7) predictor (device-side); part overlays dead Acat
  seqmean1_kernel<<<dim3(4, 8, B_), blk, 0, stream>>>(glo, part);
  seqmean2_kernel<<<dim3(4, B_), blk, 0, stream>>>(part, mbd);
  predictor_kernel<<<dim3(1), blk, 0, stream>>>(mbd, Wp, bp, fpar, ipar);
  // 8) local = LN_a(x) -> loc (Vth/Vtl dead now)
  ln_kernel<<<dim3(B_*S_), blk, 0, stream>>>(x, ln_a_g, ln_a_b, loc);
  // 9) local attention -> A3[:, 0:1024] bf16 (QKVf dead)
  hipMemsetAsync(A3, 0, (size_t)4096*2048*2, stream);
  lattn_kernel<<<dim3(64, B_*H_), blk, 0, stream>>>(loc, A3, ipar, fpar);
  // 10) A3[:, 1024:2048] = bf16(globe_out); B3 = bf16(Wproj)
  cvt_bf16_kernel<<<dim3(4096), blk, 0, stream>>>(glo, A3, 8, 2048, 1024);
  cvt_bf16_kernel<<<dim3(2048), blk, 0, stream>>>(Wproj, B3, 9, 2048, 0);
  // 11) out = A3 · B3^T + bproj
  mfma_gemm<<<dim3(8, 32), blk, 0, stream>>>(A3, B3, bproj, out, 2048, 1024);
}

// Round 7
// 483.552 us; speedup vs baseline: 2.6644x; 1.0124x over previous
//
#include <hip/hip_runtime.h>
#include <math.h>

#define B_ 4
#define S_ 1024
#define D_ 1024
#define H_ 16
#define HD_ 64
#define BSD_ (B_*S_*D_)

using short8 = __attribute__((ext_vector_type(8))) short;
using f32x4  = __attribute__((ext_vector_type(4))) float;

#define MFMA16(a,b,c) __builtin_amdgcn_mfma_f32_16x16x32_bf16((a),(b),(c),0,0,0)

// ---------------- bf16 helpers (RNE) ----------------
__device__ __forceinline__ ushort f2bf(float f) {
  uint u = __float_as_uint(f);
  return (ushort)((u + 0x7fffu + ((u >> 16) & 1u)) >> 16);
}
__device__ __forceinline__ float bf2f(ushort h) {
  return __uint_as_float(((uint)h) << 16);
}
__device__ __forceinline__ void split8(const float* p, short8* hi, short8* lo) {
  #pragma unroll
  for (int j = 0; j < 8; j++) {
    ushort h = f2bf(p[j]);
    (*hi)[j] = (short)h;
    (*lo)[j] = (short)f2bf(p[j] - bf2f(h));
  }
}
// async global->LDS, 16B per lane; LDS dest = wave-uniform base + lane*16
__device__ __forceinline__ void async_load16(const ushort* g, ushort* l) {
  __builtin_amdgcn_global_load_lds(
      (const __attribute__((address_space(1))) unsigned int*)g,
      (__attribute__((address_space(3))) unsigned int*)l, 16, 0, 0);
}

// ---------------- block reduce (256 threads = 4 waves) ----------------
__device__ __forceinline__ float block_reduce_sum_256(float v, float* sbuf) {
  #pragma unroll
  for (int off = 32; off > 0; off >>= 1) v += __shfl_xor(v, off, 64);
  int lane = threadIdx.x & 63, wid = threadIdx.x >> 6;
  __syncthreads();
  if (lane == 0) sbuf[wid] = v;
  __syncthreads();
  return sbuf[0] + sbuf[1] + sbuf[2] + sbuf[3];
}

// ---------------- LayerNorm (fp32 out) ----------------
__global__ __launch_bounds__(256) void ln_kernel(const float* __restrict__ x,
                                                 const float* __restrict__ g,
                                                 const float* __restrict__ bta,
                                                 float* __restrict__ out) {
  __shared__ float sbuf[4];
  const int row = blockIdx.x;
  const float* xr = x + (size_t)row * D_;
  const int t = threadIdx.x;
  float v[4]; float s = 0.f;
  #pragma unroll
  for (int i = 0; i < 4; i++) { v[i] = xr[t + 256*i]; s += v[i]; }
  const float mean = block_reduce_sum_256(s, sbuf) * (1.0f/D_);
  float sq = 0.f;
  #pragma unroll
  for (int i = 0; i < 4; i++) { float d = v[i]-mean; sq += d*d; }
  const float var = block_reduce_sum_256(sq, sbuf) * (1.0f/D_);
  const float r = rsqrtf(var + 1e-5f);
  float* orow = out + (size_t)row * D_;
  #pragma unroll
  for (int i = 0; i < 4; i++) {
    int c = t + 256*i;
    orow[c] = (v[i]-mean)*r*g[c] + bta[c];
  }
}

// ---------------- fused LayerNorm + [hi|lo] split (stride 2048) ----------------
__global__ __launch_bounds__(256) void ln_split_kernel(const float* __restrict__ x,
                                                       const float* __restrict__ g,
                                                       const float* __restrict__ bta,
                                                       ushort* __restrict__ out) {
  __shared__ float sbuf[4];
  const int row = blockIdx.x;
  const int t = threadIdx.x;
  const int c = t*4;
  const float* xr = x + (size_t)row * D_;
  float4 v = *(const float4*)(xr + c);
  float s = v.x + v.y + v.z + v.w;
  const float mean = block_reduce_sum_256(s, sbuf) * (1.0f/D_);
  float4 dv = make_float4(v.x-mean, v.y-mean, v.z-mean, v.w-mean);
  float sq = dv.x*dv.x + dv.y*dv.y + dv.z*dv.z + dv.w*dv.w;
  const float var = block_reduce_sum_256(sq, sbuf) * (1.0f/D_);
  const float r = rsqrtf(var + 1e-5f);
  float4 gg = *(const float4*)(g + c);
  float4 bb = *(const float4*)(bta + c);
  float n[4];
  n[0] = dv.x*r*gg.x + bb.x; n[1] = dv.y*r*gg.y + bb.y;
  n[2] = dv.z*r*gg.z + bb.z; n[3] = dv.w*r*gg.w + bb.w;
  ushort4 hi, lo;
  hi.x = f2bf(n[0]); hi.y = f2bf(n[1]); hi.z = f2bf(n[2]); hi.w = f2bf(n[3]);
  lo.x = f2bf(n[0]-bf2f(hi.x)); lo.y = f2bf(n[1]-bf2f(hi.y));
  lo.z = f2bf(n[2]-bf2f(hi.z)); lo.w = f2bf(n[3]-bf2f(hi.w));
  ushort* orow = out + (size_t)row*2048;
  *(ushort4*)(orow + c)        = hi;
  *(ushort4*)(orow + 1024 + c) = lo;
}

// ---------------- act split [hi|lo] from fp32 (stride 2048) ----------------
__global__ __launch_bounds__(256) void split_act_kernel(const float* __restrict__ in,
                                                        ushort* __restrict__ out) {
  const int idx = blockIdx.x*256 + threadIdx.x;
  const int row = idx >> 8;
  const int col4 = (idx & 255) << 2;
  const float4 a = *(const float4*)(in + (size_t)row*1024 + col4);
  ushort4 hi, lo;
  hi.x = f2bf(a.x); hi.y = f2bf(a.y); hi.z = f2bf(a.z); hi.w = f2bf(a.w);
  lo.x = f2bf(a.x - bf2f(hi.x)); lo.y = f2bf(a.y - bf2f(hi.y));
  lo.z = f2bf(a.z - bf2f(hi.z)); lo.w = f2bf(a.w - bf2f(hi.w));
  ushort* orow = out + (size_t)row*2048;
  *(ushort4*)(orow + col4)        = hi;
  *(ushort4*)(orow + 1024 + col4) = lo;
}

// ------- weight split [hi|lo] for Wq/Wk/Wv stacked (3072 rows) + bias concat -----
__global__ __launch_bounds__(256) void split_w3_kernel(const float* __restrict__ Wq,
                                                       const float* __restrict__ Wk,
                                                       const float* __restrict__ Wv,
                                                       const float* __restrict__ bq,
                                                       const float* __restrict__ bv,
                                                       ushort* __restrict__ out,
                                                       float* __restrict__ biascat) {
  const int idx = blockIdx.x*256 + threadIdx.x;
  const int n = idx >> 8;
  const int col4 = (idx & 255) << 2;
  const float* src = (n < 1024) ? (Wq + (size_t)n*1024)
                   : (n < 2048) ? (Wk + (size_t)(n-1024)*1024)
                                : (Wv + (size_t)(n-2048)*1024);
  const float4 a = *(const float4*)(src + col4);
  ushort4 hi, lo;
  hi.x = f2bf(a.x); hi.y = f2bf(a.y); hi.z = f2bf(a.z); hi.w = f2bf(a.w);
  lo.x = f2bf(a.x - bf2f(hi.x)); lo.y = f2bf(a.y - bf2f(hi.y));
  lo.z = f2bf(a.z - bf2f(hi.z)); lo.w = f2bf(a.w - bf2f(hi.w));
  ushort* orow = out + (size_t)n*2048;
  *(ushort4*)(orow + col4)        = hi;
  *(ushort4*)(orow + 1024 + col4) = lo;
  if (idx < 3072)
    biascat[idx] = (idx < 1024) ? bq[idx] : (idx < 2048) ? 0.f : bv[idx-2048];
}

// ---------------- weight split [hi|lo] single 1024-row weight (Wo) ---------------
__global__ __launch_bounds__(256) void split_w1_kernel(const float* __restrict__ W,
                                                       ushort* __restrict__ out) {
  const int idx = blockIdx.x*256 + threadIdx.x;
  const int n = idx >> 8;
  const int col4 = (idx & 255) << 2;
  const float4 a = *(const float4*)(W + (size_t)n*1024 + col4);
  ushort4 hi, lo;
  hi.x = f2bf(a.x); hi.y = f2bf(a.y); hi.z = f2bf(a.z); hi.w = f2bf(a.w);
  lo.x = f2bf(a.x - bf2f(hi.x)); lo.y = f2bf(a.y - bf2f(hi.y));
  lo.z = f2bf(a.z - bf2f(hi.z)); lo.w = f2bf(a.w - bf2f(hi.w));
  ushort* orow = out + (size_t)n*2048;
  *(ushort4*)(orow + col4)        = hi;
  *(ushort4*)(orow + 1024 + col4) = lo;
}

// ---------------- plain fp32 -> bf16 convert ----------------
__global__ __launch_bounds__(256) void cvt_bf16_kernel(const float* __restrict__ in,
                                                       ushort* __restrict__ out,
                                                       int gprshift, int ostride, int ooff) {
  const int idx = blockIdx.x*256 + threadIdx.x;
  const int row = idx >> gprshift;
  const int col4 = (idx & ((1 << gprshift) - 1)) << 2;
  const int ncols = 4 << gprshift;
  const float4 a = *(const float4*)(in + (size_t)row*ncols + col4);
  ushort4 hi;
  hi.x = f2bf(a.x); hi.y = f2bf(a.y); hi.z = f2bf(a.z); hi.w = f2bf(a.w);
  *(ushort4*)(out + (size_t)row*ostride + ooff + col4) = hi;
}

// ---------------- QKV GEMM with fused split epilogue ----------------
// C = AhBh + AlBh + AhBl + bias (dual-panel bf16x3), N=3072.
// Epilogue: n<2048 -> Qsp/Ksp [hi|lo] rows; n>=2048 -> V transposed via LDS
// into Vth/Vtl[(b*16+h)*64+d][s].
__global__ __launch_bounds__(256) void mfma_gemm_qkv(
    const ushort* __restrict__ A, const ushort* __restrict__ Bw,
    const float* __restrict__ bias,
    ushort* __restrict__ Qsp, ushort* __restrict__ Ksp,
    ushort* __restrict__ Vth, ushort* __restrict__ Vtl, int Kh) {
  __shared__ __align__(16) ushort smem[17408];   // 34 KB: staging / V-transpose
  ushort* Ash = smem;
  ushort* Asl = smem + 4096;
  ushort* Bsh = smem + 8192;
  ushort* Bsl = smem + 12288;
  const int lda = 2*Kh;
  const int tid = threadIdx.x;
  const int bm = blockIdx.y * 128, bn = blockIdx.x * 128;
  const int wave = tid >> 6, lane = tid & 63;
  const int wm = wave >> 1, wn = wave & 1;
  const int lm = lane & 15, q = lane >> 4;
  const int lrow = lane >> 2;
  const int sw = (((lane & 3) ^ (lrow & 3)) << 3);

  f32x4 acc[4][4];
  #pragma unroll
  for (int i = 0; i < 4; i++)
    #pragma unroll
    for (int j = 0; j < 4; j++)
      acc[i][j] = (f32x4){0.f,0.f,0.f,0.f};

  const ushort* Agh = A  + (size_t)(bm + wave*32 + lrow)*lda + sw;
  const ushort* Agl = Agh + Kh;
  const ushort* Bgh = Bw + (size_t)(bn + wave*32 + lrow)*lda + sw;
  const ushort* Bgl = Bgh + Kh;
  const size_t r16a = (size_t)16*lda;
  ushort* AhD0 = &Ash[(wave*32)*32];      ushort* AhD1 = &Ash[(wave*32+16)*32];
  ushort* AlD0 = &Asl[(wave*32)*32];      ushort* AlD1 = &Asl[(wave*32+16)*32];
  ushort* BhD0 = &Bsh[(wave*32)*32];      ushort* BhD1 = &Bsh[(wave*32+16)*32];
  ushort* BlD0 = &Bsl[(wave*32)*32];      ushort* BlD1 = &Bsl[(wave*32+16)*32];
  const int rsw  = ((q ^ (lm & 3)) << 3);
  const int aoff = (wm*64 + lm)*32 + rsw;
  const int boff = (wn*64 + lm)*32 + rsw;

  for (int k0 = 0; k0 < Kh; k0 += 32) {
    __syncthreads();
    async_load16(Agh + k0, AhD0);
    async_load16(Agh + r16a + k0, AhD1);
    async_load16(Agl + k0, AlD0);
    async_load16(Agl + r16a + k0, AlD1);
    async_load16(Bgh + k0, BhD0);
    async_load16(Bgh + r16a + k0, BhD1);
    async_load16(Bgl + k0, BlD0);
    async_load16(Bgl + r16a + k0, BlD1);
    __syncthreads();
    short8 ah[4], al[4], bh[4], bl[4];
    #pragma unroll
    for (int mt = 0; mt < 4; mt++) {
      ah[mt] = *(const short8*)&Ash[aoff + mt*512];
      al[mt] = *(const short8*)&Asl[aoff + mt*512];
    }
    #pragma unroll
    for (int nt = 0; nt < 4; nt++) {
      bh[nt] = *(const short8*)&Bsh[boff + nt*512];
      bl[nt] = *(const short8*)&Bsl[boff + nt*512];
    }
    #pragma unroll
    for (int mt = 0; mt < 4; mt++)
      #pragma unroll
      for (int nt = 0; nt < 4; nt++) {
        f32x4 a = acc[mt][nt];
        a = MFMA16(ah[mt], bh[nt], a);
        a = MFMA16(al[mt], bh[nt], a);
        a = MFMA16(ah[mt], bl[nt], a);
        acc[mt][nt] = a;
      }
  }

  const int b = bm >> 10, s0 = bm & 1023;
  if (blockIdx.x < 16) {
    // ---- Q/K epilogue: [hi|lo] rows, 2B stores in 32B segments ----
    ushort* dst = (blockIdx.x < 8) ? Qsp : Ksp;
    const int h = ((bn + wn*64) >> 6) & 15;
    #pragma unroll
    for (int mt = 0; mt < 4; mt++) {
      #pragma unroll
      for (int nt = 0; nt < 4; nt++) {
        const int n = bn + wn*64 + nt*16 + lm;
        const int d = nt*16 + lm;
        const float bb = bias[n];
        #pragma unroll
        for (int reg = 0; reg < 4; reg++) {
          const int s = s0 + wm*64 + mt*16 + q*4 + reg;
          const float val = acc[mt][nt][reg] + bb;
          const ushort hi = f2bf(val);
          const ushort lo = f2bf(val - bf2f(hi));
          ushort* rp = dst + ((size_t)((b*16 + h)*1024 + s))*128;
          rp[d] = hi; rp[64 + d] = lo;
        }
      }
    }
  } else {
    // ---- V epilogue: LDS transpose, coalesced short8 writes ----
    ushort* Th = smem;            // [64][136] ushorts
    ushort* Tl = smem + 8704;
    #pragma unroll
    for (int c = 0; c < 2; c++) {
      __syncthreads();            // staging / prev chunk reads done
      if (wn == c) {
        #pragma unroll
        for (int mt = 0; mt < 4; mt++)
          #pragma unroll
          for (int nt = 0; nt < 4; nt++) {
            const int nl = nt*16 + lm;
            const float bb = bias[bn + c*64 + nl];
            #pragma unroll
            for (int reg = 0; reg < 4; reg++) {
              const int sl = wm*64 + mt*16 + q*4 + reg;
              const float val = acc[mt][nt][reg] + bb;
              const ushort hi = f2bf(val);
              const ushort lo = f2bf(val - bf2f(hi));
              Th[nl*136 + sl] = hi;
              Tl[nl*136 + sl] = lo;
            }
          }
      }
      __syncthreads();
      const int nl = tid >> 2, s32 = (tid & 3)*32;
      const int h = ((bn - 2048 + c*64) >> 6) & 15;
      const size_t drow = ((size_t)((b*16 + h)*64 + nl))*1024 + s0 + s32;
      #pragma unroll
      for (int j = 0; j < 4; j++) {
        *(short8*)(Vth + drow + j*8) = *(const short8*)&Th[nl*136 + s32 + j*8];
        *(short8*)(Vtl + drow + j*8) = *(const short8*)&Tl[nl*136 + s32 + j*8];
      }
    }
  }
}

// ---------------- dual-panel bf16x3 MFMA GEMM (+optional aux bf16 out) ----------
__global__ __launch_bounds__(256) void mfma_gemm2(
    const ushort* __restrict__ A, const ushort* __restrict__ Bw,
    const float* __restrict__ bias, float* __restrict__ C,
    int Kh, int ldc, ushort* __restrict__ aux) {
  __shared__ __align__(16) ushort Ash[128*32];
  __shared__ __align__(16) ushort Asl[128*32];
  __shared__ __align__(16) ushort Bsh[128*32];
  __shared__ __align__(16) ushort Bsl[128*32];
  const int lda = 2*Kh;
  const int tid = threadIdx.x;
  const int bm = blockIdx.y * 128, bn = blockIdx.x * 128;
  const int wave = tid >> 6, lane = tid & 63;
  const int wm = wave >> 1, wn = wave & 1;
  const int lm = lane & 15, q = lane >> 4;
  const int lrow = lane >> 2;
  const int sw = (((lane & 3) ^ (lrow & 3)) << 3);

  f32x4 acc[4][4];
  #pragma unroll
  for (int i = 0; i < 4; i++)
    #pragma unroll
    for (int j = 0; j < 4; j++)
      acc[i][j] = (f32x4){0.f,0.f,0.f,0.f};

  const ushort* Agh = A  + (size_t)(bm + wave*32 + lrow)*lda + sw;
  const ushort* Agl = Agh + Kh;
  const ushort* Bgh = Bw + (size_t)(bn + wave*32 + lrow)*lda + sw;
  const ushort* Bgl = Bgh + Kh;
  const size_t r16a = (size_t)16*lda;
  ushort* AhD0 = &Ash[(wave*32)*32];      ushort* AhD1 = &Ash[(wave*32+16)*32];
  ushort* AlD0 = &Asl[(wave*32)*32];      ushort* AlD1 = &Asl[(wave*32+16)*32];
  ushort* BhD0 = &Bsh[(wave*32)*32];      ushort* BhD1 = &Bsh[(wave*32+16)*32];
  ushort* BlD0 = &Bsl[(wave*32)*32];      ushort* BlD1 = &Bsl[(wave*32+16)*32];
  const int rsw  = ((q ^ (lm & 3)) << 3);
  const int aoff = (wm*64 + lm)*32 + rsw;
  const int boff = (wn*64 + lm)*32 + rsw;

  for (int k0 = 0; k0 < Kh; k0 += 32) {
    __syncthreads();
    async_load16(Agh + k0, AhD0);
    async_load16(Agh + r16a + k0, AhD1);
    async_load16(Agl + k0, AlD0);
    async_load16(Agl + r16a + k0, AlD1);
    async_load16(Bgh + k0, BhD0);
    async_load16(Bgh + r16a + k0, BhD1);
    async_load16(Bgl + k0, BlD0);
    async_load16(Bgl + r16a + k0, BlD1);
    __syncthreads();
    short8 ah[4], al[4], bh[4], bl[4];
    #pragma unroll
    for (int mt = 0; mt < 4; mt++) {
      ah[mt] = *(const short8*)&Ash[aoff + mt*512];
      al[mt] = *(const short8*)&Asl[aoff + mt*512];
    }
    #pragma unroll
    for (int nt = 0; nt < 4; nt++) {
      bh[nt] = *(const short8*)&Bsh[boff + nt*512];
      bl[nt] = *(const short8*)&Bsl[boff + nt*512];
    }
    #pragma unroll
    for (int mt = 0; mt < 4; mt++)
      #pragma unroll
      for (int nt = 0; nt < 4; nt++) {
        f32x4 a = acc[mt][nt];
        a = MFMA16(ah[mt], bh[nt], a);
        a = MFMA16(al[mt], bh[nt], a);
        a = MFMA16(ah[mt], bl[nt], a);
        acc[mt][nt] = a;
      }
  }

  #pragma unroll
  for (int mt = 0; mt < 4; mt++) {
    #pragma unroll
    for (int nt = 0; nt < 4; nt++) {
      const int n = bn + wn*64 + nt*16 + lm;
      const float bb = bias ? bias[n] : 0.f;
      #pragma unroll
      for (int reg = 0; reg < 4; reg++) {
        const int m = bm + wm*64 + mt*16 + q*4 + reg;
        const float val = acc[mt][nt][reg] + bb;
        C[(size_t)m*ldc + n] = val;
        if (aux) aux[(size_t)m*2048 + 1024 + n] = f2bf(val);
      }
    }
  }
}

// ---------------- plain bf16 MFMA GEMM (final projection), swizzled --------------
__global__ __launch_bounds__(256) void mfma_gemm(
    const ushort* __restrict__ A, const ushort* __restrict__ Bw,
    const float* __restrict__ bias, float* __restrict__ C,
    int K, int ldc) {
  __shared__ __align__(16) ushort As[128*32];
  __shared__ __align__(16) ushort Bs[128*32];
  const int tid = threadIdx.x;
  const int bm = blockIdx.y * 128, bn = blockIdx.x * 128;
  const int wave = tid >> 6, lane = tid & 63;
  const int wm = wave >> 1, wn = wave & 1;
  const int lm = lane & 15, q = lane >> 4;
  const int lrow = lane >> 2;
  const int sw = (((lane & 3) ^ (lrow & 3)) << 3);

  f32x4 acc[4][4];
  #pragma unroll
  for (int i = 0; i < 4; i++)
    #pragma unroll
    for (int j = 0; j < 4; j++)
      acc[i][j] = (f32x4){0.f,0.f,0.f,0.f};

  const ushort* Ar0 = A  + (size_t)(bm + wave*32 + lrow)*K + sw;
  const ushort* Br0 = Bw + (size_t)(bn + wave*32 + lrow)*K + sw;
  const size_t r16 = (size_t)16*K;
  ushort* AsD0 = &As[(wave*32)*32];
  ushort* AsD1 = &As[(wave*32 + 16)*32];
  ushort* BsD0 = &Bs[(wave*32)*32];
  ushort* BsD1 = &Bs[(wave*32 + 16)*32];
  const int rsw  = ((q ^ (lm & 3)) << 3);
  const int aoff0 = (wm*64 + lm)*32 + rsw;
  const int boff0 = (wn*64 + lm)*32 + rsw;

  for (int k0 = 0; k0 < K; k0 += 32) {
    __syncthreads();
    async_load16(Ar0 + k0, AsD0);
    async_load16(Ar0 + r16 + k0, AsD1);
    async_load16(Br0 + k0, BsD0);
    async_load16(Br0 + r16 + k0, BsD1);
    __syncthreads();
    short8 af[4], bf[4];
    #pragma unroll
    for (int mt = 0; mt < 4; mt++) af[mt] = *(const short8*)&As[aoff0 + mt*512];
    #pragma unroll
    for (int nt = 0; nt < 4; nt++) bf[nt] = *(const short8*)&Bs[boff0 + nt*512];
    #pragma unroll
    for (int mt = 0; mt < 4; mt++)
      #pragma unroll
      for (int nt = 0; nt < 4; nt++)
        acc[mt][nt] = MFMA16(af[mt], bf[nt], acc[mt][nt]);
  }

  #pragma unroll
  for (int mt = 0; mt < 4; mt++) {
    #pragma unroll
    for (int nt = 0; nt < 4; nt++) {
      const int n = bn + wn*64 + nt*16 + lm;
      const float bb = bias ? bias[n] : 0.f;
      #pragma unroll
      for (int reg = 0; reg < 4; reg++) {
        const int m = bm + wm*64 + mt*16 + q*4 + reg;
        C[(size_t)m*ldc + n] = acc[mt][nt][reg] + bb;
      }
    }
  }
}

// ---------------- MFMA causal flash attention (2 barriers/kt) --------------------
__global__ __launch_bounds__(256) void gattn_mfma(
    const ushort* __restrict__ Qsp, const ushort* __restrict__ Ksp,
    const ushort* __restrict__ Vth, const ushort* __restrict__ Vtl,
    float* __restrict__ O) {
  __shared__ __align__(16) ushort Kc[64*136];
  __shared__ __align__(16) ushort Vc[64*136];
  __shared__ __align__(16) float  Pf[64*66];     // wave-private rows: no barriers
  const int bh = blockIdx.y;
  const int b = bh >> 4, h = bh & 15;
  const int tid = threadIdx.x;
  const int w = tid >> 6, lane = tid & 63;
  const int lm = lane & 15, q = lane >> 4;
  const ushort* Qb_ = Qsp + (size_t)bh * (1024*128);
  const ushort* Kb_ = Ksp + (size_t)bh * (1024*128);
  const ushort* Vhb = Vth + (size_t)bh * (64*1024);
  const ushort* Vlb = Vtl + (size_t)bh * (64*1024);

  for (int half = 0; half < 2; ++half) {
    const int qt = half ? blockIdx.x : 15 - blockIdx.x;
    short8 qh[2], ql[2];
    {
      const ushort* qr = Qb_ + (size_t)(qt*64 + w*16 + lm)*128 + q*8;
      qh[0] = *(const short8*)(qr);
      qh[1] = *(const short8*)(qr + 32);
      ql[0] = *(const short8*)(qr + 64);
      ql[1] = *(const short8*)(qr + 96);
    }
    f32x4 of[4];
    float mst[4], lst[4];
    #pragma unroll
    for (int nt = 0; nt < 4; nt++) of[nt] = (f32x4){0.f,0.f,0.f,0.f};
    #pragma unroll
    for (int rm = 0; rm < 4; rm++) { mst[rm] = -INFINITY; lst[rm] = 0.f; }
    const int nkt = qt + 1;
    for (int kt = 0; kt < nkt; ++kt) {
      __syncthreads();                 // (A) prior iter's Kc/Vc reads done
      #pragma unroll
      for (int i = 0; i < 4; i++) {
        const int slot = i*256 + tid;  // 0..1023: 64 rows x 16 chunks of 8
        const int row = slot >> 4, c8 = slot & 15;
        *(float4*)&Kc[row*136 + c8*8] =
            *(const float4*)(Kb_ + (size_t)(kt*64 + row)*128 + c8*8);
        const ushort* vsrc = ((c8 < 8) ? Vhb : Vlb) + (size_t)row*1024 + kt*64 + (c8&7)*8;
        *(float4*)&Vc[row*136 + c8*8] = *(const float4*)vsrc;
      }
      __syncthreads();                 // (B) staging visible
      f32x4 sS[4];
      #pragma unroll
      for (int nt = 0; nt < 4; nt++) {
        const ushort* kr = &Kc[(nt*16 + lm)*136 + q*8];
        const short8 kh0 = *(const short8*)(kr);
        const short8 kh1 = *(const short8*)(kr + 32);
        const short8 kl0 = *(const short8*)(kr + 64);
        const short8 kl1 = *(const short8*)(kr + 96);
        f32x4 a = (f32x4){0.f,0.f,0.f,0.f};
        a = MFMA16(qh[0], kh0, a);
        a = MFMA16(ql[0], kh0, a);
        a = MFMA16(qh[0], kl0, a);
        a = MFMA16(qh[1], kh1, a);
        a = MFMA16(ql[1], kh1, a);
        a = MFMA16(qh[1], kl1, a);
        sS[nt] = a;
      }
      const int ktbase = kt*64;
      const int qrow0 = qt*64 + w*16 + q*4;
      #pragma unroll
      for (int rm = 0; rm < 4; rm++) {
        const int qrow = qrow0 + rm;
        float v[4];
        #pragma unroll
        for (int nt = 0; nt < 4; nt++) {
          const int kcol = ktbase + nt*16 + lm;
          const float x = sS[nt][rm]*0.125f;
          v[nt] = (kcol <= qrow) ? x : -INFINITY;
        }
        float tm = fmaxf(fmaxf(v[0],v[1]), fmaxf(v[2],v[3]));
        #pragma unroll
        for (int off = 1; off < 16; off <<= 1) tm = fmaxf(tm, __shfl_xor(tm, off, 64));
        const float nm = fmaxf(mst[rm], tm);
        const float alpha = __expf(mst[rm] - nm);
        float ps = 0.f;
        #pragma unroll
        for (int nt = 0; nt < 4; nt++) {
          float p = __expf(v[nt] - nm);
          sS[nt][rm] = p;
          ps += p;
        }
        #pragma unroll
        for (int off = 1; off < 16; off <<= 1) ps += __shfl_xor(ps, off, 64);
        lst[rm] = lst[rm]*alpha + ps;
        mst[rm] = nm;
        #pragma unroll
        for (int nt = 0; nt < 4; nt++) of[nt][rm] *= alpha;
      }
      // P round-trip: wave-private Pf rows (w*16 .. w*16+15) — in-order LDS,
      // no cross-wave dependency, no barriers needed.
      #pragma unroll
      for (int rm = 0; rm < 4; rm++)
        #pragma unroll
        for (int nt = 0; nt < 4; nt++)
          Pf[(w*16 + q*4 + rm)*66 + nt*16 + lm] = sS[nt][rm];
      short8 ph[2], pl[2];
      {
        const float* prow = &Pf[(w*16 + lm)*66];
        float pv[16];
        *(float4*)&pv[0]  = *(const float4*)(prow + q*8);
        *(float4*)&pv[4]  = *(const float4*)(prow + q*8 + 4);
        *(float4*)&pv[8]  = *(const float4*)(prow + 32 + q*8);
        *(float4*)&pv[12] = *(const float4*)(prow + 32 + q*8 + 4);
        split8(&pv[0], &ph[0], &pl[0]);
        split8(&pv[8], &ph[1], &pl[1]);
      }
      #pragma unroll
      for (int nt = 0; nt < 4; nt++) {
        const ushort* vr = &Vc[(nt*16 + lm)*136 + q*8];
        const short8 vh0 = *(const short8*)(vr);
        const short8 vh1 = *(const short8*)(vr + 32);
        const short8 vl0 = *(const short8*)(vr + 64);
        const short8 vl1 = *(const short8*)(vr + 96);
        f32x4 a = of[nt];
        a = MFMA16(ph[0], vh0, a);
        a = MFMA16(pl[0], vh0, a);
        a = MFMA16(ph[0], vl0, a);
        a = MFMA16(ph[1], vh1, a);
        a = MFMA16(pl[1], vh1, a);
        a = MFMA16(ph[1], vl1, a);
        of[nt] = a;
      }
    }
    #pragma unroll
    for (int rm = 0; rm < 4; rm++) {
      const float inv = 1.0f / lst[rm];
      const int s = qt*64 + w*16 + q*4 + rm;
      float* orow = O + ((size_t)(b*1024 + s))*1024 + h*64;
      #pragma unroll
      for (int nt = 0; nt < 4; nt++)
        orow[nt*16 + lm] = of[nt][rm] * inv;
    }
  }
}

// ---------------- seq-mean, 2-stage deterministic ----------------
__global__ __launch_bounds__(256) void seqmean1_kernel(const float* __restrict__ g,
                                                       float* __restrict__ part) {
  const int d = blockIdx.x*256 + threadIdx.x;
  const int sc = blockIdx.y;
  const int b = blockIdx.z;
  const float* p = g + ((size_t)b*S_ + sc*128)*D_ + d;
  float s = 0.f;
  #pragma unroll 4
  for (int i = 0; i < 128; i++) s += p[(size_t)i*D_];
  part[((size_t)(b*8 + sc))*D_ + d] = s;
}
__global__ __launch_bounds__(256) void seqmean2_kernel(const float* __restrict__ part,
                                                       float* __restrict__ mbd) {
  const int d = blockIdx.x*256 + threadIdx.x;
  const int b = blockIdx.y;
  float s = 0.f;
  #pragma unroll
  for (int i = 0; i < 8; i++) s += part[((size_t)(b*8 + i))*D_ + d];
  mbd[b*D_ + d] = s * (1.0f/S_);
}

// ---------------- predictor ----------------
__global__ __launch_bounds__(256) void predictor_kernel(
    const float* __restrict__ mbd, const float* __restrict__ Wp,
    const float* __restrict__ bp, float* __restrict__ fpar, int* __restrict__ ipar) {
  __shared__ float sbuf[4];
  __shared__ float sdots[4];
  const int tid = threadIdx.x;
  for (int b = 0; b < 4; b++) {
    float psum = 0.f;
    for (int d = tid; d < D_; d += 256) psum += mbd[b*D_ + d]*Wp[d];
    float tot = block_reduce_sum_256(psum, sbuf);
    if (tid == 0) sdots[b] = tot;
  }
  __syncthreads();
  if (tid == 0) {
    float smv = 0.f;
    for (int b = 0; b < 4; b++) {
      float z = sdots[b] + bp[0];
      smv += 1.0f/(1.0f + expf(-z));
    }
    smv *= 0.25f;
    int win = max(1, (int)(256.0f*smv));
    int span_len = max(1, (int)(512.0f*smv));
    int local_max = min(512, min(span_len, win));
    float temp = 1.0f + 0.01f*(1.0f - smv);
    int n_win = (S_ + win - 1)/win;
    fpar[0] = smv; fpar[1] = temp;
    ipar[0] = win; ipar[1] = span_len; ipar[2] = local_max; ipar[3] = n_win;
  }
}

// -------- dynamic sliding-window span attention (fp32 -> bf16 out, self-zeroing) --
#define LDP 68
__global__ __launch_bounds__(256) void lattn_kernel(
    const float* __restrict__ Lc, ushort* __restrict__ Out,
    const int* __restrict__ ip, const float* __restrict__ fpp) {
  __shared__ __align__(16) float Qs[HD_][LDP];
  __shared__ __align__(16) float KPs[64][LDP];
  __shared__ __align__(16) float Vs[64][LDP];
  const int n_win = ip[3];
  const int win = ip[0], span_len = ip[1], local_max = ip[2];
  const float sm = fpp[0], temp = fpp[1];
  const int bh = blockIdx.y;
  const int b = bh >> 4, h = bh & 15;
  const int tid = threadIdx.x;
  const int tx = tid & 15, ty = tid >> 4;
  const float sc = 0.35355339059327373f / temp;
  for (int w = blockIdx.x; w < n_win; w += gridDim.x) {
    const int st = w * win;
    const int en = min(st + win, S_); const int wlen = en - st;
    const int ks = max(0, st - span_len + win);
    const int ke = min(st + span_len, S_); const int klen = ke - ks;
    int eff = (int)((double)wlen * (double)sm);
    eff = min(min(eff, wlen), min(klen, local_max));
    if (eff > 0) {
      const int nt = (eff + 63) >> 6;
      for (int qt = 0; qt < nt; ++qt) {
        const int qn = min(64, eff - qt*64);
        __syncthreads();
        #pragma unroll
        for (int c = 0; c < 4; c++) {
          int f = tid + c*256;
          int r = f >> 4;
          int dc = (f & 15) << 2;
          float4 q4 = make_float4(0.f,0.f,0.f,0.f);
          if (r < qn) q4 = *(const float4*)(Lc + ((size_t)(b*S_ + st + qt*64 + r)) * D_ + h*HD_ + dc);
          Qs[dc+0][r]=q4.x; Qs[dc+1][r]=q4.y; Qs[dc+2][r]=q4.z; Qs[dc+3][r]=q4.w;
        }
        float o[4][4] = {{0.f,0.f,0.f,0.f},{0.f,0.f,0.f,0.f},{0.f,0.f,0.f,0.f},{0.f,0.f,0.f,0.f}};
        float mrow[4], lrow[4];
        #pragma unroll
        for (int i=0;i<4;i++){ mrow[i] = -INFINITY; lrow[i] = 0.f; }
        for (int kt = 0; kt < nt; ++kt) {
          const int kn = min(64, eff - kt*64);
          __syncthreads();
          #pragma unroll
          for (int c = 0; c < 4; c++) {
            int f = tid + c*256;
            int r = f >> 4;
            int dc = (f & 15) << 2;
            float4 k4 = make_float4(0.f,0.f,0.f,0.f);
            if (r < kn) k4 = *(const float4*)(Lc + ((size_t)(b*S_ + ks + kt*64 + r)) * D_ + h*HD_ + dc);
            KPs[dc+0][r]=k4.x; KPs[dc+1][r]=k4.y; KPs[dc+2][r]=k4.z; KPs[dc+3][r]=k4.w;
            *(float4*)&Vs[r][dc] = k4;
          }
          __syncthreads();
          float s[4][4] = {{0.f,0.f,0.f,0.f},{0.f,0.f,0.f,0.f},{0.f,0.f,0.f,0.f},{0.f,0.f,0.f,0.f}};
          #pragma unroll 8
          for (int d = 0; d < HD_; ++d) {
            const float4 a  = *(const float4*)&Qs[d][ty*4];
            const float4 bb = *(const float4*)&KPs[d][tx*4];
            const float av[4]={a.x,a.y,a.z,a.w};
            const float bv[4]={bb.x,bb.y,bb.z,bb.w};
            #pragma unroll
            for (int i=0;i<4;i++)
              #pragma unroll
              for (int j=0;j<4;j++)
                s[i][j] += av[i]*bv[j];
          }
          #pragma unroll
          for (int i=0;i<4;i++) {
            #pragma unroll
            for (int j=0;j<4;j++) {
              float lg = s[i][j]*sc;
              if (kt*64 + tx*4 + j >= eff) lg = -INFINITY;
              s[i][j] = lg;
            }
          }
          #pragma unroll
          for (int i=0;i<4;i++) {
            float tm = fmaxf(fmaxf(s[i][0],s[i][1]), fmaxf(s[i][2],s[i][3]));
            #pragma unroll
            for (int off=1; off<16; off<<=1) tm = fmaxf(tm, __shfl_xor(tm, off, 64));
            const float nm = fmaxf(mrow[i], tm);
            const float alpha = __expf(mrow[i]-nm);
            float ps = 0.f;
            #pragma unroll
            for (int j=0;j<4;j++){ float p = __expf(s[i][j]-nm); s[i][j]=p; ps += p; }
            #pragma unroll
            for (int off=1; off<16; off<<=1) ps += __shfl_xor(ps, off, 64);
            lrow[i] = lrow[i]*alpha + ps;
            mrow[i] = nm;
            #pragma unroll
            for (int j=0;j<4;j++) o[i][j] *= alpha;
          }
          __syncthreads();
          #pragma unroll
          for (int i=0;i<4;i++)
            #pragma unroll
            for (int j=0;j<4;j++)
              KPs[tx*4+j][ty*4+i] = s[i][j];
          __syncthreads();
          #pragma unroll 8
          for (int kk = 0; kk < 64; ++kk) {
            const float4 a  = *(const float4*)&KPs[kk][ty*4];
            const float4 bb = *(const float4*)&Vs[kk][tx*4];
            const float av[4]={a.x,a.y,a.z,a.w};
            const float bv[4]={bb.x,bb.y,bb.z,bb.w};
            #pragma unroll
            for (int i=0;i<4;i++)
              #pragma unroll
              for (int j=0;j<4;j++)
                o[i][j] += av[i]*bv[j];
          }
        }
        #pragma unroll
        for (int i=0;i<4;i++){
          const int r = ty*4 + i;
          if (r < qn) {
            const float inv = 1.0f / lrow[i];
            ushort4 ov;
            ov.x = f2bf(o[i][0]*inv); ov.y = f2bf(o[i][1]*inv);
            ov.z = f2bf(o[i][2]*inv); ov.w = f2bf(o[i][3]*inv);
            *(ushort4*)(Out + ((size_t)(b*S_ + st + qt*64 + r)) * 2048 + h*HD_ + tx*4) = ov;
          }
        }
      }
    }
    // zero-fill rows [max(eff,0), wlen) for this window/head (replaces memset)
    const ushort4 z = {0,0,0,0};
    for (int r = max(eff, 0) + ty; r < wlen; r += 16)
      *(ushort4*)(Out + ((size_t)(b*S_ + st + r)) * 2048 + h*HD_ + tx*4) = z;
  }
}

// ---------------- launch ----------------
extern "C" void kernel_launch(void* const* d_in, const int* in_sizes, int n_in,
                              void* d_out, int out_size, void* d_ws, size_t ws_size,
                              hipStream_t stream) {
  const float* x      = (const float*)d_in[0];
  const float* ln_a_g = (const float*)d_in[1];
  const float* ln_a_b = (const float*)d_in[2];
  const float* ln_b_g = (const float*)d_in[3];
  const float* ln_b_b = (const float*)d_in[4];
  const float* Wq     = (const float*)d_in[5];
  const float* bq     = (const float*)d_in[6];
  const float* Wk     = (const float*)d_in[7];
  const float* Wv     = (const float*)d_in[8];
  const float* bv     = (const float*)d_in[9];
  const float* Wo     = (const float*)d_in[10];
  const float* bo     = (const float*)d_in[11];
  const float* Wp     = (const float*)d_in[12];
  const float* bp     = (const float*)d_in[13];
  const float* Wproj  = (const float*)d_in[14];
  const float* bproj  = (const float*)d_in[15];
  float* out = (float*)d_out;
  float* ws  = (float*)d_ws;
  ushort* wsu = (ushort*)d_ws;

  // layout: first 50.3MB region holds Qsp/Ksp/Vth/Vtl (later A3/B3 overlay)
  ushort* Qsp = wsu;                         // [64*1024,128] 16.8MB
  ushort* Ksp = wsu + 8388608;               // [64*1024,128] 16.8MB
  ushort* Vth = wsu + 16777216;              // [64*64,1024]  8.4MB
  ushort* Vtl = wsu + 20971520;              // [64*64,1024]  8.4MB
  float* buf0 = ws + 12582912;               // [4096,1024] attn out
  float* glo  = ws + 16777216;               // [4096,1024] globe_out
  float* loc  = ws + 20971520;               // [4096,1024] LN_a out
  float* biascat = ws + 25165824;            // [3072]
  float* mbd  = biascat + 4096;
  float* fpar = mbd + 4096;
  int*   ipar = (int*)(fpar + 8);
  ushort* Acat  = (ushort*)(ws + 25182208);  // [4096,2048] bf16
  ushort* Bqkv  = Acat + 12582912;           // [3072,2048] bf16
  ushort* Bo    = Bqkv + 9437184;            // [1024,2048] bf16
  float*  part = (float*)Acat;               // [B*8,1024] fp32 (after Acat dead)
  ushort* A3  = wsu;                         // [4096,2048] overlays Qsp (dead)
  ushort* B3  = wsu + 8388608;               // [1024,2048] overlays Ksp (dead)

  const dim3 blk(256);

  // 1) LN_b(x) fused with [hi|lo] split -> Acat
  ln_split_kernel<<<dim3(B_*S_), blk, 0, stream>>>(x, ln_b_g, ln_b_b, Acat);
  // 2) weight split [hi|lo] + bias concat
  split_w3_kernel<<<dim3(3072), blk, 0, stream>>>(Wq, Wk, Wv, bq, bv, Bqkv, biascat);
  // 3) QKV GEMM with fused split epilogue -> Qsp/Ksp/Vth/Vtl
  mfma_gemm_qkv<<<dim3(24, 32), blk, 0, stream>>>(Acat, Bqkv, biascat,
                                                  Qsp, Ksp, Vth, Vtl, 1024);
  // 4) MFMA causal attention -> buf0
  gattn_mfma<<<dim3(8, 64), blk, 0, stream>>>(Qsp, Ksp, Vth, Vtl, buf0);
  // 5) globe_out = attn · Wo^T + bo (dual-panel bf16x3; aux bf16 -> A3[:,1024:])
  split_act_kernel<<<dim3(4096), blk, 0, stream>>>(buf0, Acat);
  split_w1_kernel<<<dim3(1024), blk, 0, stream>>>(Wo, Bo);
  mfma_gemm2<<<dim3(8, 32), blk, 0, stream>>>(Acat, Bo, bo, glo, 1024, 1024, A3);
  // 6) predictor (device-side)
  seqmean1_kernel<<<dim3(4, 8, B_), blk, 0, stream>>>(glo, part);
  seqmean2_kernel<<<dim3(4, B_), blk, 0, stream>>>(part, mbd);
  predictor_kernel<<<dim3(1), blk, 0, stream>>>(mbd, Wp, bp, fpar, ipar);
  // 7) local = LN_a(x) -> loc
  ln_kernel<<<dim3(B_*S_), blk, 0, stream>>>(x, ln_a_g, ln_a_b, loc);
  // 8) local attention -> A3[:, 0:1024] bf16 (self-zeroing; no memset)
  lattn_kernel<<<dim3(64, B_*H_), blk, 0, stream>>>(loc, A3, ipar, fpar);
  // 9) B3 = bf16(Wproj)
  cvt_bf16_kernel<<<dim3(2048), blk, 0, stream>>>(Wproj, B3, 9, 2048, 0);
  // 10) out = A3 · B3^T + bproj
  mfma_gemm<<<dim3(8, 32), blk, 0, stream>>>(A3, B3, bproj, out, 2048, 1024);
}

// Round 8
// 481.371 us; speedup vs baseline: 2.6765x; 1.0045x over previous
//
#include <hip/hip_runtime.h>
#include <math.h>

#define B_ 4
#define S_ 1024
#define D_ 1024
#define H_ 16
#define HD_ 64
#define BSD_ (B_*S_*D_)

using short8 = __attribute__((ext_vector_type(8))) short;
using f32x4  = __attribute__((ext_vector_type(4))) float;

#define MFMA16(a,b,c) __builtin_amdgcn_mfma_f32_16x16x32_bf16((a),(b),(c),0,0,0)

// ---------------- bf16 helpers (RNE) ----------------
__device__ __forceinline__ ushort f2bf(float f) {
  uint u = __float_as_uint(f);
  return (ushort)((u + 0x7fffu + ((u >> 16) & 1u)) >> 16);
}
__device__ __forceinline__ float bf2f(ushort h) {
  return __uint_as_float(((uint)h) << 16);
}
__device__ __forceinline__ void split8(const float* p, short8* hi, short8* lo) {
  #pragma unroll
  for (int j = 0; j < 8; j++) {
    ushort h = f2bf(p[j]);
    (*hi)[j] = (short)h;
    (*lo)[j] = (short)f2bf(p[j] - bf2f(h));
  }
}
// async global->LDS, 16B per lane; LDS dest = wave-uniform base + lane*16
__device__ __forceinline__ void async_load16(const ushort* g, ushort* l) {
  __builtin_amdgcn_global_load_lds(
      (const __attribute__((address_space(1))) unsigned int*)g,
      (__attribute__((address_space(3))) unsigned int*)l, 16, 0, 0);
}

// ---------------- block reduce (256 threads = 4 waves) ----------------
__device__ __forceinline__ float block_reduce_sum_256(float v, float* sbuf) {
  #pragma unroll
  for (int off = 32; off > 0; off >>= 1) v += __shfl_xor(v, off, 64);
  int lane = threadIdx.x & 63, wid = threadIdx.x >> 6;
  __syncthreads();
  if (lane == 0) sbuf[wid] = v;
  __syncthreads();
  return sbuf[0] + sbuf[1] + sbuf[2] + sbuf[3];
}

// ---------------- LayerNorm (fp32 out) ----------------
__global__ __launch_bounds__(256) void ln_kernel(const float* __restrict__ x,
                                                 const float* __restrict__ g,
                                                 const float* __restrict__ bta,
                                                 float* __restrict__ out) {
  __shared__ float sbuf[4];
  const int row = blockIdx.x;
  const float* xr = x + (size_t)row * D_;
  const int t = threadIdx.x;
  float v[4]; float s = 0.f;
  #pragma unroll
  for (int i = 0; i < 4; i++) { v[i] = xr[t + 256*i]; s += v[i]; }
  const float mean = block_reduce_sum_256(s, sbuf) * (1.0f/D_);
  float sq = 0.f;
  #pragma unroll
  for (int i = 0; i < 4; i++) { float d = v[i]-mean; sq += d*d; }
  const float var = block_reduce_sum_256(sq, sbuf) * (1.0f/D_);
  const float r = rsqrtf(var + 1e-5f);
  float* orow = out + (size_t)row * D_;
  #pragma unroll
  for (int i = 0; i < 4; i++) {
    int c = t + 256*i;
    orow[c] = (v[i]-mean)*r*g[c] + bta[c];
  }
}

// ---------------- fused LayerNorm + [hi|lo] split (stride 2048) ----------------
__global__ __launch_bounds__(256) void ln_split_kernel(const float* __restrict__ x,
                                                       const float* __restrict__ g,
                                                       const float* __restrict__ bta,
                                                       ushort* __restrict__ out) {
  __shared__ float sbuf[4];
  const int row = blockIdx.x;
  const int t = threadIdx.x;
  const int c = t*4;
  const float* xr = x + (size_t)row * D_;
  float4 v = *(const float4*)(xr + c);
  float s = v.x + v.y + v.z + v.w;
  const float mean = block_reduce_sum_256(s, sbuf) * (1.0f/D_);
  float4 dv = make_float4(v.x-mean, v.y-mean, v.z-mean, v.w-mean);
  float sq = dv.x*dv.x + dv.y*dv.y + dv.z*dv.z + dv.w*dv.w;
  const float var = block_reduce_sum_256(sq, sbuf) * (1.0f/D_);
  const float r = rsqrtf(var + 1e-5f);
  float4 gg = *(const float4*)(g + c);
  float4 bb = *(const float4*)(bta + c);
  float n[4];
  n[0] = dv.x*r*gg.x + bb.x; n[1] = dv.y*r*gg.y + bb.y;
  n[2] = dv.z*r*gg.z + bb.z; n[3] = dv.w*r*gg.w + bb.w;
  ushort4 hi, lo;
  hi.x = f2bf(n[0]); hi.y = f2bf(n[1]); hi.z = f2bf(n[2]); hi.w = f2bf(n[3]);
  lo.x = f2bf(n[0]-bf2f(hi.x)); lo.y = f2bf(n[1]-bf2f(hi.y));
  lo.z = f2bf(n[2]-bf2f(hi.z)); lo.w = f2bf(n[3]-bf2f(hi.w));
  ushort* orow = out + (size_t)row*2048;
  *(ushort4*)(orow + c)        = hi;
  *(ushort4*)(orow + 1024 + c) = lo;
}

// ---------------- act split [hi|lo] from fp32 (stride 2048) ----------------
__global__ __launch_bounds__(256) void split_act_kernel(const float* __restrict__ in,
                                                        ushort* __restrict__ out) {
  const int idx = blockIdx.x*256 + threadIdx.x;
  const int row = idx >> 8;
  const int col4 = (idx & 255) << 2;
  const float4 a = *(const float4*)(in + (size_t)row*1024 + col4);
  ushort4 hi, lo;
  hi.x = f2bf(a.x); hi.y = f2bf(a.y); hi.z = f2bf(a.z); hi.w = f2bf(a.w);
  lo.x = f2bf(a.x - bf2f(hi.x)); lo.y = f2bf(a.y - bf2f(hi.y));
  lo.z = f2bf(a.z - bf2f(hi.z)); lo.w = f2bf(a.w - bf2f(hi.w));
  ushort* orow = out + (size_t)row*2048;
  *(ushort4*)(orow + col4)        = hi;
  *(ushort4*)(orow + 1024 + col4) = lo;
}

// ------- weight split [hi|lo] for Wq/Wk/Wv stacked (3072 rows) + bias concat -----
__global__ __launch_bounds__(256) void split_w3_kernel(const float* __restrict__ Wq,
                                                       const float* __restrict__ Wk,
                                                       const float* __restrict__ Wv,
                                                       const float* __restrict__ bq,
                                                       const float* __restrict__ bv,
                                                       ushort* __restrict__ out,
                                                       float* __restrict__ biascat) {
  const int idx = blockIdx.x*256 + threadIdx.x;
  const int n = idx >> 8;
  const int col4 = (idx & 255) << 2;
  const float* src = (n < 1024) ? (Wq + (size_t)n*1024)
                   : (n < 2048) ? (Wk + (size_t)(n-1024)*1024)
                                : (Wv + (size_t)(n-2048)*1024);
  const float4 a = *(const float4*)(src + col4);
  ushort4 hi, lo;
  hi.x = f2bf(a.x); hi.y = f2bf(a.y); hi.z = f2bf(a.z); hi.w = f2bf(a.w);
  lo.x = f2bf(a.x - bf2f(hi.x)); lo.y = f2bf(a.y - bf2f(hi.y));
  lo.z = f2bf(a.z - bf2f(hi.z)); lo.w = f2bf(a.w - bf2f(hi.w));
  ushort* orow = out + (size_t)n*2048;
  *(ushort4*)(orow + col4)        = hi;
  *(ushort4*)(orow + 1024 + col4) = lo;
  if (idx < 3072)
    biascat[idx] = (idx < 1024) ? bq[idx] : (idx < 2048) ? 0.f : bv[idx-2048];
}

// ---------------- weight split [hi|lo] single 1024-row weight (Wo) ---------------
__global__ __launch_bounds__(256) void split_w1_kernel(const float* __restrict__ W,
                                                       ushort* __restrict__ out) {
  const int idx = blockIdx.x*256 + threadIdx.x;
  const int n = idx >> 8;
  const int col4 = (idx & 255) << 2;
  const float4 a = *(const float4*)(W + (size_t)n*1024 + col4);
  ushort4 hi, lo;
  hi.x = f2bf(a.x); hi.y = f2bf(a.y); hi.z = f2bf(a.z); hi.w = f2bf(a.w);
  lo.x = f2bf(a.x - bf2f(hi.x)); lo.y = f2bf(a.y - bf2f(hi.y));
  lo.z = f2bf(a.z - bf2f(hi.z)); lo.w = f2bf(a.w - bf2f(hi.w));
  ushort* orow = out + (size_t)n*2048;
  *(ushort4*)(orow + col4)        = hi;
  *(ushort4*)(orow + 1024 + col4) = lo;
}

// ---------------- plain fp32 -> bf16 convert ----------------
__global__ __launch_bounds__(256) void cvt_bf16_kernel(const float* __restrict__ in,
                                                       ushort* __restrict__ out,
                                                       int gprshift, int ostride, int ooff) {
  const int idx = blockIdx.x*256 + threadIdx.x;
  const int row = idx >> gprshift;
  const int col4 = (idx & ((1 << gprshift) - 1)) << 2;
  const int ncols = 4 << gprshift;
  const float4 a = *(const float4*)(in + (size_t)row*ncols + col4);
  ushort4 hi;
  hi.x = f2bf(a.x); hi.y = f2bf(a.y); hi.z = f2bf(a.z); hi.w = f2bf(a.w);
  *(ushort4*)(out + (size_t)row*ostride + ooff + col4) = hi;
}

// ---------------- QKV GEMM with fused split epilogue ----------------
// Swizzle: store lane fetches global chunk (lane&3)^((lane>>3)&3); read uses
// LDS chunk q^((lm>>1)&3) -> 2-way bank aliasing (free on gfx950, m136).
__global__ __launch_bounds__(256) void mfma_gemm_qkv(
    const ushort* __restrict__ A, const ushort* __restrict__ Bw,
    const float* __restrict__ bias,
    ushort* __restrict__ Qsp, ushort* __restrict__ Ksp,
    ushort* __restrict__ Vth, ushort* __restrict__ Vtl, int Kh) {
  __shared__ __align__(16) ushort smem[17408];   // 34 KB: staging / V-transpose
  ushort* Ash = smem;
  ushort* Asl = smem + 4096;
  ushort* Bsh = smem + 8192;
  ushort* Bsl = smem + 12288;
  const int lda = 2*Kh;
  const int tid = threadIdx.x;
  const int bm = blockIdx.y * 128, bn = blockIdx.x * 128;
  const int wave = tid >> 6, lane = tid & 63;
  const int wm = wave >> 1, wn = wave & 1;
  const int lm = lane & 15, q = lane >> 4;
  const int lrow = lane >> 2;
  const int sw = (((lane & 3) ^ ((lane >> 3) & 3)) << 3);

  f32x4 acc[4][4];
  #pragma unroll
  for (int i = 0; i < 4; i++)
    #pragma unroll
    for (int j = 0; j < 4; j++)
      acc[i][j] = (f32x4){0.f,0.f,0.f,0.f};

  const ushort* Agh = A  + (size_t)(bm + wave*32 + lrow)*lda + sw;
  const ushort* Agl = Agh + Kh;
  const ushort* Bgh = Bw + (size_t)(bn + wave*32 + lrow)*lda + sw;
  const ushort* Bgl = Bgh + Kh;
  const size_t r16a = (size_t)16*lda;
  ushort* AhD0 = &Ash[(wave*32)*32];      ushort* AhD1 = &Ash[(wave*32+16)*32];
  ushort* AlD0 = &Asl[(wave*32)*32];      ushort* AlD1 = &Asl[(wave*32+16)*32];
  ushort* BhD0 = &Bsh[(wave*32)*32];      ushort* BhD1 = &Bsh[(wave*32+16)*32];
  ushort* BlD0 = &Bsl[(wave*32)*32];      ushort* BlD1 = &Bsl[(wave*32+16)*32];
  const int rsw  = ((q ^ ((lm >> 1) & 3)) << 3);
  const int aoff = (wm*64 + lm)*32 + rsw;
  const int boff = (wn*64 + lm)*32 + rsw;

  for (int k0 = 0; k0 < Kh; k0 += 32) {
    __syncthreads();
    async_load16(Agh + k0, AhD0);
    async_load16(Agh + r16a + k0, AhD1);
    async_load16(Agl + k0, AlD0);
    async_load16(Agl + r16a + k0, AlD1);
    async_load16(Bgh + k0, BhD0);
    async_load16(Bgh + r16a + k0, BhD1);
    async_load16(Bgl + k0, BlD0);
    async_load16(Bgl + r16a + k0, BlD1);
    __syncthreads();
    short8 ah[4], al[4], bh[4], bl[4];
    #pragma unroll
    for (int mt = 0; mt < 4; mt++) {
      ah[mt] = *(const short8*)&Ash[aoff + mt*512];
      al[mt] = *(const short8*)&Asl[aoff + mt*512];
    }
    #pragma unroll
    for (int nt = 0; nt < 4; nt++) {
      bh[nt] = *(const short8*)&Bsh[boff + nt*512];
      bl[nt] = *(const short8*)&Bsl[boff + nt*512];
    }
    #pragma unroll
    for (int mt = 0; mt < 4; mt++)
      #pragma unroll
      for (int nt = 0; nt < 4; nt++) {
        f32x4 a = acc[mt][nt];
        a = MFMA16(ah[mt], bh[nt], a);
        a = MFMA16(al[mt], bh[nt], a);
        a = MFMA16(ah[mt], bl[nt], a);
        acc[mt][nt] = a;
      }
  }

  const int b = bm >> 10, s0 = bm & 1023;
  if (blockIdx.x < 16) {
    // ---- Q/K epilogue: [hi|lo] rows, 2B stores in 32B segments ----
    ushort* dst = (blockIdx.x < 8) ? Qsp : Ksp;
    const int h = ((bn + wn*64) >> 6) & 15;
    #pragma unroll
    for (int mt = 0; mt < 4; mt++) {
      #pragma unroll
      for (int nt = 0; nt < 4; nt++) {
        const int n = bn + wn*64 + nt*16 + lm;
        const int d = nt*16 + lm;
        const float bb = bias[n];
        #pragma unroll
        for (int reg = 0; reg < 4; reg++) {
          const int s = s0 + wm*64 + mt*16 + q*4 + reg;
          const float val = acc[mt][nt][reg] + bb;
          const ushort hi = f2bf(val);
          const ushort lo = f2bf(val - bf2f(hi));
          ushort* rp = dst + ((size_t)((b*16 + h)*1024 + s))*128;
          rp[d] = hi; rp[64 + d] = lo;
        }
      }
    }
  } else {
    // ---- V epilogue: LDS transpose, coalesced short8 writes ----
    ushort* Th = smem;            // [64][136] ushorts
    ushort* Tl = smem + 8704;
    #pragma unroll
    for (int c = 0; c < 2; c++) {
      __syncthreads();            // staging / prev chunk reads done
      if (wn == c) {
        #pragma unroll
        for (int mt = 0; mt < 4; mt++)
          #pragma unroll
          for (int nt = 0; nt < 4; nt++) {
            const int nl = nt*16 + lm;
            const float bb = bias[bn + c*64 + nl];
            #pragma unroll
            for (int reg = 0; reg < 4; reg++) {
              const int sl = wm*64 + mt*16 + q*4 + reg;
              const float val = acc[mt][nt][reg] + bb;
              const ushort hi = f2bf(val);
              const ushort lo = f2bf(val - bf2f(hi));
              Th[nl*136 + sl] = hi;
              Tl[nl*136 + sl] = lo;
            }
          }
      }
      __syncthreads();
      const int nl = tid >> 2, s32 = (tid & 3)*32;
      const int h = ((bn - 2048 + c*64) >> 6) & 15;
      const size_t drow = ((size_t)((b*16 + h)*64 + nl))*1024 + s0 + s32;
      #pragma unroll
      for (int j = 0; j < 4; j++) {
        *(short8*)(Vth + drow + j*8) = *(const short8*)&Th[nl*136 + s32 + j*8];
        *(short8*)(Vtl + drow + j*8) = *(const short8*)&Tl[nl*136 + s32 + j*8];
      }
    }
  }
}

// ---------------- dual-panel bf16x3 MFMA GEMM (+optional aux bf16 out) ----------
__global__ __launch_bounds__(256) void mfma_gemm2(
    const ushort* __restrict__ A, const ushort* __restrict__ Bw,
    const float* __restrict__ bias, float* __restrict__ C,
    int Kh, int ldc, ushort* __restrict__ aux) {
  __shared__ __align__(16) ushort Ash[128*32];
  __shared__ __align__(16) ushort Asl[128*32];
  __shared__ __align__(16) ushort Bsh[128*32];
  __shared__ __align__(16) ushort Bsl[128*32];
  const int lda = 2*Kh;
  const int tid = threadIdx.x;
  const int bm = blockIdx.y * 128, bn = blockIdx.x * 128;
  const int wave = tid >> 6, lane = tid & 63;
  const int wm = wave >> 1, wn = wave & 1;
  const int lm = lane & 15, q = lane >> 4;
  const int lrow = lane >> 2;
  const int sw = (((lane & 3) ^ ((lane >> 3) & 3)) << 3);

  f32x4 acc[4][4];
  #pragma unroll
  for (int i = 0; i < 4; i++)
    #pragma unroll
    for (int j = 0; j < 4; j++)
      acc[i][j] = (f32x4){0.f,0.f,0.f,0.f};

  const ushort* Agh = A  + (size_t)(bm + wave*32 + lrow)*lda + sw;
  const ushort* Agl = Agh + Kh;
  const ushort* Bgh = Bw + (size_t)(bn + wave*32 + lrow)*lda + sw;
  const ushort* Bgl = Bgh + Kh;
  const size_t r16a = (size_t)16*lda;
  ushort* AhD0 = &Ash[(wave*32)*32];      ushort* AhD1 = &Ash[(wave*32+16)*32];
  ushort* AlD0 = &Asl[(wave*32)*32];      ushort* AlD1 = &Asl[(wave*32+16)*32];
  ushort* BhD0 = &Bsh[(wave*32)*32];      ushort* BhD1 = &Bsh[(wave*32+16)*32];
  ushort* BlD0 = &Bsl[(wave*32)*32];      ushort* BlD1 = &Bsl[(wave*32+16)*32];
  const int rsw  = ((q ^ ((lm >> 1) & 3)) << 3);
  const int aoff = (wm*64 + lm)*32 + rsw;
  const int boff = (wn*64 + lm)*32 + rsw;

  for (int k0 = 0; k0 < Kh; k0 += 32) {
    __syncthreads();
    async_load16(Agh + k0, AhD0);
    async_load16(Agh + r16a + k0, AhD1);
    async_load16(Agl + k0, AlD0);
    async_load16(Agl + r16a + k0, AlD1);
    async_load16(Bgh + k0, BhD0);
    async_load16(Bgh + r16a + k0, BhD1);
    async_load16(Bgl + k0, BlD0);
    async_load16(Bgl + r16a + k0, BlD1);
    __syncthreads();
    short8 ah[4], al[4], bh[4], bl[4];
    #pragma unroll
    for (int mt = 0; mt < 4; mt++) {
      ah[mt] = *(const short8*)&Ash[aoff + mt*512];
      al[mt] = *(const short8*)&Asl[aoff + mt*512];
    }
    #pragma unroll
    for (int nt = 0; nt < 4; nt++) {
      bh[nt] = *(const short8*)&Bsh[boff + nt*512];
      bl[nt] = *(const short8*)&Bsl[boff + nt*512];
    }
    #pragma unroll
    for (int mt = 0; mt < 4; mt++)
      #pragma unroll
      for (int nt = 0; nt < 4; nt++) {
        f32x4 a = acc[mt][nt];
        a = MFMA16(ah[mt], bh[nt], a);
        a = MFMA16(al[mt], bh[nt], a);
        a = MFMA16(ah[mt], bl[nt], a);
        acc[mt][nt] = a;
      }
  }

  #pragma unroll
  for (int mt = 0; mt < 4; mt++) {
    #pragma unroll
    for (int nt = 0; nt < 4; nt++) {
      const int n = bn + wn*64 + nt*16 + lm;
      const float bb = bias ? bias[n] : 0.f;
      #pragma unroll
      for (int reg = 0; reg < 4; reg++) {
        const int m = bm + wm*64 + mt*16 + q*4 + reg;
        const float val = acc[mt][nt][reg] + bb;
        C[(size_t)m*ldc + n] = val;
        if (aux) aux[(size_t)m*2048 + 1024 + n] = f2bf(val);
      }
    }
  }
}

// ---------------- plain bf16 MFMA GEMM (final projection), swizzled --------------
__global__ __launch_bounds__(256) void mfma_gemm(
    const ushort* __restrict__ A, const ushort* __restrict__ Bw,
    const float* __restrict__ bias, float* __restrict__ C,
    int K, int ldc) {
  __shared__ __align__(16) ushort As[128*32];
  __shared__ __align__(16) ushort Bs[128*32];
  const int tid = threadIdx.x;
  const int bm = blockIdx.y * 128, bn = blockIdx.x * 128;
  const int wave = tid >> 6, lane = tid & 63;
  const int wm = wave >> 1, wn = wave & 1;
  const int lm = lane & 15, q = lane >> 4;
  const int lrow = lane >> 2;
  const int sw = (((lane & 3) ^ ((lane >> 3) & 3)) << 3);

  f32x4 acc[4][4];
  #pragma unroll
  for (int i = 0; i < 4; i++)
    #pragma unroll
    for (int j = 0; j < 4; j++)
      acc[i][j] = (f32x4){0.f,0.f,0.f,0.f};

  const ushort* Ar0 = A  + (size_t)(bm + wave*32 + lrow)*K + sw;
  const ushort* Br0 = Bw + (size_t)(bn + wave*32 + lrow)*K + sw;
  const size_t r16 = (size_t)16*K;
  ushort* AsD0 = &As[(wave*32)*32];
  ushort* AsD1 = &As[(wave*32 + 16)*32];
  ushort* BsD0 = &Bs[(wave*32)*32];
  ushort* BsD1 = &Bs[(wave*32 + 16)*32];
  const int rsw  = ((q ^ ((lm >> 1) & 3)) << 3);
  const int aoff0 = (wm*64 + lm)*32 + rsw;
  const int boff0 = (wn*64 + lm)*32 + rsw;

  for (int k0 = 0; k0 < K; k0 += 32) {
    __syncthreads();
    async_load16(Ar0 + k0, AsD0);
    async_load16(Ar0 + r16 + k0, AsD1);
    async_load16(Br0 + k0, BsD0);
    async_load16(Br0 + r16 + k0, BsD1);
    __syncthreads();
    short8 af[4], bf[4];
    #pragma unroll
    for (int mt = 0; mt < 4; mt++) af[mt] = *(const short8*)&As[aoff0 + mt*512];
    #pragma unroll
    for (int nt = 0; nt < 4; nt++) bf[nt] = *(const short8*)&Bs[boff0 + nt*512];
    #pragma unroll
    for (int mt = 0; mt < 4; mt++)
      #pragma unroll
      for (int nt = 0; nt < 4; nt++)
        acc[mt][nt] = MFMA16(af[mt], bf[nt], acc[mt][nt]);
  }

  #pragma unroll
  for (int mt = 0; mt < 4; mt++) {
    #pragma unroll
    for (int nt = 0; nt < 4; nt++) {
      const int n = bn + wn*64 + nt*16 + lm;
      const float bb = bias ? bias[n] : 0.f;
      #pragma unroll
      for (int reg = 0; reg < 4; reg++) {
        const int m = bm + wm*64 + mt*16 + q*4 + reg;
        C[(size_t)m*ldc + n] = acc[mt][nt][reg] + bb;
      }
    }
  }
}

// ---------------- MFMA causal flash attention (2 barriers/kt) --------------------
__global__ __launch_bounds__(256) void gattn_mfma(
    const ushort* __restrict__ Qsp, const ushort* __restrict__ Ksp,
    const ushort* __restrict__ Vth, const ushort* __restrict__ Vtl,
    float* __restrict__ O) {
  __shared__ __align__(16) ushort Kc[64*136];
  __shared__ __align__(16) ushort Vc[64*136];
  __shared__ __align__(16) float  Pf[64*66];     // wave-private rows: no barriers
  const int bh = blockIdx.y;
  const int b = bh >> 4, h = bh & 15;
  const int tid = threadIdx.x;
  const int w = tid >> 6, lane = tid & 63;
  const int lm = lane & 15, q = lane >> 4;
  const ushort* Qb_ = Qsp + (size_t)bh * (1024*128);
  const ushort* Kb_ = Ksp + (size_t)bh * (1024*128);
  const ushort* Vhb = Vth + (size_t)bh * (64*1024);
  const ushort* Vlb = Vtl + (size_t)bh * (64*1024);

  for (int half = 0; half < 2; ++half) {
    const int qt = half ? blockIdx.x : 15 - blockIdx.x;
    short8 qh[2], ql[2];
    {
      const ushort* qr = Qb_ + (size_t)(qt*64 + w*16 + lm)*128 + q*8;
      qh[0] = *(const short8*)(qr);
      qh[1] = *(const short8*)(qr + 32);
      ql[0] = *(const short8*)(qr + 64);
      ql[1] = *(const short8*)(qr + 96);
    }
    f32x4 of[4];
    float mst[4], lst[4];
    #pragma unroll
    for (int nt = 0; nt < 4; nt++) of[nt] = (f32x4){0.f,0.f,0.f,0.f};
    #pragma unroll
    for (int rm = 0; rm < 4; rm++) { mst[rm] = -INFINITY; lst[rm] = 0.f; }
    const int nkt = qt + 1;
    for (int kt = 0; kt < nkt; ++kt) {
      __syncthreads();                 // (A) prior iter's Kc/Vc reads done
      #pragma unroll
      for (int i = 0; i < 4; i++) {
        const int slot = i*256 + tid;  // 0..1023: 64 rows x 16 chunks of 8
        const int row = slot >> 4, c8 = slot & 15;
        *(float4*)&Kc[row*136 + c8*8] =
            *(const float4*)(Kb_ + (size_t)(kt*64 + row)*128 + c8*8);
        const ushort* vsrc = ((c8 < 8) ? Vhb : Vlb) + (size_t)row*1024 + kt*64 + (c8&7)*8;
        *(float4*)&Vc[row*136 + c8*8] = *(const float4*)vsrc;
      }
      __syncthreads();                 // (B) staging visible
      f32x4 sS[4];
      #pragma unroll
      for (int nt = 0; nt < 4; nt++) {
        const ushort* kr = &Kc[(nt*16 + lm)*136 + q*8];
        const short8 kh0 = *(const short8*)(kr);
        const short8 kh1 = *(const short8*)(kr + 32);
        const short8 kl0 = *(const short8*)(kr + 64);
        const short8 kl1 = *(const short8*)(kr + 96);
        f32x4 a = (f32x4){0.f,0.f,0.f,0.f};
        a = MFMA16(qh[0], kh0, a);
        a = MFMA16(ql[0], kh0, a);
        a = MFMA16(qh[0], kl0, a);
        a = MFMA16(qh[1], kh1, a);
        a = MFMA16(ql[1], kh1, a);
        a = MFMA16(qh[1], kl1, a);
        sS[nt] = a;
      }
      const int ktbase = kt*64;
      const int qrow0 = qt*64 + w*16 + q*4;
      #pragma unroll
      for (int rm = 0; rm < 4; rm++) {
        const int qrow = qrow0 + rm;
        float v[4];
        #pragma unroll
        for (int nt = 0; nt < 4; nt++) {
          const int kcol = ktbase + nt*16 + lm;
          const float x = sS[nt][rm]*0.125f;
          v[nt] = (kcol <= qrow) ? x : -INFINITY;
        }
        float tm = fmaxf(fmaxf(v[0],v[1]), fmaxf(v[2],v[3]));
        #pragma unroll
        for (int off = 1; off < 16; off <<= 1) tm = fmaxf(tm, __shfl_xor(tm, off, 64));
        const float nm = fmaxf(mst[rm], tm);
        const float alpha = __expf(mst[rm] - nm);
        float ps = 0.f;
        #pragma unroll
        for (int nt = 0; nt < 4; nt++) {
          float p = __expf(v[nt] - nm);
          sS[nt][rm] = p;
          ps += p;
        }
        #pragma unroll
        for (int off = 1; off < 16; off <<= 1) ps += __shfl_xor(ps, off, 64);
        lst[rm] = lst[rm]*alpha + ps;
        mst[rm] = nm;
        #pragma unroll
        for (int nt = 0; nt < 4; nt++) of[nt][rm] *= alpha;
      }
      // P round-trip: wave-private Pf rows — no barriers needed.
      #pragma unroll
      for (int rm = 0; rm < 4; rm++)
        #pragma unroll
        for (int nt = 0; nt < 4; nt++)
          Pf[(w*16 + q*4 + rm)*66 + nt*16 + lm] = sS[nt][rm];
      short8 ph[2], pl[2];
      {
        const float* prow = &Pf[(w*16 + lm)*66];
        float pv[16];
        *(float4*)&pv[0]  = *(const float4*)(prow + q*8);
        *(float4*)&pv[4]  = *(const float4*)(prow + q*8 + 4);
        *(float4*)&pv[8]  = *(const float4*)(prow + 32 + q*8);
        *(float4*)&pv[12] = *(const float4*)(prow + 32 + q*8 + 4);
        split8(&pv[0], &ph[0], &pl[0]);
        split8(&pv[8], &ph[1], &pl[1]);
      }
      #pragma unroll
      for (int nt = 0; nt < 4; nt++) {
        const ushort* vr = &Vc[(nt*16 + lm)*136 + q*8];
        const short8 vh0 = *(const short8*)(vr);
        const short8 vh1 = *(const short8*)(vr + 32);
        const short8 vl0 = *(const short8*)(vr + 64);
        const short8 vl1 = *(const short8*)(vr + 96);
        f32x4 a = of[nt];
        a = MFMA16(ph[0], vh0, a);
        a = MFMA16(pl[0], vh0, a);
        a = MFMA16(ph[0], vl0, a);
        a = MFMA16(ph[1], vh1, a);
        a = MFMA16(pl[1], vh1, a);
        a = MFMA16(ph[1], vl1, a);
        of[nt] = a;
      }
    }
    #pragma unroll
    for (int rm = 0; rm < 4; rm++) {
      const float inv = 1.0f / lst[rm];
      const int s = qt*64 + w*16 + q*4 + rm;
      float* orow = O + ((size_t)(b*1024 + s))*1024 + h*64;
      #pragma unroll
      for (int nt = 0; nt < 4; nt++)
        orow[nt*16 + lm] = of[nt][rm] * inv;
    }
  }
}

// ---------------- seq-mean, 2-stage deterministic ----------------
__global__ __launch_bounds__(256) void seqmean1_kernel(const float* __restrict__ g,
                                                       float* __restrict__ part) {
  const int d = blockIdx.x*256 + threadIdx.x;
  const int sc = blockIdx.y;
  const int b = blockIdx.z;
  const float* p = g + ((size_t)b*S_ + sc*128)*D_ + d;
  float s = 0.f;
  #pragma unroll 4
  for (int i = 0; i < 128; i++) s += p[(size_t)i*D_];
  part[((size_t)(b*8 + sc))*D_ + d] = s;
}
__global__ __launch_bounds__(256) void seqmean2_kernel(const float* __restrict__ part,
                                                       float* __restrict__ mbd) {
  const int d = blockIdx.x*256 + threadIdx.x;
  const int b = blockIdx.y;
  float s = 0.f;
  #pragma unroll
  for (int i = 0; i < 8; i++) s += part[((size_t)(b*8 + i))*D_ + d];
  mbd[b*D_ + d] = s * (1.0f/S_);
}

// ---------------- predictor ----------------
__global__ __launch_bounds__(256) void predictor_kernel(
    const float* __restrict__ mbd, const float* __restrict__ Wp,
    const float* __restrict__ bp, float* __restrict__ fpar, int* __restrict__ ipar) {
  __shared__ float sbuf[4];
  __shared__ float sdots[4];
  const int tid = threadIdx.x;
  for (int b = 0; b < 4; b++) {
    float psum = 0.f;
    for (int d = tid; d < D_; d += 256) psum += mbd[b*D_ + d]*Wp[d];
    float tot = block_reduce_sum_256(psum, sbuf);
    if (tid == 0) sdots[b] = tot;
  }
  __syncthreads();
  if (tid == 0) {
    float smv = 0.f;
    for (int b = 0; b < 4; b++) {
      float z = sdots[b] + bp[0];
      smv += 1.0f/(1.0f + expf(-z));
    }
    smv *= 0.25f;
    int win = max(1, (int)(256.0f*smv));
    int span_len = max(1, (int)(512.0f*smv));
    int local_max = min(512, min(span_len, win));
    float temp = 1.0f + 0.01f*(1.0f - smv);
    int n_win = (S_ + win - 1)/win;
    fpar[0] = smv; fpar[1] = temp;
    ipar[0] = win; ipar[1] = span_len; ipar[2] = local_max; ipar[3] = n_win;
  }
}

// -------- dynamic sliding-window span attention (fp32 -> bf16 out, self-zeroing) --
#define LDP 68
__global__ __launch_bounds__(256) void lattn_kernel(
    const float* __restrict__ Lc, ushort* __restrict__ Out,
    const int* __restrict__ ip, const float* __restrict__ fpp) {
  __shared__ __align__(16) float Qs[HD_][LDP];
  __shared__ __align__(16) float KPs[64][LDP];
  __shared__ __align__(16) float Vs[64][LDP];
  const int n_win = ip[3];
  const int win = ip[0], span_len = ip[1], local_max = ip[2];
  const float sm = fpp[0], temp = fpp[1];
  const int bh = blockIdx.y;
  const int b = bh >> 4, h = bh & 15;
  const int tid = threadIdx.x;
  const int tx = tid & 15, ty = tid >> 4;
  const float sc = 0.35355339059327373f / temp;
  for (int w = blockIdx.x; w < n_win; w += gridDim.x) {
    const int st = w * win;
    const int en = min(st + win, S_); const int wlen = en - st;
    const int ks = max(0, st - span_len + win);
    const int ke = min(st + span_len, S_); const int klen = ke - ks;
    int eff = (int)((double)wlen * (double)sm);
    eff = min(min(eff, wlen), min(klen, local_max));
    if (eff > 0) {
      const int nt = (eff + 63) >> 6;
      for (int qt = 0; qt < nt; ++qt) {
        const int qn = min(64, eff - qt*64);
        __syncthreads();
        #pragma unroll
        for (int c = 0; c < 4; c++) {
          int f = tid + c*256;
          int r = f >> 4;
          int dc = (f & 15) << 2;
          float4 q4 = make_float4(0.f,0.f,0.f,0.f);
          if (r < qn) q4 = *(const float4*)(Lc + ((size_t)(b*S_ + st + qt*64 + r)) * D_ + h*HD_ + dc);
          Qs[dc+0][r]=q4.x; Qs[dc+1][r]=q4.y; Qs[dc+2][r]=q4.z; Qs[dc+3][r]=q4.w;
        }
        float o[4][4] = {{0.f,0.f,0.f,0.f},{0.f,0.f,0.f,0.f},{0.f,0.f,0.f,0.f},{0.f,0.f,0.f,0.f}};
        float mrow[4], lrow[4];
        #pragma unroll
        for (int i=0;i<4;i++){ mrow[i] = -INFINITY; lrow[i] = 0.f; }
        for (int kt = 0; kt < nt; ++kt) {
          const int kn = min(64, eff - kt*64);
          __syncthreads();
          #pragma unroll
          for (int c = 0; c < 4; c++) {
            int f = tid + c*256;
            int r = f >> 4;
            int dc = (f & 15) << 2;
            float4 k4 = make_float4(0.f,0.f,0.f,0.f);
            if (r < kn) k4 = *(const float4*)(Lc + ((size_t)(b*S_ + ks + kt*64 + r)) * D_ + h*HD_ + dc);
            KPs[dc+0][r]=k4.x; KPs[dc+1][r]=k4.y; KPs[dc+2][r]=k4.z; KPs[dc+3][r]=k4.w;
            *(float4*)&Vs[r][dc] = k4;
          }
          __syncthreads();
          float s[4][4] = {{0.f,0.f,0.f,0.f},{0.f,0.f,0.f,0.f},{0.f,0.f,0.f,0.f},{0.f,0.f,0.f,0.f}};
          #pragma unroll 8
          for (int d = 0; d < HD_; ++d) {
            const float4 a  = *(const float4*)&Qs[d][ty*4];
            const float4 bb = *(const float4*)&KPs[d][tx*4];
            const float av[4]={a.x,a.y,a.z,a.w};
            const float bv[4]={bb.x,bb.y,bb.z,bb.w};
            #pragma unroll
            for (int i=0;i<4;i++)
              #pragma unroll
              for (int j=0;j<4;j++)
                s[i][j] += av[i]*bv[j];
          }
          #pragma unroll
          for (int i=0;i<4;i++) {
            #pragma unroll
            for (int j=0;j<4;j++) {
              float lg = s[i][j]*sc;
              if (kt*64 + tx*4 + j >= eff) lg = -INFINITY;
              s[i][j] = lg;
            }
          }
          #pragma unroll
          for (int i=0;i<4;i++) {
            float tm = fmaxf(fmaxf(s[i][0],s[i][1]), fmaxf(s[i][2],s[i][3]));
            #pragma unroll
            for (int off=1; off<16; off<<=1) tm = fmaxf(tm, __shfl_xor(tm, off, 64));
            const float nm = fmaxf(mrow[i], tm);
            const float alpha = __expf(mrow[i]-nm);
            float ps = 0.f;
            #pragma unroll
            for (int j=0;j<4;j++){ float p = __expf(s[i][j]-nm); s[i][j]=p; ps += p; }
            #pragma unroll
            for (int off=1; off<16; off<<=1) ps += __shfl_xor(ps, off, 64);
            lrow[i] = lrow[i]*alpha + ps;
            mrow[i] = nm;
            #pragma unroll
            for (int j=0;j<4;j++) o[i][j] *= alpha;
          }
          __syncthreads();
          #pragma unroll
          for (int i=0;i<4;i++)
            #pragma unroll
            for (int j=0;j<4;j++)
              KPs[tx*4+j][ty*4+i] = s[i][j];
          __syncthreads();
          #pragma unroll 8
          for (int kk = 0; kk < 64; ++kk) {
            const float4 a  = *(const float4*)&KPs[kk][ty*4];
            const float4 bb = *(const float4*)&Vs[kk][tx*4];
            const float av[4]={a.x,a.y,a.z,a.w};
            const float bv[4]={bb.x,bb.y,bb.z,bb.w};
            #pragma unroll
            for (int i=0;i<4;i++)
              #pragma unroll
              for (int j=0;j<4;j++)
                o[i][j] += av[i]*bv[j];
          }
        }
        #pragma unroll
        for (int i=0;i<4;i++){
          const int r = ty*4 + i;
          if (r < qn) {
            const float inv = 1.0f / lrow[i];
            ushort4 ov;
            ov.x = f2bf(o[i][0]*inv); ov.y = f2bf(o[i][1]*inv);
            ov.z = f2bf(o[i][2]*inv); ov.w = f2bf(o[i][3]*inv);
            *(ushort4*)(Out + ((size_t)(b*S_ + st + qt*64 + r)) * 2048 + h*HD_ + tx*4) = ov;
          }
        }
      }
    }
    // zero-fill rows [max(eff,0), wlen) for this window/head (replaces memset)
    const ushort4 z = {0,0,0,0};
    for (int r = max(eff, 0) + ty; r < wlen; r += 16)
      *(ushort4*)(Out + ((size_t)(b*S_ + st + r)) * 2048 + h*HD_ + tx*4) = z;
  }
}

// ---------------- launch ----------------
extern "C" void kernel_launch(void* const* d_in, const int* in_sizes, int n_in,
                              void* d_out, int out_size, void* d_ws, size_t ws_size,
                              hipStream_t stream) {
  const float* x      = (const float*)d_in[0];
  const float* ln_a_g = (const float*)d_in[1];
  const float* ln_a_b = (const float*)d_in[2];
  const float* ln_b_g = (const float*)d_in[3];
  const float* ln_b_b = (const float*)d_in[4];
  const float* Wq     = (const float*)d_in[5];
  const float* bq     = (const float*)d_in[6];
  const float* Wk     = (const float*)d_in[7];
  const float* Wv     = (const float*)d_in[8];
  const float* bv     = (const float*)d_in[9];
  const float* Wo     = (const float*)d_in[10];
  const float* bo     = (const float*)d_in[11];
  const float* Wp     = (const float*)d_in[12];
  const float* bp     = (const float*)d_in[13];
  const float* Wproj  = (const float*)d_in[14];
  const float* bproj  = (const float*)d_in[15];
  float* out = (float*)d_out;
  float* ws  = (float*)d_ws;
  ushort* wsu = (ushort*)d_ws;

  // layout: first 50.3MB region holds Qsp/Ksp/Vth/Vtl (later A3/B3 overlay)
  ushort* Qsp = wsu;                         // [64*1024,128] 16.8MB
  ushort* Ksp = wsu + 8388608;               // [64*1024,128] 16.8MB
  ushort* Vth = wsu + 16777216;              // [64*64,1024]  8.4MB
  ushort* Vtl = wsu + 20971520;              // [64*64,1024]  8.4MB
  float* buf0 = ws + 12582912;               // [4096,1024] attn out
  float* glo  = ws + 16777216;               // [4096,1024] globe_out
  float* loc  = ws + 20971520;               // [4096,1024] LN_a out
  float* biascat = ws + 25165824;            // [3072]
  float* mbd  = biascat + 4096;
  float* fpar = mbd + 4096;
  int*   ipar = (int*)(fpar + 8);
  ushort* Acat  = (ushort*)(ws + 25182208);  // [4096,2048] bf16
  ushort* Bqkv  = Acat + 12582912;           // [3072,2048] bf16
  ushort* Bo    = Bqkv + 9437184;            // [1024,2048] bf16
  float*  part = (float*)Acat;               // [B*8,1024] fp32 (after Acat dead)
  ushort* A3  = wsu;                         // [4096,2048] overlays Qsp (dead)
  ushort* B3  = wsu + 8388608;               // [1024,2048] overlays Ksp (dead)

  const dim3 blk(256);

  // 1) LN_b(x) fused with [hi|lo] split -> Acat
  ln_split_kernel<<<dim3(B_*S_), blk, 0, stream>>>(x, ln_b_g, ln_b_b, Acat);
  // 2) weight split [hi|lo] + bias concat
  split_w3_kernel<<<dim3(3072), blk, 0, stream>>>(Wq, Wk, Wv, bq, bv, Bqkv, biascat);
  // 3) QKV GEMM with fused split epilogue -> Qsp/Ksp/Vth/Vtl
  mfma_gemm_qkv<<<dim3(24, 32), blk, 0, stream>>>(Acat, Bqkv, biascat,
                                                  Qsp, Ksp, Vth, Vtl, 1024);
  // 4) MFMA causal attention -> buf0
  gattn_mfma<<<dim3(8, 64), blk, 0, stream>>>(Qsp, Ksp, Vth, Vtl, buf0);
  // 5) globe_out = attn · Wo^T + bo (dual-panel bf16x3; aux bf16 -> A3[:,1024:])
  split_act_kernel<<<dim3(4096), blk, 0, stream>>>(buf0, Acat);
  split_w1_kernel<<<dim3(1024), blk, 0, stream>>>(Wo, Bo);
  mfma_gemm2<<<dim3(8, 32), blk, 0, stream>>>(Acat, Bo, bo, glo, 1024, 1024, A3);
  // 6) predictor (device-side)
  seqmean1_kernel<<<dim3(4, 8, B_), blk, 0, stream>>>(glo, part);
  seqmean2_kernel<<<dim3(4, B_), blk, 0, stream>>>(part, mbd);
  predictor_kernel<<<dim3(1), blk, 0, stream>>>(mbd, Wp, bp, fpar, ipar);
  // 7) local = LN_a(x) -> loc
  ln_kernel<<<dim3(B_*S_), blk, 0, stream>>>(x, ln_a_g, ln_a_b, loc);
  // 8) local attention -> A3[:, 0:1024] bf16 (self-zeroing; no memset)
  lattn_kernel<<<dim3(64, B_*H_), blk, 0, stream>>>(loc, A3, ipar, fpar);
  // 9) B3 = bf16(Wproj)
  cvt_bf16_kernel<<<dim3(2048), blk, 0, stream>>>(Wproj, B3, 9, 2048, 0);
  // 10) out = A3 · B3^T + bproj
  mfma_gemm<<<dim3(8, 32), blk, 0, stream>>>(A3, B3, bproj, out, 2048, 1024);
}

// Round 9
// 480.021 us; speedup vs baseline: 2.6840x; 1.0028x over previous
//
#include <hip/hip_runtime.h>
#include <math.h>

#define B_ 4
#define S_ 1024
#define D_ 1024
#define H_ 16
#define HD_ 64
#define BSD_ (B_*S_*D_)

using short8 = __attribute__((ext_vector_type(8))) short;
using f32x4  = __attribute__((ext_vector_type(4))) float;

#define MFMA16(a,b,c) __builtin_amdgcn_mfma_f32_16x16x32_bf16((a),(b),(c),0,0,0)

// ---------------- bf16 helpers (RNE) ----------------
__device__ __forceinline__ ushort f2bf(float f) {
  uint u = __float_as_uint(f);
  return (ushort)((u + 0x7fffu + ((u >> 16) & 1u)) >> 16);
}
__device__ __forceinline__ float bf2f(ushort h) {
  return __uint_as_float(((uint)h) << 16);
}
__device__ __forceinline__ void split8(const float* p, short8* hi, short8* lo) {
  #pragma unroll
  for (int j = 0; j < 8; j++) {
    ushort h = f2bf(p[j]);
    (*hi)[j] = (short)h;
    (*lo)[j] = (short)f2bf(p[j] - bf2f(h));
  }
}
// async global->LDS, 16B per lane; LDS dest = wave-uniform base + lane*16
__device__ __forceinline__ void async_load16(const ushort* g, ushort* l) {
  __builtin_amdgcn_global_load_lds(
      (const __attribute__((address_space(1))) unsigned int*)g,
      (__attribute__((address_space(3))) unsigned int*)l, 16, 0, 0);
}

// ---------------- block reduce (256 threads = 4 waves) ----------------
__device__ __forceinline__ float block_reduce_sum_256(float v, float* sbuf) {
  #pragma unroll
  for (int off = 32; off > 0; off >>= 1) v += __shfl_xor(v, off, 64);
  int lane = threadIdx.x & 63, wid = threadIdx.x >> 6;
  __syncthreads();
  if (lane == 0) sbuf[wid] = v;
  __syncthreads();
  return sbuf[0] + sbuf[1] + sbuf[2] + sbuf[3];
}

// ---------------- LayerNorm (fp32 out) ----------------
__global__ __launch_bounds__(256) void ln_kernel(const float* __restrict__ x,
                                                 const float* __restrict__ g,
                                                 const float* __restrict__ bta,
                                                 float* __restrict__ out) {
  __shared__ float sbuf[4];
  const int row = blockIdx.x;
  const float* xr = x + (size_t)row * D_;
  const int t = threadIdx.x;
  float v[4]; float s = 0.f;
  #pragma unroll
  for (int i = 0; i < 4; i++) { v[i] = xr[t + 256*i]; s += v[i]; }
  const float mean = block_reduce_sum_256(s, sbuf) * (1.0f/D_);
  float sq = 0.f;
  #pragma unroll
  for (int i = 0; i < 4; i++) { float d = v[i]-mean; sq += d*d; }
  const float var = block_reduce_sum_256(sq, sbuf) * (1.0f/D_);
  const float r = rsqrtf(var + 1e-5f);
  float* orow = out + (size_t)row * D_;
  #pragma unroll
  for (int i = 0; i < 4; i++) {
    int c = t + 256*i;
    orow[c] = (v[i]-mean)*r*g[c] + bta[c];
  }
}

// ---------------- fused LayerNorm + [hi|lo] split (stride 2048) ----------------
__global__ __launch_bounds__(256) void ln_split_kernel(const float* __restrict__ x,
                                                       const float* __restrict__ g,
                                                       const float* __restrict__ bta,
                                                       ushort* __restrict__ out) {
  __shared__ float sbuf[4];
  const int row = blockIdx.x;
  const int t = threadIdx.x;
  const int c = t*4;
  const float* xr = x + (size_t)row * D_;
  float4 v = *(const float4*)(xr + c);
  float s = v.x + v.y + v.z + v.w;
  const float mean = block_reduce_sum_256(s, sbuf) * (1.0f/D_);
  float4 dv = make_float4(v.x-mean, v.y-mean, v.z-mean, v.w-mean);
  float sq = dv.x*dv.x + dv.y*dv.y + dv.z*dv.z + dv.w*dv.w;
  const float var = block_reduce_sum_256(sq, sbuf) * (1.0f/D_);
  const float r = rsqrtf(var + 1e-5f);
  float4 gg = *(const float4*)(g + c);
  float4 bb = *(const float4*)(bta + c);
  float n[4];
  n[0] = dv.x*r*gg.x + bb.x; n[1] = dv.y*r*gg.y + bb.y;
  n[2] = dv.z*r*gg.z + bb.z; n[3] = dv.w*r*gg.w + bb.w;
  ushort4 hi, lo;
  hi.x = f2bf(n[0]); hi.y = f2bf(n[1]); hi.z = f2bf(n[2]); hi.w = f2bf(n[3]);
  lo.x = f2bf(n[0]-bf2f(hi.x)); lo.y = f2bf(n[1]-bf2f(hi.y));
  lo.z = f2bf(n[2]-bf2f(hi.z)); lo.w = f2bf(n[3]-bf2f(hi.w));
  ushort* orow = out + (size_t)row*2048;
  *(ushort4*)(orow + c)        = hi;
  *(ushort4*)(orow + 1024 + c) = lo;
}

// ------- weight split [hi|lo] for Wq/Wk/Wv stacked (3072 rows) + bias concat -----
__global__ __launch_bounds__(256) void split_w3_kernel(const float* __restrict__ Wq,
                                                       const float* __restrict__ Wk,
                                                       const float* __restrict__ Wv,
                                                       const float* __restrict__ bq,
                                                       const float* __restrict__ bv,
                                                       ushort* __restrict__ out,
                                                       float* __restrict__ biascat) {
  const int idx = blockIdx.x*256 + threadIdx.x;
  const int n = idx >> 8;
  const int col4 = (idx & 255) << 2;
  const float* src = (n < 1024) ? (Wq + (size_t)n*1024)
                   : (n < 2048) ? (Wk + (size_t)(n-1024)*1024)
                                : (Wv + (size_t)(n-2048)*1024);
  const float4 a = *(const float4*)(src + col4);
  ushort4 hi, lo;
  hi.x = f2bf(a.x); hi.y = f2bf(a.y); hi.z = f2bf(a.z); hi.w = f2bf(a.w);
  lo.x = f2bf(a.x - bf2f(hi.x)); lo.y = f2bf(a.y - bf2f(hi.y));
  lo.z = f2bf(a.z - bf2f(hi.z)); lo.w = f2bf(a.w - bf2f(hi.w));
  ushort* orow = out + (size_t)n*2048;
  *(ushort4*)(orow + col4)        = hi;
  *(ushort4*)(orow + 1024 + col4) = lo;
  if (idx < 3072)
    biascat[idx] = (idx < 1024) ? bq[idx] : (idx < 2048) ? 0.f : bv[idx-2048];
}

// ---------------- weight split [hi|lo] single 1024-row weight (Wo) ---------------
__global__ __launch_bounds__(256) void split_w1_kernel(const float* __restrict__ W,
                                                       ushort* __restrict__ out) {
  const int idx = blockIdx.x*256 + threadIdx.x;
  const int n = idx >> 8;
  const int col4 = (idx & 255) << 2;
  const float4 a = *(const float4*)(W + (size_t)n*1024 + col4);
  ushort4 hi, lo;
  hi.x = f2bf(a.x); hi.y = f2bf(a.y); hi.z = f2bf(a.z); hi.w = f2bf(a.w);
  lo.x = f2bf(a.x - bf2f(hi.x)); lo.y = f2bf(a.y - bf2f(hi.y));
  lo.z = f2bf(a.z - bf2f(hi.z)); lo.w = f2bf(a.w - bf2f(hi.w));
  ushort* orow = out + (size_t)n*2048;
  *(ushort4*)(orow + col4)        = hi;
  *(ushort4*)(orow + 1024 + col4) = lo;
}

// ---------------- plain fp32 -> bf16 convert ----------------
__global__ __launch_bounds__(256) void cvt_bf16_kernel(const float* __restrict__ in,
                                                       ushort* __restrict__ out,
                                                       int gprshift, int ostride, int ooff) {
  const int idx = blockIdx.x*256 + threadIdx.x;
  const int row = idx >> gprshift;
  const int col4 = (idx & ((1 << gprshift) - 1)) << 2;
  const int ncols = 4 << gprshift;
  const float4 a = *(const float4*)(in + (size_t)row*ncols + col4);
  ushort4 hi;
  hi.x = f2bf(a.x); hi.y = f2bf(a.y); hi.z = f2bf(a.z); hi.w = f2bf(a.w);
  *(ushort4*)(out + (size_t)row*ostride + ooff + col4) = hi;
}

// ---------------- QKV GEMM with fused split epilogue ----------------
__global__ __launch_bounds__(256) void mfma_gemm_qkv(
    const ushort* __restrict__ A, const ushort* __restrict__ Bw,
    const float* __restrict__ bias,
    ushort* __restrict__ Qsp, ushort* __restrict__ Ksp,
    ushort* __restrict__ Vth, ushort* __restrict__ Vtl, int Kh) {
  __shared__ __align__(16) ushort smem[17408];   // 34 KB: staging / V-transpose
  ushort* Ash = smem;
  ushort* Asl = smem + 4096;
  ushort* Bsh = smem + 8192;
  ushort* Bsl = smem + 12288;
  const int lda = 2*Kh;
  const int tid = threadIdx.x;
  const int bm = blockIdx.y * 128, bn = blockIdx.x * 128;
  const int wave = tid >> 6, lane = tid & 63;
  const int wm = wave >> 1, wn = wave & 1;
  const int lm = lane & 15, q = lane >> 4;
  const int lrow = lane >> 2;
  const int sw = (((lane & 3) ^ ((lane >> 3) & 3)) << 3);

  f32x4 acc[4][4];
  #pragma unroll
  for (int i = 0; i < 4; i++)
    #pragma unroll
    for (int j = 0; j < 4; j++)
      acc[i][j] = (f32x4){0.f,0.f,0.f,0.f};

  const ushort* Agh = A  + (size_t)(bm + wave*32 + lrow)*lda + sw;
  const ushort* Agl = Agh + Kh;
  const ushort* Bgh = Bw + (size_t)(bn + wave*32 + lrow)*lda + sw;
  const ushort* Bgl = Bgh + Kh;
  const size_t r16a = (size_t)16*lda;
  ushort* AhD0 = &Ash[(wave*32)*32];      ushort* AhD1 = &Ash[(wave*32+16)*32];
  ushort* AlD0 = &Asl[(wave*32)*32];      ushort* AlD1 = &Asl[(wave*32+16)*32];
  ushort* BhD0 = &Bsh[(wave*32)*32];      ushort* BhD1 = &Bsh[(wave*32+16)*32];
  ushort* BlD0 = &Bsl[(wave*32)*32];      ushort* BlD1 = &Bsl[(wave*32+16)*32];
  const int rsw  = ((q ^ ((lm >> 1) & 3)) << 3);
  const int aoff = (wm*64 + lm)*32 + rsw;
  const int boff = (wn*64 + lm)*32 + rsw;

  for (int k0 = 0; k0 < Kh; k0 += 32) {
    __syncthreads();
    async_load16(Agh + k0, AhD0);
    async_load16(Agh + r16a + k0, AhD1);
    async_load16(Agl + k0, AlD0);
    async_load16(Agl + r16a + k0, AlD1);
    async_load16(Bgh + k0, BhD0);
    async_load16(Bgh + r16a + k0, BhD1);
    async_load16(Bgl + k0, BlD0);
    async_load16(Bgl + r16a + k0, BlD1);
    __syncthreads();
    short8 ah[4], al[4], bh[4], bl[4];
    #pragma unroll
    for (int mt = 0; mt < 4; mt++) {
      ah[mt] = *(const short8*)&Ash[aoff + mt*512];
      al[mt] = *(const short8*)&Asl[aoff + mt*512];
    }
    #pragma unroll
    for (int nt = 0; nt < 4; nt++) {
      bh[nt] = *(const short8*)&Bsh[boff + nt*512];
      bl[nt] = *(const short8*)&Bsl[boff + nt*512];
    }
    #pragma unroll
    for (int mt = 0; mt < 4; mt++)
      #pragma unroll
      for (int nt = 0; nt < 4; nt++) {
        f32x4 a = acc[mt][nt];
        a = MFMA16(ah[mt], bh[nt], a);
        a = MFMA16(al[mt], bh[nt], a);
        a = MFMA16(ah[mt], bl[nt], a);
        acc[mt][nt] = a;
      }
  }

  const int b = bm >> 10, s0 = bm & 1023;
  if (blockIdx.x < 16) {
    ushort* dst = (blockIdx.x < 8) ? Qsp : Ksp;
    const int h = ((bn + wn*64) >> 6) & 15;
    #pragma unroll
    for (int mt = 0; mt < 4; mt++) {
      #pragma unroll
      for (int nt = 0; nt < 4; nt++) {
        const int n = bn + wn*64 + nt*16 + lm;
        const int d = nt*16 + lm;
        const float bb = bias[n];
        #pragma unroll
        for (int reg = 0; reg < 4; reg++) {
          const int s = s0 + wm*64 + mt*16 + q*4 + reg;
          const float val = acc[mt][nt][reg] + bb;
          const ushort hi = f2bf(val);
          const ushort lo = f2bf(val - bf2f(hi));
          ushort* rp = dst + ((size_t)((b*16 + h)*1024 + s))*128;
          rp[d] = hi; rp[64 + d] = lo;
        }
      }
    }
  } else {
    ushort* Th = smem;            // [64][136] ushorts
    ushort* Tl = smem + 8704;
    #pragma unroll
    for (int c = 0; c < 2; c++) {
      __syncthreads();
      if (wn == c) {
        #pragma unroll
        for (int mt = 0; mt < 4; mt++)
          #pragma unroll
          for (int nt = 0; nt < 4; nt++) {
            const int nl = nt*16 + lm;
            const float bb = bias[bn + c*64 + nl];
            #pragma unroll
            for (int reg = 0; reg < 4; reg++) {
              const int sl = wm*64 + mt*16 + q*4 + reg;
              const float val = acc[mt][nt][reg] + bb;
              const ushort hi = f2bf(val);
              const ushort lo = f2bf(val - bf2f(hi));
              Th[nl*136 + sl] = hi;
              Tl[nl*136 + sl] = lo;
            }
          }
      }
      __syncthreads();
      const int nl = tid >> 2, s32 = (tid & 3)*32;
      const int h = ((bn - 2048 + c*64) >> 6) & 15;
      const size_t drow = ((size_t)((b*16 + h)*64 + nl))*1024 + s0 + s32;
      #pragma unroll
      for (int j = 0; j < 4; j++) {
        *(short8*)(Vth + drow + j*8) = *(const short8*)&Th[nl*136 + s32 + j*8];
        *(short8*)(Vtl + drow + j*8) = *(const short8*)&Tl[nl*136 + s32 + j*8];
      }
    }
  }
}

// ---------------- dual-panel bf16x3 MFMA GEMM (+optional aux bf16 out) ----------
__global__ __launch_bounds__(256) void mfma_gemm2(
    const ushort* __restrict__ A, const ushort* __restrict__ Bw,
    const float* __restrict__ bias, float* __restrict__ C,
    int Kh, int ldc, ushort* __restrict__ aux) {
  __shared__ __align__(16) ushort Ash[128*32];
  __shared__ __align__(16) ushort Asl[128*32];
  __shared__ __align__(16) ushort Bsh[128*32];
  __shared__ __align__(16) ushort Bsl[128*32];
  const int lda = 2*Kh;
  const int tid = threadIdx.x;
  const int bm = blockIdx.y * 128, bn = blockIdx.x * 128;
  const int wave = tid >> 6, lane = tid & 63;
  const int wm = wave >> 1, wn = wave & 1;
  const int lm = lane & 15, q = lane >> 4;
  const int lrow = lane >> 2;
  const int sw = (((lane & 3) ^ ((lane >> 3) & 3)) << 3);

  f32x4 acc[4][4];
  #pragma unroll
  for (int i = 0; i < 4; i++)
    #pragma unroll
    for (int j = 0; j < 4; j++)
      acc[i][j] = (f32x4){0.f,0.f,0.f,0.f};

  const ushort* Agh = A  + (size_t)(bm + wave*32 + lrow)*lda + sw;
  const ushort* Agl = Agh + Kh;
  const ushort* Bgh = Bw + (size_t)(bn + wave*32 + lrow)*lda + sw;
  const ushort* Bgl = Bgh + Kh;
  const size_t r16a = (size_t)16*lda;
  ushort* AhD0 = &Ash[(wave*32)*32];      ushort* AhD1 = &Ash[(wave*32+16)*32];
  ushort* AlD0 = &Asl[(wave*32)*32];      ushort* AlD1 = &Asl[(wave*32+16)*32];
  ushort* BhD0 = &Bsh[(wave*32)*32];      ushort* BhD1 = &Bsh[(wave*32+16)*32];
  ushort* BlD0 = &Bsl[(wave*32)*32];      ushort* BlD1 = &Bsl[(wave*32+16)*32];
  const int rsw  = ((q ^ ((lm >> 1) & 3)) << 3);
  const int aoff = (wm*64 + lm)*32 + rsw;
  const int boff = (wn*64 + lm)*32 + rsw;

  for (int k0 = 0; k0 < Kh; k0 += 32) {
    __syncthreads();
    async_load16(Agh + k0, AhD0);
    async_load16(Agh + r16a + k0, AhD1);
    async_load16(Agl + k0, AlD0);
    async_load16(Agl + r16a + k0, AlD1);
    async_load16(Bgh + k0, BhD0);
    async_load16(Bgh + r16a + k0, BhD1);
    async_load16(Bgl + k0, BlD0);
    async_load16(Bgl + r16a + k0, BlD1);
    __syncthreads();
    short8 ah[4], al[4], bh[4], bl[4];
    #pragma unroll
    for (int mt = 0; mt < 4; mt++) {
      ah[mt] = *(const short8*)&Ash[aoff + mt*512];
      al[mt] = *(const short8*)&Asl[aoff + mt*512];
    }
    #pragma unroll
    for (int nt = 0; nt < 4; nt++) {
      bh[nt] = *(const short8*)&Bsh[boff + nt*512];
      bl[nt] = *(const short8*)&Bsl[boff + nt*512];
    }
    #pragma unroll
    for (int mt = 0; mt < 4; mt++)
      #pragma unroll
      for (int nt = 0; nt < 4; nt++) {
        f32x4 a = acc[mt][nt];
        a = MFMA16(ah[mt], bh[nt], a);
        a = MFMA16(al[mt], bh[nt], a);
        a = MFMA16(ah[mt], bl[nt], a);
        acc[mt][nt] = a;
      }
  }

  #pragma unroll
  for (int mt = 0; mt < 4; mt++) {
    #pragma unroll
    for (int nt = 0; nt < 4; nt++) {
      const int n = bn + wn*64 + nt*16 + lm;
      const float bb = bias ? bias[n] : 0.f;
      #pragma unroll
      for (int reg = 0; reg < 4; reg++) {
        const int m = bm + wm*64 + mt*16 + q*4 + reg;
        const float val = acc[mt][nt][reg] + bb;
        C[(size_t)m*ldc + n] = val;
        if (aux) aux[(size_t)m*2048 + 1024 + n] = f2bf(val);
      }
    }
  }
}

// ---------------- plain bf16 MFMA GEMM (final projection), swizzled --------------
__global__ __launch_bounds__(256) void mfma_gemm(
    const ushort* __restrict__ A, const ushort* __restrict__ Bw,
    const float* __restrict__ bias, float* __restrict__ C,
    int K, int ldc) {
  __shared__ __align__(16) ushort As[128*32];
  __shared__ __align__(16) ushort Bs[128*32];
  const int tid = threadIdx.x;
  const int bm = blockIdx.y * 128, bn = blockIdx.x * 128;
  const int wave = tid >> 6, lane = tid & 63;
  const int wm = wave >> 1, wn = wave & 1;
  const int lm = lane & 15, q = lane >> 4;
  const int lrow = lane >> 2;
  const int sw = (((lane & 3) ^ ((lane >> 3) & 3)) << 3);

  f32x4 acc[4][4];
  #pragma unroll
  for (int i = 0; i < 4; i++)
    #pragma unroll
    for (int j = 0; j < 4; j++)
      acc[i][j] = (f32x4){0.f,0.f,0.f,0.f};

  const ushort* Ar0 = A  + (size_t)(bm + wave*32 + lrow)*K + sw;
  const ushort* Br0 = Bw + (size_t)(bn + wave*32 + lrow)*K + sw;
  const size_t r16 = (size_t)16*K;
  ushort* AsD0 = &As[(wave*32)*32];
  ushort* AsD1 = &As[(wave*32 + 16)*32];
  ushort* BsD0 = &Bs[(wave*32)*32];
  ushort* BsD1 = &Bs[(wave*32 + 16)*32];
  const int rsw  = ((q ^ ((lm >> 1) & 3)) << 3);
  const int aoff0 = (wm*64 + lm)*32 + rsw;
  const int boff0 = (wn*64 + lm)*32 + rsw;

  for (int k0 = 0; k0 < K; k0 += 32) {
    __syncthreads();
    async_load16(Ar0 + k0, AsD0);
    async_load16(Ar0 + r16 + k0, AsD1);
    async_load16(Br0 + k0, BsD0);
    async_load16(Br0 + r16 + k0, BsD1);
    __syncthreads();
    short8 af[4], bf[4];
    #pragma unroll
    for (int mt = 0; mt < 4; mt++) af[mt] = *(const short8*)&As[aoff0 + mt*512];
    #pragma unroll
    for (int nt = 0; nt < 4; nt++) bf[nt] = *(const short8*)&Bs[boff0 + nt*512];
    #pragma unroll
    for (int mt = 0; mt < 4; mt++)
      #pragma unroll
      for (int nt = 0; nt < 4; nt++)
        acc[mt][nt] = MFMA16(af[mt], bf[nt], acc[mt][nt]);
  }

  #pragma unroll
  for (int mt = 0; mt < 4; mt++) {
    #pragma unroll
    for (int nt = 0; nt < 4; nt++) {
      const int n = bn + wn*64 + nt*16 + lm;
      const float bb = bias ? bias[n] : 0.f;
      #pragma unroll
      for (int reg = 0; reg < 4; reg++) {
        const int m = bm + wm*64 + mt*16 + q*4 + reg;
        C[(size_t)m*ldc + n] = acc[mt][nt][reg] + bb;
      }
    }
  }
}

// ---- one q-tile x k-tile attention unit (scores -> softmax -> PV) ----
__device__ __forceinline__ void attn_unit(
    int qt, int kt, int w, int lm, int q,
    const short8 qh[2], const short8 ql[2],
    const ushort* Kc, const ushort* Vc, float* Pf,
    f32x4 of[4], float mst[4], float lst[4]) {
  f32x4 sS[4];
  #pragma unroll
  for (int nt = 0; nt < 4; nt++) {
    const ushort* kr = &Kc[(nt*16 + lm)*136 + q*8];
    const short8 kh0 = *(const short8*)(kr);
    const short8 kh1 = *(const short8*)(kr + 32);
    const short8 kl0 = *(const short8*)(kr + 64);
    const short8 kl1 = *(const short8*)(kr + 96);
    f32x4 a = (f32x4){0.f,0.f,0.f,0.f};
    a = MFMA16(qh[0], kh0, a);
    a = MFMA16(ql[0], kh0, a);
    a = MFMA16(qh[0], kl0, a);
    a = MFMA16(qh[1], kh1, a);
    a = MFMA16(ql[1], kh1, a);
    a = MFMA16(qh[1], kl1, a);
    sS[nt] = a;
  }
  const int ktbase = kt*64;
  const int qrow0 = qt*64 + w*16 + q*4;
  #pragma unroll
  for (int rm = 0; rm < 4; rm++) {
    const int qrow = qrow0 + rm;
    float v[4];
    #pragma unroll
    for (int nt = 0; nt < 4; nt++) {
      const int kcol = ktbase + nt*16 + lm;
      const float x = sS[nt][rm]*0.125f;
      v[nt] = (kcol <= qrow) ? x : -INFINITY;
    }
    float tm = fmaxf(fmaxf(v[0],v[1]), fmaxf(v[2],v[3]));
    #pragma unroll
    for (int off = 1; off < 16; off <<= 1) tm = fmaxf(tm, __shfl_xor(tm, off, 64));
    const float nm = fmaxf(mst[rm], tm);
    const float alpha = __expf(mst[rm] - nm);
    float ps = 0.f;
    #pragma unroll
    for (int nt = 0; nt < 4; nt++) {
      float p = __expf(v[nt] - nm);
      sS[nt][rm] = p;
      ps += p;
    }
    #pragma unroll
    for (int off = 1; off < 16; off <<= 1) ps += __shfl_xor(ps, off, 64);
    lst[rm] = lst[rm]*alpha + ps;
    mst[rm] = nm;
    #pragma unroll
    for (int nt = 0; nt < 4; nt++) of[nt][rm] *= alpha;
  }
  // P round-trip: wave-private Pf rows — in-order LDS within wave, no barriers.
  #pragma unroll
  for (int rm = 0; rm < 4; rm++)
    #pragma unroll
    for (int nt = 0; nt < 4; nt++)
      Pf[(w*16 + q*4 + rm)*66 + nt*16 + lm] = sS[nt][rm];
  short8 ph[2], pl[2];
  {
    const float* prow = &Pf[(w*16 + lm)*66];
    float pv[16];
    *(float4*)&pv[0]  = *(const float4*)(prow + q*8);
    *(float4*)&pv[4]  = *(const float4*)(prow + q*8 + 4);
    *(float4*)&pv[8]  = *(const float4*)(prow + 32 + q*8);
    *(float4*)&pv[12] = *(const float4*)(prow + 32 + q*8 + 4);
    split8(&pv[0], &ph[0], &pl[0]);
    split8(&pv[8], &ph[1], &pl[1]);
  }
  #pragma unroll
  for (int nt = 0; nt < 4; nt++) {
    const ushort* vr = &Vc[(nt*16 + lm)*136 + q*8];
    const short8 vh0 = *(const short8*)(vr);
    const short8 vh1 = *(const short8*)(vr + 32);
    const short8 vl0 = *(const short8*)(vr + 64);
    const short8 vl1 = *(const short8*)(vr + 96);
    f32x4 a = of[nt];
    a = MFMA16(ph[0], vh0, a);
    a = MFMA16(pl[0], vh0, a);
    a = MFMA16(ph[0], vl0, a);
    a = MFMA16(ph[1], vh1, a);
    a = MFMA16(pl[1], vh1, a);
    a = MFMA16(ph[1], vl1, a);
    of[nt] = a;
  }
}

// ---- MFMA causal flash attention: dual q-tile, shared K/V staging ----
// grid (8, 64): block handles q-tiles A=15-bx and B=bx in ONE kt loop
// (0..qtA); kt<=qtB also updates B. Staged tiles/block: 16-bx (was 17).
// Epilogue writes [hi|lo] bf16 directly into the Wo-GEMM A operand.
__global__ __launch_bounds__(256) void gattn_mfma(
    const ushort* __restrict__ Qsp, const ushort* __restrict__ Ksp,
    const ushort* __restrict__ Vth, const ushort* __restrict__ Vtl,
    ushort* __restrict__ Aout) {
  __shared__ __align__(16) ushort Kc[64*136];
  __shared__ __align__(16) ushort Vc[64*136];
  __shared__ __align__(16) float  Pf[64*66];
  const int bh = blockIdx.y;
  const int b = bh >> 4, h = bh & 15;
  const int tid = threadIdx.x;
  const int w = tid >> 6, lane = tid & 63;
  const int lm = lane & 15, q = lane >> 4;
  const ushort* Qb_ = Qsp + (size_t)bh * (1024*128);
  const ushort* Kb_ = Ksp + (size_t)bh * (1024*128);
  const ushort* Vhb = Vth + (size_t)bh * (64*1024);
  const ushort* Vlb = Vtl + (size_t)bh * (64*1024);
  const int qtA = 15 - blockIdx.x;
  const int qtB = blockIdx.x;

  short8 qhA[2], qlA[2], qhB[2], qlB[2];
  {
    const ushort* qr = Qb_ + (size_t)(qtA*64 + w*16 + lm)*128 + q*8;
    qhA[0] = *(const short8*)(qr);
    qhA[1] = *(const short8*)(qr + 32);
    qlA[0] = *(const short8*)(qr + 64);
    qlA[1] = *(const short8*)(qr + 96);
    const ushort* qr2 = Qb_ + (size_t)(qtB*64 + w*16 + lm)*128 + q*8;
    qhB[0] = *(const short8*)(qr2);
    qhB[1] = *(const short8*)(qr2 + 32);
    qlB[0] = *(const short8*)(qr2 + 64);
    qlB[1] = *(const short8*)(qr2 + 96);
  }
  f32x4 ofA[4], ofB[4];
  float mstA[4], lstA[4], mstB[4], lstB[4];
  #pragma unroll
  for (int nt = 0; nt < 4; nt++) {
    ofA[nt] = (f32x4){0.f,0.f,0.f,0.f};
    ofB[nt] = (f32x4){0.f,0.f,0.f,0.f};
  }
  #pragma unroll
  for (int rm = 0; rm < 4; rm++) {
    mstA[rm] = -INFINITY; lstA[rm] = 0.f;
    mstB[rm] = -INFINITY; lstB[rm] = 0.f;
  }

  for (int kt = 0; kt <= qtA; ++kt) {
    __syncthreads();                 // prior iter's Kc/Vc reads done
    #pragma unroll
    for (int i = 0; i < 4; i++) {
      const int slot = i*256 + tid;  // 0..1023: 64 rows x 16 chunks of 8
      const int row = slot >> 4, c8 = slot & 15;
      *(float4*)&Kc[row*136 + c8*8] =
          *(const float4*)(Kb_ + (size_t)(kt*64 + row)*128 + c8*8);
      const ushort* vsrc = ((c8 < 8) ? Vhb : Vlb) + (size_t)row*1024 + kt*64 + (c8&7)*8;
      *(float4*)&Vc[row*136 + c8*8] = *(const float4*)vsrc;
    }
    __syncthreads();                 // staging visible
    attn_unit(qtA, kt, w, lm, q, qhA, qlA, Kc, Vc, Pf, ofA, mstA, lstA);
    if (kt <= qtB)
      attn_unit(qtB, kt, w, lm, q, qhB, qlB, Kc, Vc, Pf, ofB, mstB, lstB);
  }

  #pragma unroll
  for (int rm = 0; rm < 4; rm++) {
    const float invA = 1.0f / lstA[rm];
    const int sA = qtA*64 + w*16 + q*4 + rm;
    ushort* arow = Aout + ((size_t)(b*1024 + sA))*2048 + h*64;
    #pragma unroll
    for (int nt = 0; nt < 4; nt++) {
      const float val = ofA[nt][rm] * invA;
      const ushort hi = f2bf(val);
      arow[nt*16 + lm] = hi;
      arow[1024 + nt*16 + lm] = f2bf(val - bf2f(hi));
    }
    const float invB = 1.0f / lstB[rm];
    const int sB = qtB*64 + w*16 + q*4 + rm;
    ushort* brow = Aout + ((size_t)(b*1024 + sB))*2048 + h*64;
    #pragma unroll
    for (int nt = 0; nt < 4; nt++) {
      const float val = ofB[nt][rm] * invB;
      const ushort hi = f2bf(val);
      brow[nt*16 + lm] = hi;
      brow[1024 + nt*16 + lm] = f2bf(val - bf2f(hi));
    }
  }
}

// ---------------- seq-mean, 2-stage deterministic ----------------
__global__ __launch_bounds__(256) void seqmean1_kernel(const float* __restrict__ g,
                                                       float* __restrict__ part) {
  const int d = blockIdx.x*256 + threadIdx.x;
  const int sc = blockIdx.y;
  const int b = blockIdx.z;
  const float* p = g + ((size_t)b*S_ + sc*128)*D_ + d;
  float s = 0.f;
  #pragma unroll 4
  for (int i = 0; i < 128; i++) s += p[(size_t)i*D_];
  part[((size_t)(b*8 + sc))*D_ + d] = s;
}
__global__ __launch_bounds__(256) void seqmean2_kernel(const float* __restrict__ part,
                                                       float* __restrict__ mbd) {
  const int d = blockIdx.x*256 + threadIdx.x;
  const int b = blockIdx.y;
  float s = 0.f;
  #pragma unroll
  for (int i = 0; i < 8; i++) s += part[((size_t)(b*8 + i))*D_ + d];
  mbd[b*D_ + d] = s * (1.0f/S_);
}

// ---------------- predictor ----------------
__global__ __launch_bounds__(256) void predictor_kernel(
    const float* __restrict__ mbd, const float* __restrict__ Wp,
    const float* __restrict__ bp, float* __restrict__ fpar, int* __restrict__ ipar) {
  __shared__ float sbuf[4];
  __shared__ float sdots[4];
  const int tid = threadIdx.x;
  for (int b = 0; b < 4; b++) {
    float psum = 0.f;
    for (int d = tid; d < D_; d += 256) psum += mbd[b*D_ + d]*Wp[d];
    float tot = block_reduce_sum_256(psum, sbuf);
    if (tid == 0) sdots[b] = tot;
  }
  __syncthreads();
  if (tid == 0) {
    float smv = 0.f;
    for (int b = 0; b < 4; b++) {
      float z = sdots[b] + bp[0];
      smv += 1.0f/(1.0f + expf(-z));
    }
    smv *= 0.25f;
    int win = max(1, (int)(256.0f*smv));
    int span_len = max(1, (int)(512.0f*smv));
    int local_max = min(512, min(span_len, win));
    float temp = 1.0f + 0.01f*(1.0f - smv);
    int n_win = (S_ + win - 1)/win;
    fpar[0] = smv; fpar[1] = temp;
    ipar[0] = win; ipar[1] = span_len; ipar[2] = local_max; ipar[3] = n_win;
  }
}

// -------- dynamic sliding-window span attention (fp32 -> bf16 out, self-zeroing) --
#define LDP 68
__global__ __launch_bounds__(256) void lattn_kernel(
    const float* __restrict__ Lc, ushort* __restrict__ Out,
    const int* __restrict__ ip, const float* __restrict__ fpp) {
  __shared__ __align__(16) float Qs[HD_][LDP];
  __shared__ __align__(16) float KPs[64][LDP];
  __shared__ __align__(16) float Vs[64][LDP];
  const int n_win = ip[3];
  const int win = ip[0], span_len = ip[1], local_max = ip[2];
  const float sm = fpp[0], temp = fpp[1];
  const int bh = blockIdx.y;
  const int b = bh >> 4, h = bh & 15;
  const int tid = threadIdx.x;
  const int tx = tid & 15, ty = tid >> 4;
  const float sc = 0.35355339059327373f / temp;
  for (int w = blockIdx.x; w < n_win; w += gridDim.x) {
    const int st = w * win;
    const int en = min(st + win, S_); const int wlen = en - st;
    const int ks = max(0, st - span_len + win);
    const int ke = min(st + span_len, S_); const int klen = ke - ks;
    int eff = (int)((double)wlen * (double)sm);
    eff = min(min(eff, wlen), min(klen, local_max));
    if (eff > 0) {
      const int nt = (eff + 63) >> 6;
      for (int qt = 0; qt < nt; ++qt) {
        const int qn = min(64, eff - qt*64);
        __syncthreads();
        #pragma unroll
        for (int c = 0; c < 4; c++) {
          int f = tid + c*256;
          int r = f >> 4;
          int dc = (f & 15) << 2;
          float4 q4 = make_float4(0.f,0.f,0.f,0.f);
          if (r < qn) q4 = *(const float4*)(Lc + ((size_t)(b*S_ + st + qt*64 + r)) * D_ + h*HD_ + dc);
          Qs[dc+0][r]=q4.x; Qs[dc+1][r]=q4.y; Qs[dc+2][r]=q4.z; Qs[dc+3][r]=q4.w;
        }
        float o[4][4] = {{0.f,0.f,0.f,0.f},{0.f,0.f,0.f,0.f},{0.f,0.f,0.f,0.f},{0.f,0.f,0.f,0.f}};
        float mrow[4], lrow[4];
        #pragma unroll
        for (int i=0;i<4;i++){ mrow[i] = -INFINITY; lrow[i] = 0.f; }
        for (int kt = 0; kt < nt; ++kt) {
          const int kn = min(64, eff - kt*64);
          __syncthreads();
          #pragma unroll
          for (int c = 0; c < 4; c++) {
            int f = tid + c*256;
            int r = f >> 4;
            int dc = (f & 15) << 2;
            float4 k4 = make_float4(0.f,0.f,0.f,0.f);
            if (r < kn) k4 = *(const float4*)(Lc + ((size_t)(b*S_ + ks + kt*64 + r)) * D_ + h*HD_ + dc);
            KPs[dc+0][r]=k4.x; KPs[dc+1][r]=k4.y; KPs[dc+2][r]=k4.z; KPs[dc+3][r]=k4.w;
            *(float4*)&Vs[r][dc] = k4;
          }
          __syncthreads();
          float s[4][4] = {{0.f,0.f,0.f,0.f},{0.f,0.f,0.f,0.f},{0.f,0.f,0.f,0.f},{0.f,0.f,0.f,0.f}};
          #pragma unroll 8
          for (int d = 0; d < HD_; ++d) {
            const float4 a  = *(const float4*)&Qs[d][ty*4];
            const float4 bb = *(const float4*)&KPs[d][tx*4];
            const float av[4]={a.x,a.y,a.z,a.w};
            const float bv[4]={bb.x,bb.y,bb.z,bb.w};
            #pragma unroll
            for (int i=0;i<4;i++)
              #pragma unroll
              for (int j=0;j<4;j++)
                s[i][j] += av[i]*bv[j];
          }
          #pragma unroll
          for (int i=0;i<4;i++) {
            #pragma unroll
            for (int j=0;j<4;j++) {
              float lg = s[i][j]*sc;
              if (kt*64 + tx*4 + j >= eff) lg = -INFINITY;
              s[i][j] = lg;
            }
          }
          #pragma unroll
          for (int i=0;i<4;i++) {
            float tm = fmaxf(fmaxf(s[i][0],s[i][1]), fmaxf(s[i][2],s[i][3]));
            #pragma unroll
            for (int off=1; off<16; off<<=1) tm = fmaxf(tm, __shfl_xor(tm, off, 64));
            const float nm = fmaxf(mrow[i], tm);
            const float alpha = __expf(mrow[i]-nm);
            float ps = 0.f;
            #pragma unroll
            for (int j=0;j<4;j++){ float p = __expf(s[i][j]-nm); s[i][j]=p; ps += p; }
            #pragma unroll
            for (int off=1; off<16; off<<=1) ps += __shfl_xor(ps, off, 64);
            lrow[i] = lrow[i]*alpha + ps;
            mrow[i] = nm;
            #pragma unroll
            for (int j=0;j<4;j++) o[i][j] *= alpha;
          }
          __syncthreads();
          #pragma unroll
          for (int i=0;i<4;i++)
            #pragma unroll
            for (int j=0;j<4;j++)
              KPs[tx*4+j][ty*4+i] = s[i][j];
          __syncthreads();
          #pragma unroll 8
          for (int kk = 0; kk < 64; ++kk) {
            const float4 a  = *(const float4*)&KPs[kk][ty*4];
            const float4 bb = *(const float4*)&Vs[kk][tx*4];
            const float av[4]={a.x,a.y,a.z,a.w};
            const float bv[4]={bb.x,bb.y,bb.z,bb.w};
            #pragma unroll
            for (int i=0;i<4;i++)
              #pragma unroll
              for (int j=0;j<4;j++)
                o[i][j] += av[i]*bv[j];
          }
        }
        #pragma unroll
        for (int i=0;i<4;i++){
          const int r = ty*4 + i;
          if (r < qn) {
            const float inv = 1.0f / lrow[i];
            ushort4 ov;
            ov.x = f2bf(o[i][0]*inv); ov.y = f2bf(o[i][1]*inv);
            ov.z = f2bf(o[i][2]*inv); ov.w = f2bf(o[i][3]*inv);
            *(ushort4*)(Out + ((size_t)(b*S_ + st + qt*64 + r)) * 2048 + h*HD_ + tx*4) = ov;
          }
        }
      }
    }
    // zero-fill rows [max(eff,0), wlen) for this window/head (replaces memset)
    const ushort4 z = {0,0,0,0};
    for (int r = max(eff, 0) + ty; r < wlen; r += 16)
      *(ushort4*)(Out + ((size_t)(b*S_ + st + r)) * 2048 + h*HD_ + tx*4) = z;
  }
}

// ---------------- launch ----------------
extern "C" void kernel_launch(void* const* d_in, const int* in_sizes, int n_in,
                              void* d_out, int out_size, void* d_ws, size_t ws_size,
                              hipStream_t stream) {
  const float* x      = (const float*)d_in[0];
  const float* ln_a_g = (const float*)d_in[1];
  const float* ln_a_b = (const float*)d_in[2];
  const float* ln_b_g = (const float*)d_in[3];
  const float* ln_b_b = (const float*)d_in[4];
  const float* Wq     = (const float*)d_in[5];
  const float* bq     = (const float*)d_in[6];
  const float* Wk     = (const float*)d_in[7];
  const float* Wv     = (const float*)d_in[8];
  const float* bv     = (const float*)d_in[9];
  const float* Wo     = (const float*)d_in[10];
  const float* bo     = (const float*)d_in[11];
  const float* Wp     = (const float*)d_in[12];
  const float* bp     = (const float*)d_in[13];
  const float* Wproj  = (const float*)d_in[14];
  const float* bproj  = (const float*)d_in[15];
  float* out = (float*)d_out;
  float* ws  = (float*)d_ws;
  ushort* wsu = (ushort*)d_ws;

  // layout: first 50.3MB region holds Qsp/Ksp/Vth/Vtl (later A3/B3 overlay)
  ushort* Qsp = wsu;                         // [64*1024,128] 16.8MB
  ushort* Ksp = wsu + 8388608;               // [64*1024,128] 16.8MB
  ushort* Vth = wsu + 16777216;              // [64*64,1024]  8.4MB
  ushort* Vtl = wsu + 20971520;              // [64*64,1024]  8.4MB
  float* glo  = ws + 16777216;               // [4096,1024] globe_out
  float* loc  = ws + 20971520;               // [4096,1024] LN_a out
  float* biascat = ws + 25165824;            // [3072]
  float* mbd  = biascat + 4096;
  float* fpar = mbd + 4096;
  int*   ipar = (int*)(fpar + 8);
  ushort* Acat  = (ushort*)(ws + 25182208);  // [4096,2048] bf16 (LNb split; attn out)
  ushort* Bqkv  = Acat + 12582912;           // [3072,2048] bf16
  ushort* Bo    = Bqkv + 9437184;            // [1024,2048] bf16
  float*  part = (float*)Acat;               // [B*8,1024] fp32 (after Acat dead)
  ushort* A3  = wsu;                         // [4096,2048] overlays Qsp (dead)
  ushort* B3  = wsu + 8388608;               // [1024,2048] overlays Ksp (dead)

  const dim3 blk(256);

  // 1) LN_b(x) fused with [hi|lo] split -> Acat
  ln_split_kernel<<<dim3(B_*S_), blk, 0, stream>>>(x, ln_b_g, ln_b_b, Acat);
  // 2) weight split [hi|lo] + bias concat
  split_w3_kernel<<<dim3(3072), blk, 0, stream>>>(Wq, Wk, Wv, bq, bv, Bqkv, biascat);
  // 3) QKV GEMM with fused split epilogue -> Qsp/Ksp/Vth/Vtl
  mfma_gemm_qkv<<<dim3(24, 32), blk, 0, stream>>>(Acat, Bqkv, biascat,
                                                  Qsp, Ksp, Vth, Vtl, 1024);
  // 4) MFMA causal attention -> Acat [hi|lo] directly (Acat dead as LNb now)
  gattn_mfma<<<dim3(8, 64), blk, 0, stream>>>(Qsp, Ksp, Vth, Vtl, Acat);
  // 5) globe_out = attn · Wo^T + bo (dual-panel bf16x3; aux bf16 -> A3[:,1024:])
  split_w1_kernel<<<dim3(1024), blk, 0, stream>>>(Wo, Bo);
  mfma_gemm2<<<dim3(8, 32), blk, 0, stream>>>(Acat, Bo, bo, glo, 1024, 1024, A3);
  // 6) predictor (device-side)
  seqmean1_kernel<<<dim3(4, 8, B_), blk, 0, stream>>>(glo, part);
  seqmean2_kernel<<<dim3(4, B_), blk, 0, stream>>>(part, mbd);
  predictor_kernel<<<dim3(1), blk, 0, stream>>>(mbd, Wp, bp, fpar, ipar);
  // 7) local = LN_a(x) -> loc
  ln_kernel<<<dim3(B_*S_), blk, 0, stream>>>(x, ln_a_g, ln_a_b, loc);
  // 8) local attention -> A3[:, 0:1024] bf16 (self-zeroing; no memset)
  lattn_kernel<<<dim3(64, B_*H_), blk, 0, stream>>>(loc, A3, ipar, fpar);
  // 9) B3 = bf16(Wproj)
  cvt_bf16_kernel<<<dim3(2048), blk, 0, stream>>>(Wproj, B3, 9, 2048, 0);
  // 10) out = A3 · B3^T + bproj
  mfma_gemm<<<dim3(8, 32), blk, 0, stream>>>(A3, B3, bproj, out, 2048, 1024);
}

// Round 10
// 453.442 us; speedup vs baseline: 2.8414x; 1.0586x over previous
//
#include <hip/hip_runtime.h>
#include <math.h>

#define B_ 4
#define S_ 1024
#define D_ 1024
#define H_ 16
#define HD_ 64
#define BSD_ (B_*S_*D_)

using short8 = __attribute__((ext_vector_type(8))) short;
using f32x4  = __attribute__((ext_vector_type(4))) float;

#define MFMA16(a,b,c) __builtin_amdgcn_mfma_f32_16x16x32_bf16((a),(b),(c),0,0,0)

// ---------------- bf16 helpers (RNE) ----------------
__device__ __forceinline__ ushort f2bf(float f) {
  uint u = __float_as_uint(f);
  return (ushort)((u + 0x7fffu + ((u >> 16) & 1u)) >> 16);
}
__device__ __forceinline__ float bf2f(ushort h) {
  return __uint_as_float(((uint)h) << 16);
}
__device__ __forceinline__ void split8(const float* p, short8* hi, short8* lo) {
  #pragma unroll
  for (int j = 0; j < 8; j++) {
    ushort h = f2bf(p[j]);
    (*hi)[j] = (short)h;
    (*lo)[j] = (short)f2bf(p[j] - bf2f(h));
  }
}
// async global->LDS, 16B per lane; LDS dest = wave-uniform base + lane*16
__device__ __forceinline__ void async_load16(const ushort* g, ushort* l) {
  __builtin_amdgcn_global_load_lds(
      (const __attribute__((address_space(1))) unsigned int*)g,
      (__attribute__((address_space(3))) unsigned int*)l, 16, 0, 0);
}

// ---------------- block reduce (256 threads = 4 waves) ----------------
__device__ __forceinline__ float block_reduce_sum_256(float v, float* sbuf) {
  #pragma unroll
  for (int off = 32; off > 0; off >>= 1) v += __shfl_xor(v, off, 64);
  int lane = threadIdx.x & 63, wid = threadIdx.x >> 6;
  __syncthreads();
  if (lane == 0) sbuf[wid] = v;
  __syncthreads();
  return sbuf[0] + sbuf[1] + sbuf[2] + sbuf[3];
}

__device__ __forceinline__ void split4_store(const float4 a, ushort* orow, int c, int stride) {
  ushort4 hi, lo;
  hi.x = f2bf(a.x); hi.y = f2bf(a.y); hi.z = f2bf(a.z); hi.w = f2bf(a.w);
  lo.x = f2bf(a.x - bf2f(hi.x)); lo.y = f2bf(a.y - bf2f(hi.y));
  lo.z = f2bf(a.z - bf2f(hi.z)); lo.w = f2bf(a.w - bf2f(hi.w));
  *(ushort4*)(orow + c)          = hi;
  *(ushort4*)(orow + stride + c) = lo;
}

// ---------------- fused prep: all input-side transforms in ONE dispatch ----------
// blocks [0,4096): LN_b + [hi|lo] split -> Acat
// blocks [4096,7168): Wq/Wk/Wv split + bias concat -> Bqkv, biascat
// blocks [7168,11264): LN_a (fp32) -> loc
// blocks [11264,13312): bf16(Wproj) -> B3
// blocks [13312,14336): Wo split -> Bo
__global__ __launch_bounds__(256) void prep_kernel(
    const float* __restrict__ x,
    const float* __restrict__ ln_a_g, const float* __restrict__ ln_a_b,
    const float* __restrict__ ln_b_g, const float* __restrict__ ln_b_b,
    const float* __restrict__ Wq, const float* __restrict__ Wk,
    const float* __restrict__ Wv, const float* __restrict__ bq,
    const float* __restrict__ bv, const float* __restrict__ Wo,
    const float* __restrict__ Wproj,
    ushort* __restrict__ Acat, ushort* __restrict__ Bqkv,
    float* __restrict__ biascat, float* __restrict__ loc,
    ushort* __restrict__ B3, ushort* __restrict__ Bo) {
  __shared__ float sbuf[4];
  const int bx = blockIdx.x;
  const int t = threadIdx.x;
  if (bx < 4096) {
    // ---- LN_b + split ----
    const int row = bx;
    const int c = t*4;
    const float* xr = x + (size_t)row * D_;
    float4 v = *(const float4*)(xr + c);
    float s = v.x + v.y + v.z + v.w;
    const float mean = block_reduce_sum_256(s, sbuf) * (1.0f/D_);
    float4 dv = make_float4(v.x-mean, v.y-mean, v.z-mean, v.w-mean);
    float sq = dv.x*dv.x + dv.y*dv.y + dv.z*dv.z + dv.w*dv.w;
    const float var = block_reduce_sum_256(sq, sbuf) * (1.0f/D_);
    const float r = rsqrtf(var + 1e-5f);
    float4 gg = *(const float4*)(ln_b_g + c);
    float4 bb = *(const float4*)(ln_b_b + c);
    float4 n;
    n.x = dv.x*r*gg.x + bb.x; n.y = dv.y*r*gg.y + bb.y;
    n.z = dv.z*r*gg.z + bb.z; n.w = dv.w*r*gg.w + bb.w;
    split4_store(n, Acat + (size_t)row*2048, c, 1024);
  } else if (bx < 7168) {
    // ---- Wq/Wk/Wv split + bias ----
    const int idx = (bx - 4096)*256 + t;
    const int n = idx >> 8;
    const int col4 = (idx & 255) << 2;
    const float* src = (n < 1024) ? (Wq + (size_t)n*1024)
                     : (n < 2048) ? (Wk + (size_t)(n-1024)*1024)
                                  : (Wv + (size_t)(n-2048)*1024);
    const float4 a = *(const float4*)(src + col4);
    split4_store(a, Bqkv + (size_t)n*2048, col4, 1024);
    if (idx < 3072)
      biascat[idx] = (idx < 1024) ? bq[idx] : (idx < 2048) ? 0.f : bv[idx-2048];
  } else if (bx < 11264) {
    // ---- LN_a (fp32) ----
    const int row = bx - 7168;
    const float* xr = x + (size_t)row * D_;
    float v[4]; float s = 0.f;
    #pragma unroll
    for (int i = 0; i < 4; i++) { v[i] = xr[t + 256*i]; s += v[i]; }
    const float mean = block_reduce_sum_256(s, sbuf) * (1.0f/D_);
    float sq = 0.f;
    #pragma unroll
    for (int i = 0; i < 4; i++) { float d = v[i]-mean; sq += d*d; }
    const float var = block_reduce_sum_256(sq, sbuf) * (1.0f/D_);
    const float r = rsqrtf(var + 1e-5f);
    float* orow = loc + (size_t)row * D_;
    #pragma unroll
    for (int i = 0; i < 4; i++) {
      int c = t + 256*i;
      orow[c] = (v[i]-mean)*r*ln_a_g[c] + ln_a_b[c];
    }
  } else if (bx < 13312) {
    // ---- bf16(Wproj) -> B3 ----
    const int idx = (bx - 11264)*256 + t;
    const int row = idx >> 9;
    const int col4 = (idx & 511) << 2;
    const float4 a = *(const float4*)(Wproj + (size_t)row*2048 + col4);
    ushort4 hi;
    hi.x = f2bf(a.x); hi.y = f2bf(a.y); hi.z = f2bf(a.z); hi.w = f2bf(a.w);
    *(ushort4*)(B3 + (size_t)row*2048 + col4) = hi;
  } else {
    // ---- Wo split -> Bo ----
    const int idx = (bx - 13312)*256 + t;
    const int n = idx >> 8;
    const int col4 = (idx & 255) << 2;
    const float4 a = *(const float4*)(Wo + (size_t)n*1024 + col4);
    split4_store(a, Bo + (size_t)n*2048, col4, 1024);
  }
}

// ---------------- QKV GEMM with fused split epilogue (128x128, 768 blocks) -------
__global__ __launch_bounds__(256) void mfma_gemm_qkv(
    const ushort* __restrict__ A, const ushort* __restrict__ Bw,
    const float* __restrict__ bias,
    ushort* __restrict__ Qsp, ushort* __restrict__ Ksp,
    ushort* __restrict__ Vth, ushort* __restrict__ Vtl, int Kh) {
  __shared__ __align__(16) ushort smem[17408];   // 34 KB: staging / V-transpose
  ushort* Ash = smem;
  ushort* Asl = smem + 4096;
  ushort* Bsh = smem + 8192;
  ushort* Bsl = smem + 12288;
  const int lda = 2*Kh;
  const int tid = threadIdx.x;
  const int bm = blockIdx.y * 128, bn = blockIdx.x * 128;
  const int wave = tid >> 6, lane = tid & 63;
  const int wm = wave >> 1, wn = wave & 1;
  const int lm = lane & 15, q = lane >> 4;
  const int lrow = lane >> 2;
  const int sw = (((lane & 3) ^ ((lane >> 3) & 3)) << 3);

  f32x4 acc[4][4];
  #pragma unroll
  for (int i = 0; i < 4; i++)
    #pragma unroll
    for (int j = 0; j < 4; j++)
      acc[i][j] = (f32x4){0.f,0.f,0.f,0.f};

  const ushort* Agh = A  + (size_t)(bm + wave*32 + lrow)*lda + sw;
  const ushort* Agl = Agh + Kh;
  const ushort* Bgh = Bw + (size_t)(bn + wave*32 + lrow)*lda + sw;
  const ushort* Bgl = Bgh + Kh;
  const size_t r16a = (size_t)16*lda;
  ushort* AhD0 = &Ash[(wave*32)*32];      ushort* AhD1 = &Ash[(wave*32+16)*32];
  ushort* AlD0 = &Asl[(wave*32)*32];      ushort* AlD1 = &Asl[(wave*32+16)*32];
  ushort* BhD0 = &Bsh[(wave*32)*32];      ushort* BhD1 = &Bsh[(wave*32+16)*32];
  ushort* BlD0 = &Bsl[(wave*32)*32];      ushort* BlD1 = &Bsl[(wave*32+16)*32];
  const int rsw  = ((q ^ ((lm >> 1) & 3)) << 3);
  const int aoff = (wm*64 + lm)*32 + rsw;
  const int boff = (wn*64 + lm)*32 + rsw;

  for (int k0 = 0; k0 < Kh; k0 += 32) {
    __syncthreads();
    async_load16(Agh + k0, AhD0);
    async_load16(Agh + r16a + k0, AhD1);
    async_load16(Agl + k0, AlD0);
    async_load16(Agl + r16a + k0, AlD1);
    async_load16(Bgh + k0, BhD0);
    async_load16(Bgh + r16a + k0, BhD1);
    async_load16(Bgl + k0, BlD0);
    async_load16(Bgl + r16a + k0, BlD1);
    __syncthreads();
    short8 ah[4], al[4], bh[4], bl[4];
    #pragma unroll
    for (int mt = 0; mt < 4; mt++) {
      ah[mt] = *(const short8*)&Ash[aoff + mt*512];
      al[mt] = *(const short8*)&Asl[aoff + mt*512];
    }
    #pragma unroll
    for (int nt = 0; nt < 4; nt++) {
      bh[nt] = *(const short8*)&Bsh[boff + nt*512];
      bl[nt] = *(const short8*)&Bsl[boff + nt*512];
    }
    #pragma unroll
    for (int mt = 0; mt < 4; mt++)
      #pragma unroll
      for (int nt = 0; nt < 4; nt++) {
        f32x4 a = acc[mt][nt];
        a = MFMA16(ah[mt], bh[nt], a);
        a = MFMA16(al[mt], bh[nt], a);
        a = MFMA16(ah[mt], bl[nt], a);
        acc[mt][nt] = a;
      }
  }

  const int b = bm >> 10, s0 = bm & 1023;
  if (blockIdx.x < 16) {
    ushort* dst = (blockIdx.x < 8) ? Qsp : Ksp;
    const int h = ((bn + wn*64) >> 6) & 15;
    #pragma unroll
    for (int mt = 0; mt < 4; mt++) {
      #pragma unroll
      for (int nt = 0; nt < 4; nt++) {
        const int n = bn + wn*64 + nt*16 + lm;
        const int d = nt*16 + lm;
        const float bb = bias[n];
        #pragma unroll
        for (int reg = 0; reg < 4; reg++) {
          const int s = s0 + wm*64 + mt*16 + q*4 + reg;
          const float val = acc[mt][nt][reg] + bb;
          const ushort hi = f2bf(val);
          const ushort lo = f2bf(val - bf2f(hi));
          ushort* rp = dst + ((size_t)((b*16 + h)*1024 + s))*128;
          rp[d] = hi; rp[64 + d] = lo;
        }
      }
    }
  } else {
    ushort* Th = smem;            // [64][136] ushorts
    ushort* Tl = smem + 8704;
    #pragma unroll
    for (int c = 0; c < 2; c++) {
      __syncthreads();
      if (wn == c) {
        #pragma unroll
        for (int mt = 0; mt < 4; mt++)
          #pragma unroll
          for (int nt = 0; nt < 4; nt++) {
            const int nl = nt*16 + lm;
            const float bb = bias[bn + c*64 + nl];
            #pragma unroll
            for (int reg = 0; reg < 4; reg++) {
              const int sl = wm*64 + mt*16 + q*4 + reg;
              const float val = acc[mt][nt][reg] + bb;
              const ushort hi = f2bf(val);
              const ushort lo = f2bf(val - bf2f(hi));
              Th[nl*136 + sl] = hi;
              Tl[nl*136 + sl] = lo;
            }
          }
      }
      __syncthreads();
      const int nl = tid >> 2, s32 = (tid & 3)*32;
      const int h = ((bn - 2048 + c*64) >> 6) & 15;
      const size_t drow = ((size_t)((b*16 + h)*64 + nl))*1024 + s0 + s32;
      #pragma unroll
      for (int j = 0; j < 4; j++) {
        *(short8*)(Vth + drow + j*8) = *(const short8*)&Th[nl*136 + s32 + j*8];
        *(short8*)(Vtl + drow + j*8) = *(const short8*)&Tl[nl*136 + s32 + j*8];
      }
    }
  }
}

// ------- dual-panel bf16x3 MFMA GEMM, 64x128 tile (512 blocks = 2/CU) ------------
// Per-element K accumulation chain identical to the 128x128 version.
__global__ __launch_bounds__(256) void mfma_gemm2(
    const ushort* __restrict__ A, const ushort* __restrict__ Bw,
    const float* __restrict__ bias, float* __restrict__ C,
    int Kh, int ldc, ushort* __restrict__ aux) {
  __shared__ __align__(16) ushort Ash[64*32];
  __shared__ __align__(16) ushort Asl[64*32];
  __shared__ __align__(16) ushort Bsh[128*32];
  __shared__ __align__(16) ushort Bsl[128*32];
  const int lda = 2*Kh;
  const int tid = threadIdx.x;
  const int bm = blockIdx.y * 64, bn = blockIdx.x * 128;
  const int wave = tid >> 6, lane = tid & 63;
  const int lm = lane & 15, q = lane >> 4;
  const int lrow = lane >> 2;
  const int sw = (((lane & 3) ^ ((lane >> 3) & 3)) << 3);

  f32x4 acc[4][2];
  #pragma unroll
  for (int i = 0; i < 4; i++)
    #pragma unroll
    for (int j = 0; j < 2; j++)
      acc[i][j] = (f32x4){0.f,0.f,0.f,0.f};

  // 24 staging segments of 16 rows; wave w handles s = w*6 .. w*6+5
  const ushort* gsrc[6];
  ushort* ldst[6];
  #pragma unroll
  for (int i = 0; i < 6; i++) {
    const int s = wave*6 + i;
    const ushort* gp; ushort* lp;
    if (s < 4)       { gp = A  + (size_t)(bm + s*16 + lrow)*lda + sw;           lp = &Ash[(s*16)*32]; }
    else if (s < 8)  { gp = A  + (size_t)(bm + (s-4)*16 + lrow)*lda + Kh + sw;  lp = &Asl[((s-4)*16)*32]; }
    else if (s < 16) { gp = Bw + (size_t)(bn + (s-8)*16 + lrow)*lda + sw;       lp = &Bsh[((s-8)*16)*32]; }
    else             { gp = Bw + (size_t)(bn + (s-16)*16 + lrow)*lda + Kh + sw; lp = &Bsl[((s-16)*16)*32]; }
    gsrc[i] = gp; ldst[i] = lp;
  }
  const int rsw = ((q ^ ((lm >> 1) & 3)) << 3);
  const int aoff = lm*32 + rsw;
  const int boff = (wave*32 + lm)*32 + rsw;

  for (int k0 = 0; k0 < Kh; k0 += 32) {
    __syncthreads();
    #pragma unroll
    for (int i = 0; i < 6; i++) async_load16(gsrc[i] + k0, ldst[i]);
    __syncthreads();
    short8 ah[4], al[4], bh[2], bl[2];
    #pragma unroll
    for (int mt = 0; mt < 4; mt++) {
      ah[mt] = *(const short8*)&Ash[aoff + mt*512];
      al[mt] = *(const short8*)&Asl[aoff + mt*512];
    }
    #pragma unroll
    for (int nt = 0; nt < 2; nt++) {
      bh[nt] = *(const short8*)&Bsh[boff + nt*512];
      bl[nt] = *(const short8*)&Bsl[boff + nt*512];
    }
    #pragma unroll
    for (int mt = 0; mt < 4; mt++)
      #pragma unroll
      for (int nt = 0; nt < 2; nt++) {
        f32x4 a = acc[mt][nt];
        a = MFMA16(ah[mt], bh[nt], a);
        a = MFMA16(al[mt], bh[nt], a);
        a = MFMA16(ah[mt], bl[nt], a);
        acc[mt][nt] = a;
      }
  }

  #pragma unroll
  for (int mt = 0; mt < 4; mt++) {
    #pragma unroll
    for (int nt = 0; nt < 2; nt++) {
      const int n = bn + wave*32 + nt*16 + lm;
      const float bb = bias ? bias[n] : 0.f;
      #pragma unroll
      for (int reg = 0; reg < 4; reg++) {
        const int m = bm + mt*16 + q*4 + reg;
        const float val = acc[mt][nt][reg] + bb;
        C[(size_t)m*ldc + n] = val;
        if (aux) aux[(size_t)m*2048 + 1024 + n] = f2bf(val);
      }
    }
  }
}

// ---------- plain bf16 MFMA GEMM, 64x128 tile (512 blocks = 2/CU) ----------------
__global__ __launch_bounds__(256) void mfma_gemm(
    const ushort* __restrict__ A, const ushort* __restrict__ Bw,
    const float* __restrict__ bias, float* __restrict__ C,
    int K, int ldc) {
  __shared__ __align__(16) ushort As[64*32];
  __shared__ __align__(16) ushort Bs[128*32];
  const int tid = threadIdx.x;
  const int bm = blockIdx.y * 64, bn = blockIdx.x * 128;
  const int wave = tid >> 6, lane = tid & 63;
  const int lm = lane & 15, q = lane >> 4;
  const int lrow = lane >> 2;
  const int sw = (((lane & 3) ^ ((lane >> 3) & 3)) << 3);

  f32x4 acc[4][2];
  #pragma unroll
  for (int i = 0; i < 4; i++)
    #pragma unroll
    for (int j = 0; j < 2; j++)
      acc[i][j] = (f32x4){0.f,0.f,0.f,0.f};

  // 12 staging segments of 16 rows; wave w handles s = w*3 .. w*3+2
  const ushort* gsrc[3];
  ushort* ldst[3];
  #pragma unroll
  for (int i = 0; i < 3; i++) {
    const int s = wave*3 + i;
    const ushort* gp; ushort* lp;
    if (s < 4) { gp = A  + (size_t)(bm + s*16 + lrow)*K + sw;     lp = &As[(s*16)*32]; }
    else       { gp = Bw + (size_t)(bn + (s-4)*16 + lrow)*K + sw; lp = &Bs[((s-4)*16)*32]; }
    gsrc[i] = gp; ldst[i] = lp;
  }
  const int rsw = ((q ^ ((lm >> 1) & 3)) << 3);
  const int aoff = lm*32 + rsw;
  const int boff = (wave*32 + lm)*32 + rsw;

  for (int k0 = 0; k0 < K; k0 += 32) {
    __syncthreads();
    #pragma unroll
    for (int i = 0; i < 3; i++) async_load16(gsrc[i] + k0, ldst[i]);
    __syncthreads();
    short8 af[4], bf[2];
    #pragma unroll
    for (int mt = 0; mt < 4; mt++) af[mt] = *(const short8*)&As[aoff + mt*512];
    #pragma unroll
    for (int nt = 0; nt < 2; nt++) bf[nt] = *(const short8*)&Bs[boff + nt*512];
    #pragma unroll
    for (int mt = 0; mt < 4; mt++)
      #pragma unroll
      for (int nt = 0; nt < 2; nt++)
        acc[mt][nt] = MFMA16(af[mt], bf[nt], acc[mt][nt]);
  }

  #pragma unroll
  for (int mt = 0; mt < 4; mt++) {
    #pragma unroll
    for (int nt = 0; nt < 2; nt++) {
      const int n = bn + wave*32 + nt*16 + lm;
      const float bb = bias ? bias[n] : 0.f;
      #pragma unroll
      for (int reg = 0; reg < 4; reg++) {
        const int m = bm + mt*16 + q*4 + reg;
        C[(size_t)m*ldc + n] = acc[mt][nt][reg] + bb;
      }
    }
  }
}

// ---- one q-tile x k-tile attention unit (scores -> softmax -> PV) ----
__device__ __forceinline__ void attn_unit(
    int qt, int kt, int w, int lm, int q,
    const short8 qh[2], const short8 ql[2],
    const ushort* Kc, const ushort* Vc, float* Pf,
    f32x4 of[4], float mst[4], float lst[4]) {
  f32x4 sS[4];
  #pragma unroll
  for (int nt = 0; nt < 4; nt++) {
    const ushort* kr = &Kc[(nt*16 + lm)*136 + q*8];
    const short8 kh0 = *(const short8*)(kr);
    const short8 kh1 = *(const short8*)(kr + 32);
    const short8 kl0 = *(const short8*)(kr + 64);
    const short8 kl1 = *(const short8*)(kr + 96);
    f32x4 a = (f32x4){0.f,0.f,0.f,0.f};
    a = MFMA16(qh[0], kh0, a);
    a = MFMA16(ql[0], kh0, a);
    a = MFMA16(qh[0], kl0, a);
    a = MFMA16(qh[1], kh1, a);
    a = MFMA16(ql[1], kh1, a);
    a = MFMA16(qh[1], kl1, a);
    sS[nt] = a;
  }
  const int ktbase = kt*64;
  const int qrow0 = qt*64 + w*16 + q*4;
  #pragma unroll
  for (int rm = 0; rm < 4; rm++) {
    const int qrow = qrow0 + rm;
    float v[4];
    #pragma unroll
    for (int nt = 0; nt < 4; nt++) {
      const int kcol = ktbase + nt*16 + lm;
      const float x = sS[nt][rm]*0.125f;
      v[nt] = (kcol <= qrow) ? x : -INFINITY;
    }
    float tm = fmaxf(fmaxf(v[0],v[1]), fmaxf(v[2],v[3]));
    #pragma unroll
    for (int off = 1; off < 16; off <<= 1) tm = fmaxf(tm, __shfl_xor(tm, off, 64));
    const float nm = fmaxf(mst[rm], tm);
    const float alpha = __expf(mst[rm] - nm);
    float ps = 0.f;
    #pragma unroll
    for (int nt = 0; nt < 4; nt++) {
      float p = __expf(v[nt] - nm);
      sS[nt][rm] = p;
      ps += p;
    }
    #pragma unroll
    for (int off = 1; off < 16; off <<= 1) ps += __shfl_xor(ps, off, 64);
    lst[rm] = lst[rm]*alpha + ps;
    mst[rm] = nm;
    #pragma unroll
    for (int nt = 0; nt < 4; nt++) of[nt][rm] *= alpha;
  }
  #pragma unroll
  for (int rm = 0; rm < 4; rm++)
    #pragma unroll
    for (int nt = 0; nt < 4; nt++)
      Pf[(w*16 + q*4 + rm)*66 + nt*16 + lm] = sS[nt][rm];
  short8 ph[2], pl[2];
  {
    const float* prow = &Pf[(w*16 + lm)*66];
    float pv[16];
    *(float4*)&pv[0]  = *(const float4*)(prow + q*8);
    *(float4*)&pv[4]  = *(const float4*)(prow + q*8 + 4);
    *(float4*)&pv[8]  = *(const float4*)(prow + 32 + q*8);
    *(float4*)&pv[12] = *(const float4*)(prow + 32 + q*8 + 4);
    split8(&pv[0], &ph[0], &pl[0]);
    split8(&pv[8], &ph[1], &pl[1]);
  }
  #pragma unroll
  for (int nt = 0; nt < 4; nt++) {
    const ushort* vr = &Vc[(nt*16 + lm)*136 + q*8];
    const short8 vh0 = *(const short8*)(vr);
    const short8 vh1 = *(const short8*)(vr + 32);
    const short8 vl0 = *(const short8*)(vr + 64);
    const short8 vl1 = *(const short8*)(vr + 96);
    f32x4 a = of[nt];
    a = MFMA16(ph[0], vh0, a);
    a = MFMA16(pl[0], vh0, a);
    a = MFMA16(ph[0], vl0, a);
    a = MFMA16(ph[1], vh1, a);
    a = MFMA16(pl[1], vh1, a);
    a = MFMA16(ph[1], vl1, a);
    of[nt] = a;
  }
}

// ---- MFMA causal flash attention: dual q-tile, shared K/V staging ----
__global__ __launch_bounds__(256) void gattn_mfma(
    const ushort* __restrict__ Qsp, const ushort* __restrict__ Ksp,
    const ushort* __restrict__ Vth, const ushort* __restrict__ Vtl,
    ushort* __restrict__ Aout) {
  __shared__ __align__(16) ushort Kc[64*136];
  __shared__ __align__(16) ushort Vc[64*136];
  __shared__ __align__(16) float  Pf[64*66];
  const int bh = blockIdx.y;
  const int b = bh >> 4, h = bh & 15;
  const int tid = threadIdx.x;
  const int w = tid >> 6, lane = tid & 63;
  const int lm = lane & 15, q = lane >> 4;
  const ushort* Qb_ = Qsp + (size_t)bh * (1024*128);
  const ushort* Kb_ = Ksp + (size_t)bh * (1024*128);
  const ushort* Vhb = Vth + (size_t)bh * (64*1024);
  const ushort* Vlb = Vtl + (size_t)bh * (64*1024);
  const int qtA = 15 - blockIdx.x;
  const int qtB = blockIdx.x;

  short8 qhA[2], qlA[2], qhB[2], qlB[2];
  {
    const ushort* qr = Qb_ + (size_t)(qtA*64 + w*16 + lm)*128 + q*8;
    qhA[0] = *(const short8*)(qr);
    qhA[1] = *(const short8*)(qr + 32);
    qlA[0] = *(const short8*)(qr + 64);
    qlA[1] = *(const short8*)(qr + 96);
    const ushort* qr2 = Qb_ + (size_t)(qtB*64 + w*16 + lm)*128 + q*8;
    qhB[0] = *(const short8*)(qr2);
    qhB[1] = *(const short8*)(qr2 + 32);
    qlB[0] = *(const short8*)(qr2 + 64);
    qlB[1] = *(const short8*)(qr2 + 96);
  }
  f32x4 ofA[4], ofB[4];
  float mstA[4], lstA[4], mstB[4], lstB[4];
  #pragma unroll
  for (int nt = 0; nt < 4; nt++) {
    ofA[nt] = (f32x4){0.f,0.f,0.f,0.f};
    ofB[nt] = (f32x4){0.f,0.f,0.f,0.f};
  }
  #pragma unroll
  for (int rm = 0; rm < 4; rm++) {
    mstA[rm] = -INFINITY; lstA[rm] = 0.f;
    mstB[rm] = -INFINITY; lstB[rm] = 0.f;
  }

  for (int kt = 0; kt <= qtA; ++kt) {
    __syncthreads();
    #pragma unroll
    for (int i = 0; i < 4; i++) {
      const int slot = i*256 + tid;
      const int row = slot >> 4, c8 = slot & 15;
      *(float4*)&Kc[row*136 + c8*8] =
          *(const float4*)(Kb_ + (size_t)(kt*64 + row)*128 + c8*8);
      const ushort* vsrc = ((c8 < 8) ? Vhb : Vlb) + (size_t)row*1024 + kt*64 + (c8&7)*8;
      *(float4*)&Vc[row*136 + c8*8] = *(const float4*)vsrc;
    }
    __syncthreads();
    attn_unit(qtA, kt, w, lm, q, qhA, qlA, Kc, Vc, Pf, ofA, mstA, lstA);
    if (kt <= qtB)
      attn_unit(qtB, kt, w, lm, q, qhB, qlB, Kc, Vc, Pf, ofB, mstB, lstB);
  }

  #pragma unroll
  for (int rm = 0; rm < 4; rm++) {
    const float invA = 1.0f / lstA[rm];
    const int sA = qtA*64 + w*16 + q*4 + rm;
    ushort* arow = Aout + ((size_t)(b*1024 + sA))*2048 + h*64;
    #pragma unroll
    for (int nt = 0; nt < 4; nt++) {
      const float val = ofA[nt][rm] * invA;
      const ushort hi = f2bf(val);
      arow[nt*16 + lm] = hi;
      arow[1024 + nt*16 + lm] = f2bf(val - bf2f(hi));
    }
    const float invB = 1.0f / lstB[rm];
    const int sB = qtB*64 + w*16 + q*4 + rm;
    ushort* brow = Aout + ((size_t)(b*1024 + sB))*2048 + h*64;
    #pragma unroll
    for (int nt = 0; nt < 4; nt++) {
      const float val = ofB[nt][rm] * invB;
      const ushort hi = f2bf(val);
      brow[nt*16 + lm] = hi;
      brow[1024 + nt*16 + lm] = f2bf(val - bf2f(hi));
    }
  }
}

// ---------------- seq-mean, 2-stage deterministic ----------------
__global__ __launch_bounds__(256) void seqmean1_kernel(const float* __restrict__ g,
                                                       float* __restrict__ part) {
  const int d = blockIdx.x*256 + threadIdx.x;
  const int sc = blockIdx.y;
  const int b = blockIdx.z;
  const float* p = g + ((size_t)b*S_ + sc*128)*D_ + d;
  float s = 0.f;
  #pragma unroll 4
  for (int i = 0; i < 128; i++) s += p[(size_t)i*D_];
  part[((size_t)(b*8 + sc))*D_ + d] = s;
}
__global__ __launch_bounds__(256) void seqmean2_kernel(const float* __restrict__ part,
                                                       float* __restrict__ mbd) {
  const int d = blockIdx.x*256 + threadIdx.x;
  const int b = blockIdx.y;
  float s = 0.f;
  #pragma unroll
  for (int i = 0; i < 8; i++) s += part[((size_t)(b*8 + i))*D_ + d];
  mbd[b*D_ + d] = s * (1.0f/S_);
}

// ---------------- predictor ----------------
__global__ __launch_bounds__(256) void predictor_kernel(
    const float* __restrict__ mbd, const float* __restrict__ Wp,
    const float* __restrict__ bp, float* __restrict__ fpar, int* __restrict__ ipar) {
  __shared__ float sbuf[4];
  __shared__ float sdots[4];
  const int tid = threadIdx.x;
  for (int b = 0; b < 4; b++) {
    float psum = 0.f;
    for (int d = tid; d < D_; d += 256) psum += mbd[b*D_ + d]*Wp[d];
    float tot = block_reduce_sum_256(psum, sbuf);
    if (tid == 0) sdots[b] = tot;
  }
  __syncthreads();
  if (tid == 0) {
    float smv = 0.f;
    for (int b = 0; b < 4; b++) {
      float z = sdots[b] + bp[0];
      smv += 1.0f/(1.0f + expf(-z));
    }
    smv *= 0.25f;
    int win = max(1, (int)(256.0f*smv));
    int span_len = max(1, (int)(512.0f*smv));
    int local_max = min(512, min(span_len, win));
    float temp = 1.0f + 0.01f*(1.0f - smv);
    int n_win = (S_ + win - 1)/win;
    fpar[0] = smv; fpar[1] = temp;
    ipar[0] = win; ipar[1] = span_len; ipar[2] = local_max; ipar[3] = n_win;
  }
}

// -------- dynamic sliding-window span attention (fp32 -> bf16 out, self-zeroing) --
#define LDP 68
__global__ __launch_bounds__(256) void lattn_kernel(
    const float* __restrict__ Lc, ushort* __restrict__ Out,
    const int* __restrict__ ip, const float* __restrict__ fpp) {
  __shared__ __align__(16) float Qs[HD_][LDP];
  __shared__ __align__(16) float KPs[64][LDP];
  __shared__ __align__(16) float Vs[64][LDP];
  const int n_win = ip[3];
  const int win = ip[0], span_len = ip[1], local_max = ip[2];
  const float sm = fpp[0], temp = fpp[1];
  const int bh = blockIdx.y;
  const int b = bh >> 4, h = bh & 15;
  const int tid = threadIdx.x;
  const int tx = tid & 15, ty = tid >> 4;
  const float sc = 0.35355339059327373f / temp;
  for (int w = blockIdx.x; w < n_win; w += gridDim.x) {
    const int st = w * win;
    const int en = min(st + win, S_); const int wlen = en - st;
    const int ks = max(0, st - span_len + win);
    const int ke = min(st + span_len, S_); const int klen = ke - ks;
    int eff = (int)((double)wlen * (double)sm);
    eff = min(min(eff, wlen), min(klen, local_max));
    if (eff > 0) {
      const int nt = (eff + 63) >> 6;
      for (int qt = 0; qt < nt; ++qt) {
        const int qn = min(64, eff - qt*64);
        __syncthreads();
        #pragma unroll
        for (int c = 0; c < 4; c++) {
          int f = tid + c*256;
          int r = f >> 4;
          int dc = (f & 15) << 2;
          float4 q4 = make_float4(0.f,0.f,0.f,0.f);
          if (r < qn) q4 = *(const float4*)(Lc + ((size_t)(b*S_ + st + qt*64 + r)) * D_ + h*HD_ + dc);
          Qs[dc+0][r]=q4.x; Qs[dc+1][r]=q4.y; Qs[dc+2][r]=q4.z; Qs[dc+3][r]=q4.w;
        }
        float o[4][4] = {{0.f,0.f,0.f,0.f},{0.f,0.f,0.f,0.f},{0.f,0.f,0.f,0.f},{0.f,0.f,0.f,0.f}};
        float mrow[4], lrow[4];
        #pragma unroll
        for (int i=0;i<4;i++){ mrow[i] = -INFINITY; lrow[i] = 0.f; }
        for (int kt = 0; kt < nt; ++kt) {
          const int kn = min(64, eff - kt*64);
          __syncthreads();
          #pragma unroll
          for (int c = 0; c < 4; c++) {
            int f = tid + c*256;
            int r = f >> 4;
            int dc = (f & 15) << 2;
            float4 k4 = make_float4(0.f,0.f,0.f,0.f);
            if (r < kn) k4 = *(const float4*)(Lc + ((size_t)(b*S_ + ks + kt*64 + r)) * D_ + h*HD_ + dc);
            KPs[dc+0][r]=k4.x; KPs[dc+1][r]=k4.y; KPs[dc+2][r]=k4.z; KPs[dc+3][r]=k4.w;
            *(float4*)&Vs[r][dc] = k4;
          }
          __syncthreads();
          float s[4][4] = {{0.f,0.f,0.f,0.f},{0.f,0.f,0.f,0.f},{0.f,0.f,0.f,0.f},{0.f,0.f,0.f,0.f}};
          #pragma unroll 8
          for (int d = 0; d < HD_; ++d) {
            const float4 a  = *(const float4*)&Qs[d][ty*4];
            const float4 bb = *(const float4*)&KPs[d][tx*4];
            const float av[4]={a.x,a.y,a.z,a.w};
            const float bv[4]={bb.x,bb.y,bb.z,bb.w};
            #pragma unroll
            for (int i=0;i<4;i++)
              #pragma unroll
              for (int j=0;j<4;j++)
                s[i][j] += av[i]*bv[j];
          }
          #pragma unroll
          for (int i=0;i<4;i++) {
            #pragma unroll
            for (int j=0;j<4;j++) {
              float lg = s[i][j]*sc;
              if (kt*64 + tx*4 + j >= eff) lg = -INFINITY;
              s[i][j] = lg;
            }
          }
          #pragma unroll
          for (int i=0;i<4;i++) {
            float tm = fmaxf(fmaxf(s[i][0],s[i][1]), fmaxf(s[i][2],s[i][3]));
            #pragma unroll
            for (int off=1; off<16; off<<=1) tm = fmaxf(tm, __shfl_xor(tm, off, 64));
            const float nm = fmaxf(mrow[i], tm);
            const float alpha = __expf(mrow[i]-nm);
            float ps = 0.f;
            #pragma unroll
            for (int j=0;j<4;j++){ float p = __expf(s[i][j]-nm); s[i][j]=p; ps += p; }
            #pragma unroll
            for (int off=1; off<16; off<<=1) ps += __shfl_xor(ps, off, 64);
            lrow[i] = lrow[i]*alpha + ps;
            mrow[i] = nm;
            #pragma unroll
            for (int j=0;j<4;j++) o[i][j] *= alpha;
          }
          __syncthreads();
          #pragma unroll
          for (int i=0;i<4;i++)
            #pragma unroll
            for (int j=0;j<4;j++)
              KPs[tx*4+j][ty*4+i] = s[i][j];
          __syncthreads();
          #pragma unroll 8
          for (int kk = 0; kk < 64; ++kk) {
            const float4 a  = *(const float4*)&KPs[kk][ty*4];
            const float4 bb = *(const float4*)&Vs[kk][tx*4];
            const float av[4]={a.x,a.y,a.z,a.w};
            const float bv[4]={bb.x,bb.y,bb.z,bb.w};
            #pragma unroll
            for (int i=0;i<4;i++)
              #pragma unroll
              for (int j=0;j<4;j++)
                o[i][j] += av[i]*bv[j];
          }
        }
        #pragma unroll
        for (int i=0;i<4;i++){
          const int r = ty*4 + i;
          if (r < qn) {
            const float inv = 1.0f / lrow[i];
            ushort4 ov;
            ov.x = f2bf(o[i][0]*inv); ov.y = f2bf(o[i][1]*inv);
            ov.z = f2bf(o[i][2]*inv); ov.w = f2bf(o[i][3]*inv);
            *(ushort4*)(Out + ((size_t)(b*S_ + st + qt*64 + r)) * 2048 + h*HD_ + tx*4) = ov;
          }
        }
      }
    }
    const ushort4 z = {0,0,0,0};
    for (int r = max(eff, 0) + ty; r < wlen; r += 16)
      *(ushort4*)(Out + ((size_t)(b*S_ + st + r)) * 2048 + h*HD_ + tx*4) = z;
  }
}

// ---------------- launch ----------------
extern "C" void kernel_launch(void* const* d_in, const int* in_sizes, int n_in,
                              void* d_out, int out_size, void* d_ws, size_t ws_size,
                              hipStream_t stream) {
  const float* x      = (const float*)d_in[0];
  const float* ln_a_g = (const float*)d_in[1];
  const float* ln_a_b = (const float*)d_in[2];
  const float* ln_b_g = (const float*)d_in[3];
  const float* ln_b_b = (const float*)d_in[4];
  const float* Wq     = (const float*)d_in[5];
  const float* bq     = (const float*)d_in[6];
  const float* Wk     = (const float*)d_in[7];
  const float* Wv     = (const float*)d_in[8];
  const float* bv     = (const float*)d_in[9];
  const float* Wo     = (const float*)d_in[10];
  const float* bo     = (const float*)d_in[11];
  const float* Wp     = (const float*)d_in[12];
  const float* bp     = (const float*)d_in[13];
  const float* Wproj  = (const float*)d_in[14];
  const float* bproj  = (const float*)d_in[15];
  float* out = (float*)d_out;
  float* ws  = (float*)d_ws;
  ushort* wsu = (ushort*)d_ws;

  // ws layout:
  ushort* Qsp = wsu;                         // [64*1024,128] 16.8MB
  ushort* Ksp = wsu + 8388608;               // [64*1024,128] 16.8MB
  ushort* Vth = wsu + 16777216;              // [64*64,1024]  8.4MB
  ushort* Vtl = wsu + 20971520;              // [64*64,1024]  8.4MB
  ushort* B3  = (ushort*)(ws + 12582912);    // [1024,2048] bf16 (ex-buf0, free)
  float* glo  = ws + 16777216;               // [4096,1024] globe_out
  float* loc  = ws + 20971520;               // [4096,1024] LN_a out
  float* biascat = ws + 25165824;            // [3072]
  float* mbd  = biascat + 4096;
  float* fpar = mbd + 4096;
  int*   ipar = (int*)(fpar + 8);
  ushort* Acat  = (ushort*)(ws + 25182208);  // [4096,2048] bf16 (LNb split; attn out)
  ushort* Bqkv  = Acat + 12582912;           // [3072,2048] bf16
  ushort* Bo    = Bqkv + 9437184;            // [1024,2048] bf16
  float*  part = (float*)Acat;               // [B*8,1024] fp32 (after Acat dead)
  ushort* A3  = wsu;                         // [4096,2048] overlays Qsp (dead)

  const dim3 blk(256);

  // 1) all input prep in one dispatch
  prep_kernel<<<dim3(14336), blk, 0, stream>>>(
      x, ln_a_g, ln_a_b, ln_b_g, ln_b_b, Wq, Wk, Wv, bq, bv, Wo, Wproj,
      Acat, Bqkv, biascat, loc, B3, Bo);
  // 2) QKV GEMM with fused split epilogue -> Qsp/Ksp/Vth/Vtl
  mfma_gemm_qkv<<<dim3(24, 32), blk, 0, stream>>>(Acat, Bqkv, biascat,
                                                  Qsp, Ksp, Vth, Vtl, 1024);
  // 3) MFMA causal attention -> Acat [hi|lo] directly
  gattn_mfma<<<dim3(8, 64), blk, 0, stream>>>(Qsp, Ksp, Vth, Vtl, Acat);
  // 4) globe_out = attn · Wo^T + bo (64x128 tiles; aux bf16 -> A3[:,1024:])
  mfma_gemm2<<<dim3(8, 64), blk, 0, stream>>>(Acat, Bo, bo, glo, 1024, 1024, A3);
  // 5) predictor (device-side)
  seqmean1_kernel<<<dim3(4, 8, B_), blk, 0, stream>>>(glo, part);
  seqmean2_kernel<<<dim3(4, B_), blk, 0, stream>>>(part, mbd);
  predictor_kernel<<<dim3(1), blk, 0, stream>>>(mbd, Wp, bp, fpar, ipar);
  // 6) local attention -> A3[:, 0:1024] bf16 (self-zeroing)
  lattn_kernel<<<dim3(64, B_*H_), blk, 0, stream>>>(loc, A3, ipar, fpar);
  // 7) out = A3 · B3^T + bproj (64x128 tiles)
  mfma_gemm<<<dim3(8, 64), blk, 0, stream>>>(A3, B3, bproj, out, 2048, 1024);
}